// Round 16
// baseline (323.814 us; speedup 1.0000x reference)
//
#include <hip/hip_runtime.h>
#include <hip/hip_bf16.h>

typedef __bf16 bf16;
typedef __bf16 bf16x4 __attribute__((ext_vector_type(4)));
typedef __bf16 bf16x8 __attribute__((ext_vector_type(8)));
typedef float  f32x4  __attribute__((ext_vector_type(4)));
typedef float  f32x16 __attribute__((ext_vector_type(16)));
typedef int    int4v  __attribute__((ext_vector_type(4)));

#define H_DIM 1024
#define NHEAD 16
#define HD    64
// SCALE * log2(e), folded into Q-projection epilogue; attn softmax runs in base-2
#define QSCL 0.18033688011112042f

__device__ __forceinline__ void gload_lds16(const bf16* g, bf16* l) {
    __builtin_amdgcn_global_load_lds((const __attribute__((address_space(1))) void*)g,
                                     (__attribute__((address_space(3))) void*)l, 16, 0, 0);
}

__device__ __forceinline__ unsigned cvtpk_bf16(float lo, float hi) {
    unsigned r;
    asm volatile("v_cvt_pk_bf16_f32 %0, %1, %2" : "=v"(r) : "v"(lo), "v"(hi));
    return r;
}

// single-instruction 2^x (v_exp_f32); plain exp2f lowers to the multi-instr libm path
__device__ __forceinline__ float fexp2(float x) {
    float r;
    asm("v_exp_f32 %0, %1" : "=v"(r) : "v"(x));
    return r;
}

// ---------------- weight fp32 [K][N] -> bf16 [N][K] (transpose+convert) ----------------
__device__ __forceinline__ void wconv_body(const float* __restrict__ W,
                                           bf16* __restrict__ Wt, int K, int N,
                                           int bx, int by, int t) {
    __shared__ float tile[64][65];
    const int n0 = bx * 64, k0 = by * 64;
#pragma unroll
    for (int p = 0; p < 4; ++p) {
        int lin = p * 1024 + t * 4;
        int r = lin >> 6, c = lin & 63;
        f32x4 v = *(const f32x4*)(W + (size_t)(k0 + r) * N + n0 + c);
        tile[r][c]     = v[0];
        tile[r][c + 1] = v[1];
        tile[r][c + 2] = v[2];
        tile[r][c + 3] = v[3];
    }
    __syncthreads();
#pragma unroll
    for (int p = 0; p < 4; ++p) {
        int lin = p * 1024 + t * 4;
        int rn = lin >> 6, ck = lin & 63;
        bf16x4 o;
#pragma unroll
        for (int j = 0; j < 4; ++j) o[j] = (bf16)tile[ck + j][rn];
        *(bf16x4*)(Wt + (size_t)(n0 + rn) * K + k0 + ck) = o;
    }
}

__global__ __launch_bounds__(256) void wconv_kernel(const float* __restrict__ W,
                                                    bf16* __restrict__ Wt,
                                                    int K, int N) {
    wconv_body(W, Wt, K, N, blockIdx.x, blockIdx.y, threadIdx.x);
}

struct WPtrs { const float* w[8]; bf16* o[8]; };
__global__ __launch_bounds__(256) void wconv8_kernel(WPtrs p) {
    const int m = blockIdx.z;
    wconv_body(p.w[m], p.o[m], 1024, 1024, blockIdx.x, blockIdx.y, threadIdx.x);
}

// ---------------- layernorm (fp32 in, bf16 out), one row per block ----------------
__global__ __launch_bounds__(256) void ln_kernel(const float* __restrict__ in, float inScale,
                                                 const float* __restrict__ g,
                                                 const float* __restrict__ b,
                                                 bf16* __restrict__ out) {
    const int row = blockIdx.x, t = threadIdx.x;
    const float* p = in + (size_t)row * H_DIM;
    f32x4 v = *(const f32x4*)(p + t * 4);
    v *= inScale;
    float s1 = v[0] + v[1] + v[2] + v[3];
    float s2 = v[0] * v[0] + v[1] * v[1] + v[2] * v[2] + v[3] * v[3];
#pragma unroll
    for (int m = 1; m < 64; m <<= 1) {
        s1 += __shfl_xor(s1, m);
        s2 += __shfl_xor(s2, m);
    }
    __shared__ float red[8];
    const int wave = t >> 6;
    if ((t & 63) == 0) { red[wave * 2] = s1; red[wave * 2 + 1] = s2; }
    __syncthreads();
    s1 = red[0] + red[2] + red[4] + red[6];
    s2 = red[1] + red[3] + red[5] + red[7];
    float mean = s1 * (1.0f / H_DIM);
    float var  = s2 * (1.0f / H_DIM) - mean * mean;
    float inv  = rsqrtf(var + 1e-5f);
    f32x4 gg = *(const f32x4*)(g + t * 4);
    f32x4 bb = *(const f32x4*)(b + t * 4);
    bf16x4 o;
#pragma unroll
    for (int j = 0; j < 4; ++j) o[j] = (bf16)((v[j] - mean) * inv * gg[j] + bb[j]);
    *(bf16x4*)(out + (size_t)row * H_DIM + t * 4) = o;
}

// ---------------- fp32 -> bf16 with scale ----------------
__global__ __launch_bounds__(256) void cvt_scale_kernel(const float* __restrict__ in,
                                                        bf16* __restrict__ out,
                                                        float s, int n4) {
    int i = blockIdx.x * 256 + threadIdx.x;
    if (i < n4) {
        f32x4 v = *(const f32x4*)(in + (size_t)i * 4);
        bf16x4 o;
#pragma unroll
        for (int j = 0; j < 4; ++j) o[j] = (bf16)(v[j] * s);
        *(bf16x4*)(out + (size_t)i * 4) = o;
    }
}

// ---------------- GEMM v4: 32x32x16 MFMA, SINGLE-buffered LDS (m97 structure) ----
// Rationale: per-iter compute (256 cyc) < load latency (~900 cyc), so intra-block
// dbuf can't hide it and costs half the occupancy. Single buffer -> 5-6 blocks/CU;
// inter-block overlap (m114) fills the matrix pipe. XOR swizzle kept (rule #21):
// linear LDS dest + pre-swizzled global source col + same XOR on fragment reads.
// C/D: col = lane&31, row = (reg&3) + 8*(reg>>2) + 4*(lane>>5)
// MODE 0: plain epilogue -> o1; MODE 1: QKV fused; MODE 2: KV fused
// V-transposed layout: [b][h][d][s], s = row & (2^slog2 - 1)
template <int BM, int BN, int MODE, bool OUT_BF16, bool GELU_EPI, bool HAS_RES>
__global__ __launch_bounds__(256) void gemm_kernel(const bf16* __restrict__ A,
                                                   const bf16* __restrict__ Bt,
                                                   const float* __restrict__ bias1,
                                                   const float* __restrict__ bias2,
                                                   const float* __restrict__ bias3,
                                                   const float* __restrict__ res,
                                                   void* __restrict__ o1, void* __restrict__ o2,
                                                   void* __restrict__ o3,
                                                   int M, int N, int K,
                                                   float resScale, float outScale, int slog2) {
    constexpr int CHUNKS = (BM + BN) / 32;       // 32-row x 64-col staging chunks
    constexpr int WRR = BM / 2, WCC = BN / 2;    // per-wave sub-tile (2x2 wave grid)
    constexpr int MI = WRR / 32, NJ = WCC / 32;  // 32x32 fragments per wave
    __shared__ bf16 SM[(BM + BN) * 64];          // single buffer, linear (gload_lds dest)
    // T1: bijective XCD swizzle (all grids here are %8==0)
    const int nwg = gridDim.x * gridDim.y;
    const int dlin = blockIdx.y * gridDim.x + blockIdx.x;
    const int id = (dlin & 7) * (nwg >> 3) + (dlin >> 3);
    const int bx = id % gridDim.x, by = id / gridDim.x;
    const int m0 = by * BM, n0 = bx * BN;
    const int tid = threadIdx.x;
    const int wave = tid >> 6, lane = tid & 63;
    const int l31 = lane & 31, l5 = lane >> 5;
    const int wr = wave >> 1, wc = wave & 1;
    const int sr = lane >> 3, sc8 = (lane & 7) * 8;
    const int sc8x = sc8 ^ (sr << 3);            // pre-swizzled source col (involution)
    const int rxr = (l31 & 7) << 3;              // read-side XOR (row&7 == l31&7)

    f32x16 acc[MI][NJ] = {};

    auto stage = [&](int k0) {
#pragma unroll
        for (int p = 0; p < CHUNKS; ++p) {
            const int rr = p * 32 + wave * 8 + sr;
            bf16* l = &SM[0] + p * 2048 + wave * 512;        // wave-uniform base
            const bf16* g = (p < BM / 32)
                ? (A  + (size_t)(m0 + rr) * K + k0 + sc8x)
                : (Bt + (size_t)(n0 + rr - BM) * K + k0 + sc8x);
            gload_lds16(g, l);
        }
    };

    for (int k0 = 0; k0 < K; k0 += 64) {
        __syncthreads();   // all waves done reading SM from previous iter
        stage(k0);
        __syncthreads();   // drains vmcnt -> tile resident
#pragma unroll
        for (int kk = 0; kk < 4; ++kk) {            // K=16 per MFMA
            const int sa = (kk * 16 + l5 * 8) ^ rxr;
            bf16x8 af[MI], bfr[NJ];
#pragma unroll
            for (int i = 0; i < MI; ++i)
                af[i] = *(const bf16x8*)&SM[(wr * WRR + i * 32 + l31) * 64 + sa];
#pragma unroll
            for (int j = 0; j < NJ; ++j)
                bfr[j] = *(const bf16x8*)&SM[(BM + wc * WCC + j * 32 + l31) * 64 + sa];
#pragma unroll
            for (int i = 0; i < MI; ++i)
#pragma unroll
                for (int j = 0; j < NJ; ++j)
                    acc[i][j] = __builtin_amdgcn_mfma_f32_32x32x16_bf16(af[i], bfr[j], acc[i][j], 0, 0, 0);
        }
    }

#pragma unroll
    for (int i = 0; i < MI; ++i) {
#pragma unroll
        for (int j = 0; j < NJ; ++j) {
            const int col = n0 + wc * WCC + j * 32 + l31;
            const int rbase = m0 + wr * WRR + i * 32 + l5 * 4;
            if (MODE == 0) {
                const float bv = bias1[col];
#pragma unroll
                for (int rq = 0; rq < 4; ++rq)
#pragma unroll
                    for (int rr = 0; rr < 4; ++rr) {
                        const int row = rbase + rq * 8 + rr;
                        const size_t idx = (size_t)row * N + col;
                        float v = acc[i][j][rq * 4 + rr] + bv;
                        if (HAS_RES) v += res[idx] * resScale;
                        if (GELU_EPI) v = 0.5f * v * (1.0f + erff(v * 0.70710678118654752f));
                        v *= outScale;
                        if (OUT_BF16) ((bf16*)o1)[idx] = (bf16)v;
                        else          ((float*)o1)[idx] = v;
                    }
            } else {
                const int sec = col >> 10, cl = col & 1023;
                const bool isV = (MODE == 1) ? (sec == 2) : (sec == 1);
                const float* bp = (MODE == 1) ? (sec == 0 ? bias1 : sec == 1 ? bias2 : bias3)
                                              : (sec == 0 ? bias1 : bias2);
                const float bv = bp[cl];
                if (!isV) {
                    bf16* dst = (MODE == 1) ? (sec == 0 ? (bf16*)o1 : (bf16*)o2) : (bf16*)o1;
                    const float sc = (MODE == 1 && sec == 0) ? outScale : 1.f;
#pragma unroll
                    for (int rq = 0; rq < 4; ++rq)
#pragma unroll
                        for (int rr = 0; rr < 4; ++rr) {
                            const int row = rbase + rq * 8 + rr;
                            dst[(size_t)row * H_DIM + cl] = (bf16)((acc[i][j][rq * 4 + rr] + bv) * sc);
                        }
                } else {
                    bf16* dst = (MODE == 1) ? (bf16*)o3 : (bf16*)o2;
                    const int S = 1 << slog2;
                    const int hI = cl >> 6, dI = cl & 63;
#pragma unroll
                    for (int rq = 0; rq < 4; ++rq) {
                        const int row0 = rbase + rq * 8;       // 4 consecutive rows
                        const int bI = row0 >> slog2, s0 = row0 & (S - 1);
                        bf16x4 ov;
#pragma unroll
                        for (int rr = 0; rr < 4; ++rr) ov[rr] = (bf16)(acc[i][j][rq * 4 + rr] + bv);
                        *(bf16x4*)(dst + ((size_t)((bI * NHEAD + hI) * HD + dI)) * S + s0) = ov;
                    }
                }
            }
        }
    }
}

// ---------------- flash attention v10 (unchanged): raw v_exp_f32 + setprio ----------------
__global__ __launch_bounds__(256) void attn_kernel(const bf16* __restrict__ Qb,
                                                   const bf16* __restrict__ Kb,
                                                   const bf16* __restrict__ Vt_g,
                                                   bf16* __restrict__ Ob,
                                                   int SQ, int SK) {
    __shared__ bf16 SMEM[2][2][64 * 64];         // [buf][K|V][4096]; reused for O-transpose
    const int nwg = gridDim.x * gridDim.y;
    const int dlin = blockIdx.y * gridDim.x + blockIdx.x;
    const int id = (dlin & 7) * (nwg >> 3) + (dlin >> 3);
    const int NQ = gridDim.y;
    const int bh = id / NQ, qt = id - bh * NQ;
    const int b = bh >> 4, h = bh & 15;
    const int q0 = qt * 128;
    const int tid = threadIdx.x, wave = tid >> 6, lane = tid & 63;
    const int lr = lane & 15, lhi = lane >> 4;

    bf16x8 qf[2][2];
#pragma unroll
    for (int qi = 0; qi < 2; ++qi) {
        const bf16* qp = Qb + ((size_t)b * SQ + q0 + wave * 32 + qi * 16 + lr) * H_DIM + h * HD;
        qf[qi][0] = *(const bf16x8*)(qp + lhi * 8);
        qf[qi][1] = *(const bf16x8*)(qp + 32 + lhi * 8);
    }

    const int kx = (((lr & 3) | (((lr >> 2) & 1) << 2)) << 3);
    const int vx = (((lr & 3) | (((lr >> 3) & 1) << 2)) << 3);
    int krow[4];
#pragma unroll
    for (int nf = 0; nf < 4; ++nf)
        krow[nf] = (nf >> 1) * 32 + (lr >> 2) * 8 + (nf & 1) * 4 + (lr & 3);

    const int rS = tid >> 3, cS = (tid & 7) * 8;
    const int kxw = (((rS & 3) | (((rS >> 3) & 1) << 2)) << 3);
    const bf16* Kg = Kb + (size_t)b * SK * H_DIM + h * HD;
    const bf16* Vg = Vt_g + (size_t)bh * 64 * SK;

    bf16x8 onesv;
#pragma unroll
    for (int j = 0; j < 8; ++j) onesv[j] = (bf16)1.0f;

    f32x4 o[2][4] = {};
    f32x4 psum[2] = {};
    bf16x8 gK[2], gV[2];

    auto LOADG = [&](int kb) {
#pragma unroll
        for (int p = 0; p < 2; ++p) {
            gK[p] = *(const bf16x8*)(Kg + (size_t)(kb + p * 32 + rS) * H_DIM + cS);
            gV[p] = *(const bf16x8*)(Vg + (size_t)(p * 32 + rS) * SK + kb + cS);
        }
    };
    auto STORES = [&](int buf) {
#pragma unroll
        for (int p = 0; p < 2; ++p) {
            *(bf16x8*)&SMEM[buf][0][(p * 32 + rS) * 64 + (cS ^ kxw)] = gK[p];
            *(bf16x8*)&SMEM[buf][1][(p * 32 + rS) * 64 + (cS ^ kxw)] = gV[p];
        }
    };
    auto COMPUTE = [&](int buf) {
        f32x4 s[2][4] = {};
        __builtin_amdgcn_s_setprio(1);
#pragma unroll
        for (int nf = 0; nf < 4; ++nf) {
            const int base = krow[nf] * 64;
            bf16x8 kf0 = *(const bf16x8*)&SMEM[buf][0][base + ((lhi * 8) ^ kx)];
            bf16x8 kf1 = *(const bf16x8*)&SMEM[buf][0][base + ((32 + lhi * 8) ^ kx)];
#pragma unroll
            for (int qi = 0; qi < 2; ++qi) {
                s[qi][nf] = __builtin_amdgcn_mfma_f32_16x16x32_bf16(kf0, qf[qi][0], s[qi][nf], 0, 0, 0);
                s[qi][nf] = __builtin_amdgcn_mfma_f32_16x16x32_bf16(kf1, qf[qi][1], s[qi][nf], 0, 0, 0);
            }
        }
        __builtin_amdgcn_s_setprio(0);
        unsigned pw[2][8];
#pragma unroll
        for (int qi = 0; qi < 2; ++qi)
#pragma unroll
            for (int nf = 0; nf < 4; ++nf) {
                float p0 = fexp2(s[qi][nf][0]);
                float p1 = fexp2(s[qi][nf][1]);
                float p2 = fexp2(s[qi][nf][2]);
                float p3 = fexp2(s[qi][nf][3]);
                pw[qi][nf * 2]     = cvtpk_bf16(p0, p1);
                pw[qi][nf * 2 + 1] = cvtpk_bf16(p2, p3);
            }
        __builtin_amdgcn_s_setprio(1);
#pragma unroll
        for (int kk = 0; kk < 2; ++kk) {
            bf16x8 pb[2];
#pragma unroll
            for (int qi = 0; qi < 2; ++qi) {
                int4v w = { (int)pw[qi][kk * 4], (int)pw[qi][kk * 4 + 1],
                            (int)pw[qi][kk * 4 + 2], (int)pw[qi][kk * 4 + 3] };
                pb[qi] = __builtin_bit_cast(bf16x8, w);
                psum[qi] = __builtin_amdgcn_mfma_f32_16x16x32_bf16(onesv, pb[qi], psum[qi], 0, 0, 0);
            }
#pragma unroll
            for (int df = 0; df < 4; ++df) {
                bf16x8 vf = *(const bf16x8*)&SMEM[buf][1][(df * 16 + lr) * 64 + ((kk * 32 + lhi * 8) ^ vx)];
                o[0][df] = __builtin_amdgcn_mfma_f32_16x16x32_bf16(vf, pb[0], o[0][df], 0, 0, 0);
                o[1][df] = __builtin_amdgcn_mfma_f32_16x16x32_bf16(vf, pb[1], o[1][df], 0, 0, 0);
            }
        }
        __builtin_amdgcn_s_setprio(0);
    };

    const int nt = SK >> 6;
    LOADG(0);
    STORES(0);
    if (nt > 1) LOADG(64);
    __syncthreads();
    for (int t = 0; t < nt; ++t) {
        COMPUTE(t & 1);
        if (t + 1 < nt) {
            STORES((t + 1) & 1);
            if (t + 2 < nt) LOADG((t + 2) << 6);
        }
        __syncthreads();
    }

    // epilogue: per-wave O^T -> O transpose through LDS (one-time), coalesced store
    bf16* T = &SMEM[0][0][0] + wave * (32 * 72);   // 2304 elems/wave, stride-72 pad
#pragma unroll
    for (int qi = 0; qi < 2; ++qi) {
        const float inv = 1.0f / psum[qi][0];      // all rows of psum equal
#pragma unroll
        for (int df = 0; df < 4; ++df)
#pragma unroll
            for (int r = 0; r < 4; ++r)
                T[(qi * 16 + lr) * 72 + df * 16 + lhi * 4 + r] = (bf16)(o[qi][df][r] * inv);
    }
#pragma unroll
    for (int pp = 0; pp < 4; ++pp) {
        const int r32 = pp * 8 + (lane >> 3), ch = (lane & 7) * 8;
        bf16x8 v = *(const bf16x8*)&T[r32 * 72 + ch];
        *(bf16x8*)(Ob + ((size_t)b * SQ + q0 + wave * 32 + r32) * H_DIM + h * HD + ch) = v;
    }
}

extern "C" void kernel_launch(void* const* d_in, const int* in_sizes, int n_in,
                              void* d_out, int out_size, void* d_ws, size_t ws_size,
                              hipStream_t stream) {
    const float* x    = (const float*)d_in[0];
    const float* img  = (const float*)d_in[1];
    const float* W_sq = (const float*)d_in[2];   const float* b_sq = (const float*)d_in[3];
    const float* W_sk = (const float*)d_in[4];   const float* b_sk = (const float*)d_in[5];
    const float* W_sv = (const float*)d_in[6];   const float* b_sv = (const float*)d_in[7];
    const float* W_so = (const float*)d_in[8];   const float* b_so = (const float*)d_in[9];
    const float* W_cq = (const float*)d_in[10];  const float* b_cq = (const float*)d_in[11];
    const float* W_ck = (const float*)d_in[12];  const float* b_ck = (const float*)d_in[13];
    const float* W_cv = (const float*)d_in[14];  const float* b_cv = (const float*)d_in[15];
    const float* W_co = (const float*)d_in[16];  const float* b_co = (const float*)d_in[17];
    const float* W_f1 = (const float*)d_in[18];  const float* b_f1 = (const float*)d_in[19];
    const float* W_f2 = (const float*)d_in[20];  const float* b_f2 = (const float*)d_in[21];
    const float* g1 = (const float*)d_in[22];    const float* bb1 = (const float*)d_in[23];
    const float* g2 = (const float*)d_in[24];    const float* bb2 = (const float*)d_in[25];
    const float* g3 = (const float*)d_in[26];    const float* bb3 = (const float*)d_in[27];

    char* ws = (char*)d_ws;
    const size_t MB = 1ull << 20;
    bf16* WT   = (bf16*)ws;
    bf16* w_sq = WT + 0 * (1u << 20);   // sq,sk,sv contiguous -> fused QKV weight [3072][1024]
    bf16* w_sk = WT + 1 * (1u << 20);
    bf16* w_sv = WT + 2 * (1u << 20);
    bf16* w_so = WT + 3 * (1u << 20);
    bf16* w_cq = WT + 4 * (1u << 20);
    bf16* w_ck = WT + 5 * (1u << 20);   // ck,cv contiguous -> fused KV weight [2048][1024]
    bf16* w_cv = WT + 6 * (1u << 20);
    bf16* w_co = WT + 7 * (1u << 20);
    bf16* w_f1 = WT + 8 * (1u << 20);   // [4096][1024]
    bf16* w_f2 = WT + 12 * (1u << 20);  // [1024][4096]
    float* XR  = (float*)(ws + 32 * MB);
    bf16* NX   = (bf16*)(ws + 48 * MB);
    bf16* Qb   = (bf16*)(ws + 56 * MB);
    bf16* Kb   = (bf16*)(ws + 64 * MB);
    bf16* Vt   = (bf16*)(ws + 72 * MB);  // [b][h][d][s]
    bf16* FF   = (bf16*)(ws + 56 * MB);  // reused after attention
    bf16* IMGB = (bf16*)(ws + 88 * MB);

    const dim3 blk(256);

    WPtrs wp;
    wp.w[0] = W_sq; wp.o[0] = w_sq;  wp.w[1] = W_sk; wp.o[1] = w_sk;
    wp.w[2] = W_sv; wp.o[2] = w_sv;  wp.w[3] = W_so; wp.o[3] = w_so;
    wp.w[4] = W_cq; wp.o[4] = w_cq;  wp.w[5] = W_ck; wp.o[5] = w_ck;
    wp.w[6] = W_cv; wp.o[6] = w_cv;  wp.w[7] = W_co; wp.o[7] = w_co;
    wconv8_kernel<<<dim3(16, 16, 8), blk, 0, stream>>>(wp);
    wconv_kernel<<<dim3(64, 16), blk, 0, stream>>>(W_f1, w_f1, 1024, 4096);
    wconv_kernel<<<dim3(16, 64), blk, 0, stream>>>(W_f2, w_f2, 4096, 1024);

    // ---- self attention ----
    ln_kernel<<<4096, blk, 0, stream>>>(x, 0.1f, g1, bb1, NX);
    gemm_kernel<128, 128, 1, true, false, false><<<dim3(24, 32), blk, 0, stream>>>(
        NX, w_sq, b_sq, b_sk, b_sv, nullptr, Qb, Kb, Vt, 4096, 3072, 1024, 0.f, QSCL, 11);
    attn_kernel<<<dim3(32, 16), blk, 0, stream>>>(Qb, Kb, Vt, NX, 2048, 2048);
    gemm_kernel<64, 128, 0, false, false, true><<<dim3(8, 64), blk, 0, stream>>>(
        NX, w_so, b_so, nullptr, nullptr, x, XR, nullptr, nullptr, 4096, 1024, 1024, 0.1f, 1.f, 0);

    // ---- cross attention ----
    ln_kernel<<<4096, blk, 0, stream>>>(XR, 1.f, g2, bb2, NX);
    gemm_kernel<64, 128, 0, true, false, false><<<dim3(8, 64), blk, 0, stream>>>(
        NX, w_cq, b_cq, nullptr, nullptr, nullptr, Qb, nullptr, nullptr, 4096, 1024, 1024, 0.f, QSCL, 0);
    cvt_scale_kernel<<<dim3(512), blk, 0, stream>>>(img, IMGB, 0.1f, 131072);
    gemm_kernel<64, 128, 2, true, false, false><<<dim3(16, 8), blk, 0, stream>>>(
        IMGB, w_ck, b_ck, b_cv, nullptr, nullptr, Kb, Vt, nullptr, 512, 2048, 1024, 0.f, 1.f, 8);
    attn_kernel<<<dim3(32, 16), blk, 0, stream>>>(Qb, Kb, Vt, NX, 2048, 256);
    gemm_kernel<64, 128, 0, false, false, true><<<dim3(8, 64), blk, 0, stream>>>(
        NX, w_co, b_co, nullptr, nullptr, XR, XR, nullptr, nullptr, 4096, 1024, 1024, 1.f, 1.f, 0);

    // ---- feed forward ----
    ln_kernel<<<4096, blk, 0, stream>>>(XR, 1.f, g3, bb3, NX);
    gemm_kernel<128, 128, 0, true, true, false><<<dim3(32, 32), blk, 0, stream>>>(
        NX, w_f1, b_f1, nullptr, nullptr, nullptr, FF, nullptr, nullptr, 4096, 4096, 1024, 0.f, 1.f, 0);
    gemm_kernel<64, 128, 0, false, false, true><<<dim3(8, 64), blk, 0, stream>>>(
        FF, w_f2, b_f2, nullptr, nullptr, XR, d_out, nullptr, nullptr, 4096, 1024, 4096, 1.f, 10.f, 0);
}

// Round 17
// 284.703 us; speedup vs baseline: 1.1374x; 1.1374x over previous
//
#include <hip/hip_runtime.h>
#include <hip/hip_bf16.h>

typedef __bf16 bf16;
typedef __bf16 bf16x4 __attribute__((ext_vector_type(4)));
typedef __bf16 bf16x8 __attribute__((ext_vector_type(8)));
typedef float  f32x4  __attribute__((ext_vector_type(4)));
typedef float  f32x16 __attribute__((ext_vector_type(16)));
typedef int    int4v  __attribute__((ext_vector_type(4)));

#define H_DIM 1024
#define NHEAD 16
#define HD    64
// SCALE * log2(e), folded into Q-projection epilogue; attn softmax runs in base-2
#define QSCL 0.18033688011112042f

__device__ __forceinline__ void gload_lds16(const bf16* g, bf16* l) {
    __builtin_amdgcn_global_load_lds((const __attribute__((address_space(1))) void*)g,
                                     (__attribute__((address_space(3))) void*)l, 16, 0, 0);
}

__device__ __forceinline__ unsigned cvtpk_bf16(float lo, float hi) {
    unsigned r;
    asm volatile("v_cvt_pk_bf16_f32 %0, %1, %2" : "=v"(r) : "v"(lo), "v"(hi));
    return r;
}

// single-instruction 2^x (v_exp_f32); plain exp2f lowers to the multi-instr libm path
__device__ __forceinline__ float fexp2(float x) {
    float r;
    asm("v_exp_f32 %0, %1" : "=v"(r) : "v"(x));
    return r;
}

// ---------------- weight fp32 [K][N] -> bf16 [N][K] (transpose+convert) ----------------
__device__ __forceinline__ void wconv_body(const float* __restrict__ W,
                                           bf16* __restrict__ Wt, int K, int N,
                                           int bx, int by, int t) {
    __shared__ float tile[64][65];
    const int n0 = bx * 64, k0 = by * 64;
#pragma unroll
    for (int p = 0; p < 4; ++p) {
        int lin = p * 1024 + t * 4;
        int r = lin >> 6, c = lin & 63;
        f32x4 v = *(const f32x4*)(W + (size_t)(k0 + r) * N + n0 + c);
        tile[r][c]     = v[0];
        tile[r][c + 1] = v[1];
        tile[r][c + 2] = v[2];
        tile[r][c + 3] = v[3];
    }
    __syncthreads();
#pragma unroll
    for (int p = 0; p < 4; ++p) {
        int lin = p * 1024 + t * 4;
        int rn = lin >> 6, ck = lin & 63;
        bf16x4 o;
#pragma unroll
        for (int j = 0; j < 4; ++j) o[j] = (bf16)tile[ck + j][rn];
        *(bf16x4*)(Wt + (size_t)(n0 + rn) * K + k0 + ck) = o;
    }
}

__global__ __launch_bounds__(256) void wconv_kernel(const float* __restrict__ W,
                                                    bf16* __restrict__ Wt,
                                                    int K, int N) {
    wconv_body(W, Wt, K, N, blockIdx.x, blockIdx.y, threadIdx.x);
}

struct WPtrs { const float* w[8]; bf16* o[8]; };
__global__ __launch_bounds__(256) void wconv8_kernel(WPtrs p) {
    const int m = blockIdx.z;
    wconv_body(p.w[m], p.o[m], 1024, 1024, blockIdx.x, blockIdx.y, threadIdx.x);
}

// ---------------- layernorm (fp32 in, bf16 out), one row per block ----------------
__global__ __launch_bounds__(256) void ln_kernel(const float* __restrict__ in, float inScale,
                                                 const float* __restrict__ g,
                                                 const float* __restrict__ b,
                                                 bf16* __restrict__ out) {
    const int row = blockIdx.x, t = threadIdx.x;
    const float* p = in + (size_t)row * H_DIM;
    f32x4 v = *(const f32x4*)(p + t * 4);
    v *= inScale;
    float s1 = v[0] + v[1] + v[2] + v[3];
    float s2 = v[0] * v[0] + v[1] * v[1] + v[2] * v[2] + v[3] * v[3];
#pragma unroll
    for (int m = 1; m < 64; m <<= 1) {
        s1 += __shfl_xor(s1, m);
        s2 += __shfl_xor(s2, m);
    }
    __shared__ float red[8];
    const int wave = t >> 6;
    if ((t & 63) == 0) { red[wave * 2] = s1; red[wave * 2 + 1] = s2; }
    __syncthreads();
    s1 = red[0] + red[2] + red[4] + red[6];
    s2 = red[1] + red[3] + red[5] + red[7];
    float mean = s1 * (1.0f / H_DIM);
    float var  = s2 * (1.0f / H_DIM) - mean * mean;
    float inv  = rsqrtf(var + 1e-5f);
    f32x4 gg = *(const f32x4*)(g + t * 4);
    f32x4 bb = *(const f32x4*)(b + t * 4);
    bf16x4 o;
#pragma unroll
    for (int j = 0; j < 4; ++j) o[j] = (bf16)((v[j] - mean) * inv * gg[j] + bb[j]);
    *(bf16x4*)(out + (size_t)row * H_DIM + t * 4) = o;
}

// ---------------- fp32 -> bf16 with scale ----------------
__global__ __launch_bounds__(256) void cvt_scale_kernel(const float* __restrict__ in,
                                                        bf16* __restrict__ out,
                                                        float s, int n4) {
    int i = blockIdx.x * 256 + threadIdx.x;
    if (i < n4) {
        f32x4 v = *(const f32x4*)(in + (size_t)i * 4);
        bf16x4 o;
#pragma unroll
        for (int j = 0; j < 4; ++j) o[j] = (bf16)(v[j] * s);
        *(bf16x4*)(out + (size_t)i * 4) = o;
    }
}

// ---------------- GEMM v5: dbuf + COUNTED vmcnt (T4) -- prefetch stays in flight ----
// R15 structure (double-buffered global_load_lds, 32x32x16 MFMA, XOR swizzle, T1) but
// the per-iter __syncthreads (vmcnt(0) drain) is replaced by:
//   stage(next); s_waitcnt vmcnt(CHUNKS);  // old tile only; prefetch NOT drained
//   s_barrier;  compute(buf);  s_barrier;  // 2nd barrier protects next overwrite
// C/D: col = lane&31, row = (reg&3) + 8*(reg>>2) + 4*(lane>>5)
// MODE 0: plain epilogue -> o1; MODE 1: QKV fused; MODE 2: KV fused
// V-transposed layout: [b][h][d][s], s = row & (2^slog2 - 1)
template <int BM, int BN, int MODE, bool OUT_BF16, bool GELU_EPI, bool HAS_RES>
__global__ __launch_bounds__(256) void gemm_kernel(const bf16* __restrict__ A,
                                                   const bf16* __restrict__ Bt,
                                                   const float* __restrict__ bias1,
                                                   const float* __restrict__ bias2,
                                                   const float* __restrict__ bias3,
                                                   const float* __restrict__ res,
                                                   void* __restrict__ o1, void* __restrict__ o2,
                                                   void* __restrict__ o3,
                                                   int M, int N, int K,
                                                   float resScale, float outScale, int slog2) {
    constexpr int CHUNKS = (BM + BN) / 32;       // 32-row x 64-col staging chunks
    constexpr int WRR = BM / 2, WCC = BN / 2;    // per-wave sub-tile (2x2 wave grid)
    constexpr int MI = WRR / 32, NJ = WCC / 32;  // 32x32 fragments per wave
    __shared__ bf16 SM[2][(BM + BN) * 64];       // linear (gload_lds dest), A then B
    // T1: bijective XCD swizzle (all grids here are %8==0)
    const int nwg = gridDim.x * gridDim.y;
    const int dlin = blockIdx.y * gridDim.x + blockIdx.x;
    const int id = (dlin & 7) * (nwg >> 3) + (dlin >> 3);
    const int bx = id % gridDim.x, by = id / gridDim.x;
    const int m0 = by * BM, n0 = bx * BN;
    const int tid = threadIdx.x;
    const int wave = tid >> 6, lane = tid & 63;
    const int l31 = lane & 31, l5 = lane >> 5;
    const int wr = wave >> 1, wc = wave & 1;
    const int sr = lane >> 3, sc8 = (lane & 7) * 8;
    const int sc8x = sc8 ^ (sr << 3);            // pre-swizzled source col (involution)
    const int rxr = (l31 & 7) << 3;              // read-side XOR (row&7 == l31&7)

    f32x16 acc[MI][NJ] = {};

    auto stage = [&](int buf, int k0) {
#pragma unroll
        for (int p = 0; p < CHUNKS; ++p) {
            const int rr = p * 32 + wave * 8 + sr;
            bf16* l = &SM[buf][0] + p * 2048 + wave * 512;   // wave-uniform base
            const bf16* g = (p < BM / 32)
                ? (A  + (size_t)(m0 + rr) * K + k0 + sc8x)
                : (Bt + (size_t)(n0 + rr - BM) * K + k0 + sc8x);
            gload_lds16(g, l);
        }
    };

    stage(0, 0);
    int buf = 0;
    for (int k0 = 0; k0 < K; k0 += 64) {
        const bool pre = (k0 + 64 < K);
        if (pre) {
            stage(buf ^ 1, k0 + 64);             // issue prefetch first
            asm volatile("s_waitcnt vmcnt(%0)" :: "i"(CHUNKS) : "memory");  // old tile only
        } else {
            asm volatile("s_waitcnt vmcnt(0)" ::: "memory");
        }
        __builtin_amdgcn_sched_barrier(0);       // rule #18: pin MFMA after the wait
        __builtin_amdgcn_s_barrier();            // all waves: buf resident
#pragma unroll
        for (int kk = 0; kk < 4; ++kk) {            // K=16 per MFMA
            const int sa = (kk * 16 + l5 * 8) ^ rxr;
            bf16x8 af[MI], bfr[NJ];
#pragma unroll
            for (int i = 0; i < MI; ++i)
                af[i] = *(const bf16x8*)&SM[buf][(wr * WRR + i * 32 + l31) * 64 + sa];
#pragma unroll
            for (int j = 0; j < NJ; ++j)
                bfr[j] = *(const bf16x8*)&SM[buf][(BM + wc * WCC + j * 32 + l31) * 64 + sa];
#pragma unroll
            for (int i = 0; i < MI; ++i)
#pragma unroll
                for (int j = 0; j < NJ; ++j)
                    acc[i][j] = __builtin_amdgcn_mfma_f32_32x32x16_bf16(af[i], bfr[j], acc[i][j], 0, 0, 0);
        }
        __builtin_amdgcn_s_barrier();            // all waves done reading buf (next overwrite)
        buf ^= 1;
    }

#pragma unroll
    for (int i = 0; i < MI; ++i) {
#pragma unroll
        for (int j = 0; j < NJ; ++j) {
            const int col = n0 + wc * WCC + j * 32 + l31;
            const int rbase = m0 + wr * WRR + i * 32 + l5 * 4;
            if (MODE == 0) {
                const float bv = bias1[col];
#pragma unroll
                for (int rq = 0; rq < 4; ++rq)
#pragma unroll
                    for (int rr = 0; rr < 4; ++rr) {
                        const int row = rbase + rq * 8 + rr;
                        const size_t idx = (size_t)row * N + col;
                        float v = acc[i][j][rq * 4 + rr] + bv;
                        if (HAS_RES) v += res[idx] * resScale;
                        if (GELU_EPI) v = 0.5f * v * (1.0f + erff(v * 0.70710678118654752f));
                        v *= outScale;
                        if (OUT_BF16) ((bf16*)o1)[idx] = (bf16)v;
                        else          ((float*)o1)[idx] = v;
                    }
            } else {
                const int sec = col >> 10, cl = col & 1023;
                const bool isV = (MODE == 1) ? (sec == 2) : (sec == 1);
                const float* bp = (MODE == 1) ? (sec == 0 ? bias1 : sec == 1 ? bias2 : bias3)
                                              : (sec == 0 ? bias1 : bias2);
                const float bv = bp[cl];
                if (!isV) {
                    bf16* dst = (MODE == 1) ? (sec == 0 ? (bf16*)o1 : (bf16*)o2) : (bf16*)o1;
                    const float sc = (MODE == 1 && sec == 0) ? outScale : 1.f;
#pragma unroll
                    for (int rq = 0; rq < 4; ++rq)
#pragma unroll
                        for (int rr = 0; rr < 4; ++rr) {
                            const int row = rbase + rq * 8 + rr;
                            dst[(size_t)row * H_DIM + cl] = (bf16)((acc[i][j][rq * 4 + rr] + bv) * sc);
                        }
                } else {
                    bf16* dst = (MODE == 1) ? (bf16*)o3 : (bf16*)o2;
                    const int S = 1 << slog2;
                    const int hI = cl >> 6, dI = cl & 63;
#pragma unroll
                    for (int rq = 0; rq < 4; ++rq) {
                        const int row0 = rbase + rq * 8;       // 4 consecutive rows
                        const int bI = row0 >> slog2, s0 = row0 & (S - 1);
                        bf16x4 ov;
#pragma unroll
                        for (int rr = 0; rr < 4; ++rr) ov[rr] = (bf16)(acc[i][j][rq * 4 + rr] + bv);
                        *(bf16x4*)(dst + ((size_t)((bI * NHEAD + hI) * HD + dI)) * S + s0) = ov;
                    }
                }
            }
        }
    }
}

// ---------------- flash attention v10 (unchanged): raw v_exp_f32 + setprio ----------------
__global__ __launch_bounds__(256) void attn_kernel(const bf16* __restrict__ Qb,
                                                   const bf16* __restrict__ Kb,
                                                   const bf16* __restrict__ Vt_g,
                                                   bf16* __restrict__ Ob,
                                                   int SQ, int SK) {
    __shared__ bf16 SMEM[2][2][64 * 64];         // [buf][K|V][4096]; reused for O-transpose
    const int nwg = gridDim.x * gridDim.y;
    const int dlin = blockIdx.y * gridDim.x + blockIdx.x;
    const int id = (dlin & 7) * (nwg >> 3) + (dlin >> 3);
    const int NQ = gridDim.y;
    const int bh = id / NQ, qt = id - bh * NQ;
    const int b = bh >> 4, h = bh & 15;
    const int q0 = qt * 128;
    const int tid = threadIdx.x, wave = tid >> 6, lane = tid & 63;
    const int lr = lane & 15, lhi = lane >> 4;

    bf16x8 qf[2][2];
#pragma unroll
    for (int qi = 0; qi < 2; ++qi) {
        const bf16* qp = Qb + ((size_t)b * SQ + q0 + wave * 32 + qi * 16 + lr) * H_DIM + h * HD;
        qf[qi][0] = *(const bf16x8*)(qp + lhi * 8);
        qf[qi][1] = *(const bf16x8*)(qp + 32 + lhi * 8);
    }

    const int kx = (((lr & 3) | (((lr >> 2) & 1) << 2)) << 3);
    const int vx = (((lr & 3) | (((lr >> 3) & 1) << 2)) << 3);
    int krow[4];
#pragma unroll
    for (int nf = 0; nf < 4; ++nf)
        krow[nf] = (nf >> 1) * 32 + (lr >> 2) * 8 + (nf & 1) * 4 + (lr & 3);

    const int rS = tid >> 3, cS = (tid & 7) * 8;
    const int kxw = (((rS & 3) | (((rS >> 3) & 1) << 2)) << 3);
    const bf16* Kg = Kb + (size_t)b * SK * H_DIM + h * HD;
    const bf16* Vg = Vt_g + (size_t)bh * 64 * SK;

    bf16x8 onesv;
#pragma unroll
    for (int j = 0; j < 8; ++j) onesv[j] = (bf16)1.0f;

    f32x4 o[2][4] = {};
    f32x4 psum[2] = {};
    bf16x8 gK[2], gV[2];

    auto LOADG = [&](int kb) {
#pragma unroll
        for (int p = 0; p < 2; ++p) {
            gK[p] = *(const bf16x8*)(Kg + (size_t)(kb + p * 32 + rS) * H_DIM + cS);
            gV[p] = *(const bf16x8*)(Vg + (size_t)(p * 32 + rS) * SK + kb + cS);
        }
    };
    auto STORES = [&](int buf) {
#pragma unroll
        for (int p = 0; p < 2; ++p) {
            *(bf16x8*)&SMEM[buf][0][(p * 32 + rS) * 64 + (cS ^ kxw)] = gK[p];
            *(bf16x8*)&SMEM[buf][1][(p * 32 + rS) * 64 + (cS ^ kxw)] = gV[p];
        }
    };
    auto COMPUTE = [&](int buf) {
        f32x4 s[2][4] = {};
        __builtin_amdgcn_s_setprio(1);
#pragma unroll
        for (int nf = 0; nf < 4; ++nf) {
            const int base = krow[nf] * 64;
            bf16x8 kf0 = *(const bf16x8*)&SMEM[buf][0][base + ((lhi * 8) ^ kx)];
            bf16x8 kf1 = *(const bf16x8*)&SMEM[buf][0][base + ((32 + lhi * 8) ^ kx)];
#pragma unroll
            for (int qi = 0; qi < 2; ++qi) {
                s[qi][nf] = __builtin_amdgcn_mfma_f32_16x16x32_bf16(kf0, qf[qi][0], s[qi][nf], 0, 0, 0);
                s[qi][nf] = __builtin_amdgcn_mfma_f32_16x16x32_bf16(kf1, qf[qi][1], s[qi][nf], 0, 0, 0);
            }
        }
        __builtin_amdgcn_s_setprio(0);
        unsigned pw[2][8];
#pragma unroll
        for (int qi = 0; qi < 2; ++qi)
#pragma unroll
            for (int nf = 0; nf < 4; ++nf) {
                float p0 = fexp2(s[qi][nf][0]);
                float p1 = fexp2(s[qi][nf][1]);
                float p2 = fexp2(s[qi][nf][2]);
                float p3 = fexp2(s[qi][nf][3]);
                pw[qi][nf * 2]     = cvtpk_bf16(p0, p1);
                pw[qi][nf * 2 + 1] = cvtpk_bf16(p2, p3);
            }
        __builtin_amdgcn_s_setprio(1);
#pragma unroll
        for (int kk = 0; kk < 2; ++kk) {
            bf16x8 pb[2];
#pragma unroll
            for (int qi = 0; qi < 2; ++qi) {
                int4v w = { (int)pw[qi][kk * 4], (int)pw[qi][kk * 4 + 1],
                            (int)pw[qi][kk * 4 + 2], (int)pw[qi][kk * 4 + 3] };
                pb[qi] = __builtin_bit_cast(bf16x8, w);
                psum[qi] = __builtin_amdgcn_mfma_f32_16x16x32_bf16(onesv, pb[qi], psum[qi], 0, 0, 0);
            }
#pragma unroll
            for (int df = 0; df < 4; ++df) {
                bf16x8 vf = *(const bf16x8*)&SMEM[buf][1][(df * 16 + lr) * 64 + ((kk * 32 + lhi * 8) ^ vx)];
                o[0][df] = __builtin_amdgcn_mfma_f32_16x16x32_bf16(vf, pb[0], o[0][df], 0, 0, 0);
                o[1][df] = __builtin_amdgcn_mfma_f32_16x16x32_bf16(vf, pb[1], o[1][df], 0, 0, 0);
            }
        }
        __builtin_amdgcn_s_setprio(0);
    };

    const int nt = SK >> 6;
    LOADG(0);
    STORES(0);
    if (nt > 1) LOADG(64);
    __syncthreads();
    for (int t = 0; t < nt; ++t) {
        COMPUTE(t & 1);
        if (t + 1 < nt) {
            STORES((t + 1) & 1);
            if (t + 2 < nt) LOADG((t + 2) << 6);
        }
        __syncthreads();
    }

    // epilogue: per-wave O^T -> O transpose through LDS (one-time), coalesced store
    bf16* T = &SMEM[0][0][0] + wave * (32 * 72);   // 2304 elems/wave, stride-72 pad
#pragma unroll
    for (int qi = 0; qi < 2; ++qi) {
        const float inv = 1.0f / psum[qi][0];      // all rows of psum equal
#pragma unroll
        for (int df = 0; df < 4; ++df)
#pragma unroll
            for (int r = 0; r < 4; ++r)
                T[(qi * 16 + lr) * 72 + df * 16 + lhi * 4 + r] = (bf16)(o[qi][df][r] * inv);
    }
#pragma unroll
    for (int pp = 0; pp < 4; ++pp) {
        const int r32 = pp * 8 + (lane >> 3), ch = (lane & 7) * 8;
        bf16x8 v = *(const bf16x8*)&T[r32 * 72 + ch];
        *(bf16x8*)(Ob + ((size_t)b * SQ + q0 + wave * 32 + r32) * H_DIM + h * HD + ch) = v;
    }
}

extern "C" void kernel_launch(void* const* d_in, const int* in_sizes, int n_in,
                              void* d_out, int out_size, void* d_ws, size_t ws_size,
                              hipStream_t stream) {
    const float* x    = (const float*)d_in[0];
    const float* img  = (const float*)d_in[1];
    const float* W_sq = (const float*)d_in[2];   const float* b_sq = (const float*)d_in[3];
    const float* W_sk = (const float*)d_in[4];   const float* b_sk = (const float*)d_in[5];
    const float* W_sv = (const float*)d_in[6];   const float* b_sv = (const float*)d_in[7];
    const float* W_so = (const float*)d_in[8];   const float* b_so = (const float*)d_in[9];
    const float* W_cq = (const float*)d_in[10];  const float* b_cq = (const float*)d_in[11];
    const float* W_ck = (const float*)d_in[12];  const float* b_ck = (const float*)d_in[13];
    const float* W_cv = (const float*)d_in[14];  const float* b_cv = (const float*)d_in[15];
    const float* W_co = (const float*)d_in[16];  const float* b_co = (const float*)d_in[17];
    const float* W_f1 = (const float*)d_in[18];  const float* b_f1 = (const float*)d_in[19];
    const float* W_f2 = (const float*)d_in[20];  const float* b_f2 = (const float*)d_in[21];
    const float* g1 = (const float*)d_in[22];    const float* bb1 = (const float*)d_in[23];
    const float* g2 = (const float*)d_in[24];    const float* bb2 = (const float*)d_in[25];
    const float* g3 = (const float*)d_in[26];    const float* bb3 = (const float*)d_in[27];

    char* ws = (char*)d_ws;
    const size_t MB = 1ull << 20;
    bf16* WT   = (bf16*)ws;
    bf16* w_sq = WT + 0 * (1u << 20);   // sq,sk,sv contiguous -> fused QKV weight [3072][1024]
    bf16* w_sk = WT + 1 * (1u << 20);
    bf16* w_sv = WT + 2 * (1u << 20);
    bf16* w_so = WT + 3 * (1u << 20);
    bf16* w_cq = WT + 4 * (1u << 20);
    bf16* w_ck = WT + 5 * (1u << 20);   // ck,cv contiguous -> fused KV weight [2048][1024]
    bf16* w_cv = WT + 6 * (1u << 20);
    bf16* w_co = WT + 7 * (1u << 20);
    bf16* w_f1 = WT + 8 * (1u << 20);   // [4096][1024]
    bf16* w_f2 = WT + 12 * (1u << 20);  // [1024][4096]
    float* XR  = (float*)(ws + 32 * MB);
    bf16* NX   = (bf16*)(ws + 48 * MB);
    bf16* Qb   = (bf16*)(ws + 56 * MB);
    bf16* Kb   = (bf16*)(ws + 64 * MB);
    bf16* Vt   = (bf16*)(ws + 72 * MB);  // [b][h][d][s]
    bf16* FF   = (bf16*)(ws + 56 * MB);  // reused after attention
    bf16* IMGB = (bf16*)(ws + 88 * MB);

    const dim3 blk(256);

    WPtrs wp;
    wp.w[0] = W_sq; wp.o[0] = w_sq;  wp.w[1] = W_sk; wp.o[1] = w_sk;
    wp.w[2] = W_sv; wp.o[2] = w_sv;  wp.w[3] = W_so; wp.o[3] = w_so;
    wp.w[4] = W_cq; wp.o[4] = w_cq;  wp.w[5] = W_ck; wp.o[5] = w_ck;
    wp.w[6] = W_cv; wp.o[6] = w_cv;  wp.w[7] = W_co; wp.o[7] = w_co;
    wconv8_kernel<<<dim3(16, 16, 8), blk, 0, stream>>>(wp);
    wconv_kernel<<<dim3(64, 16), blk, 0, stream>>>(W_f1, w_f1, 1024, 4096);
    wconv_kernel<<<dim3(16, 64), blk, 0, stream>>>(W_f2, w_f2, 4096, 1024);

    // ---- self attention ----
    ln_kernel<<<4096, blk, 0, stream>>>(x, 0.1f, g1, bb1, NX);
    gemm_kernel<128, 128, 1, true, false, false><<<dim3(24, 32), blk, 0, stream>>>(
        NX, w_sq, b_sq, b_sk, b_sv, nullptr, Qb, Kb, Vt, 4096, 3072, 1024, 0.f, QSCL, 11);
    attn_kernel<<<dim3(32, 16), blk, 0, stream>>>(Qb, Kb, Vt, NX, 2048, 2048);
    gemm_kernel<64, 128, 0, false, false, true><<<dim3(8, 64), blk, 0, stream>>>(
        NX, w_so, b_so, nullptr, nullptr, x, XR, nullptr, nullptr, 4096, 1024, 1024, 0.1f, 1.f, 0);

    // ---- cross attention ----
    ln_kernel<<<4096, blk, 0, stream>>>(XR, 1.f, g2, bb2, NX);
    gemm_kernel<64, 128, 0, true, false, false><<<dim3(8, 64), blk, 0, stream>>>(
        NX, w_cq, b_cq, nullptr, nullptr, nullptr, Qb, nullptr, nullptr, 4096, 1024, 1024, 0.f, QSCL, 0);
    cvt_scale_kernel<<<dim3(512), blk, 0, stream>>>(img, IMGB, 0.1f, 131072);
    gemm_kernel<64, 128, 2, true, false, false><<<dim3(16, 8), blk, 0, stream>>>(
        IMGB, w_ck, b_ck, b_cv, nullptr, nullptr, Kb, Vt, nullptr, 512, 2048, 1024, 0.f, 1.f, 8);
    attn_kernel<<<dim3(32, 16), blk, 0, stream>>>(Qb, Kb, Vt, NX, 2048, 256);
    gemm_kernel<64, 128, 0, false, false, true><<<dim3(8, 64), blk, 0, stream>>>(
        NX, w_co, b_co, nullptr, nullptr, XR, XR, nullptr, nullptr, 4096, 1024, 1024, 1.f, 1.f, 0);

    // ---- feed forward ----
    ln_kernel<<<4096, blk, 0, stream>>>(XR, 1.f, g3, bb3, NX);
    gemm_kernel<128, 128, 0, true, true, false><<<dim3(32, 32), blk, 0, stream>>>(
        NX, w_f1, b_f1, nullptr, nullptr, nullptr, FF, nullptr, nullptr, 4096, 4096, 1024, 0.f, 1.f, 0);
    gemm_kernel<64, 128, 0, false, false, true><<<dim3(8, 64), blk, 0, stream>>>(
        FF, w_f2, b_f2, nullptr, nullptr, XR, d_out, nullptr, nullptr, 4096, 1024, 4096, 1.f, 10.f, 0);
}

// Round 18
// 273.495 us; speedup vs baseline: 1.1840x; 1.0410x over previous
//
#include <hip/hip_runtime.h>
#include <hip/hip_bf16.h>

typedef __bf16 bf16;
typedef __bf16 bf16x4 __attribute__((ext_vector_type(4)));
typedef __bf16 bf16x8 __attribute__((ext_vector_type(8)));
typedef float  f32x4  __attribute__((ext_vector_type(4)));
typedef float  f32x16 __attribute__((ext_vector_type(16)));
typedef int    int4v  __attribute__((ext_vector_type(4)));

#define H_DIM 1024
#define NHEAD 16
#define HD    64
// SCALE * log2(e), folded into Q-projection epilogue; attn softmax runs in base-2
#define QSCL 0.18033688011112042f

__device__ __forceinline__ void gload_lds16(const bf16* g, bf16* l) {
    __builtin_amdgcn_global_load_lds((const __attribute__((address_space(1))) void*)g,
                                     (__attribute__((address_space(3))) void*)l, 16, 0, 0);
}
__device__ __forceinline__ void gload_lds16_u8(const unsigned char* g, unsigned char* l) {
    __builtin_amdgcn_global_load_lds((const __attribute__((address_space(1))) void*)g,
                                     (__attribute__((address_space(3))) void*)l, 16, 0, 0);
}

__device__ __forceinline__ unsigned cvtpk_bf16(float lo, float hi) {
    unsigned r;
    asm volatile("v_cvt_pk_bf16_f32 %0, %1, %2" : "=v"(r) : "v"(lo), "v"(hi));
    return r;
}
// pack 2 floats -> 2 e4m3 bytes (low 16 bits of dest)
__device__ __forceinline__ unsigned cvt2_fp8(float a, float b) {
    unsigned r;
    asm volatile("v_cvt_pk_fp8_f32 %0, %1, %2" : "=v"(r) : "v"(a), "v"(b));
    return r & 0xffffu;
}
__device__ __forceinline__ unsigned pack4_fp8(float a, float b, float c, float d) {
    return cvt2_fp8(a, b) | (cvt2_fp8(c, d) << 16);
}

// single-instruction 2^x (v_exp_f32); plain exp2f lowers to the multi-instr libm path
__device__ __forceinline__ float fexp2(float x) {
    float r;
    asm("v_exp_f32 %0, %1" : "=v"(r) : "v"(x));
    return r;
}

// ---------------- weight fp32 [K][N] -> bf16 [N][K] (transpose+convert) ----------------
__device__ __forceinline__ void wconv_body(const float* __restrict__ W,
                                           bf16* __restrict__ Wt, int K, int N,
                                           int bx, int by, int t) {
    __shared__ float tile[64][65];
    const int n0 = bx * 64, k0 = by * 64;
#pragma unroll
    for (int p = 0; p < 4; ++p) {
        int lin = p * 1024 + t * 4;
        int r = lin >> 6, c = lin & 63;
        f32x4 v = *(const f32x4*)(W + (size_t)(k0 + r) * N + n0 + c);
        tile[r][c]     = v[0];
        tile[r][c + 1] = v[1];
        tile[r][c + 2] = v[2];
        tile[r][c + 3] = v[3];
    }
    __syncthreads();
#pragma unroll
    for (int p = 0; p < 4; ++p) {
        int lin = p * 1024 + t * 4;
        int rn = lin >> 6, ck = lin & 63;
        bf16x4 o;
#pragma unroll
        for (int j = 0; j < 4; ++j) o[j] = (bf16)tile[ck + j][rn];
        *(bf16x4*)(Wt + (size_t)(n0 + rn) * K + k0 + ck) = o;
    }
}

__global__ __launch_bounds__(256) void wconv_kernel(const float* __restrict__ W,
                                                    bf16* __restrict__ Wt,
                                                    int K, int N) {
    wconv_body(W, Wt, K, N, blockIdx.x, blockIdx.y, threadIdx.x);
}

struct WPtrs { const float* w[8]; bf16* o[8]; };
__global__ __launch_bounds__(256) void wconv8_kernel(WPtrs p) {
    const int m = blockIdx.z;
    wconv_body(p.w[m], p.o[m], 1024, 1024, blockIdx.x, blockIdx.y, threadIdx.x);
}

// fp8 variant for the QKV weights: out[m] = fp8 [1024][1024] at out + m*1MB
struct W3Ptrs { const float* w[3]; };
__global__ __launch_bounds__(256) void wconv_fp8_kernel(W3Ptrs p, unsigned char* __restrict__ out) {
    __shared__ float tile[64][65];
    const int m = blockIdx.z, t = threadIdx.x;
    const float* W = p.w[m];
    unsigned char* Wt = out + (size_t)m * 1024 * 1024;
    const int n0 = blockIdx.x * 64, k0 = blockIdx.y * 64;
#pragma unroll
    for (int pp = 0; pp < 4; ++pp) {
        int lin = pp * 1024 + t * 4;
        int r = lin >> 6, c = lin & 63;
        f32x4 v = *(const f32x4*)(W + (size_t)(k0 + r) * 1024 + n0 + c);
        tile[r][c]     = v[0];
        tile[r][c + 1] = v[1];
        tile[r][c + 2] = v[2];
        tile[r][c + 3] = v[3];
    }
    __syncthreads();
#pragma unroll
    for (int pp = 0; pp < 4; ++pp) {
        int lin = pp * 1024 + t * 4;
        int rn = lin >> 6, ck = lin & 63;
        unsigned u = pack4_fp8(tile[ck][rn], tile[ck + 1][rn], tile[ck + 2][rn], tile[ck + 3][rn]);
        *(unsigned*)&Wt[(size_t)(n0 + rn) * 1024 + k0 + ck] = u;
    }
}

// ---------------- layernorm (fp32 in, bf16 out), one row per block ----------------
__global__ __launch_bounds__(256) void ln_kernel(const float* __restrict__ in, float inScale,
                                                 const float* __restrict__ g,
                                                 const float* __restrict__ b,
                                                 bf16* __restrict__ out) {
    const int row = blockIdx.x, t = threadIdx.x;
    const float* p = in + (size_t)row * H_DIM;
    f32x4 v = *(const f32x4*)(p + t * 4);
    v *= inScale;
    float s1 = v[0] + v[1] + v[2] + v[3];
    float s2 = v[0] * v[0] + v[1] * v[1] + v[2] * v[2] + v[3] * v[3];
#pragma unroll
    for (int m = 1; m < 64; m <<= 1) {
        s1 += __shfl_xor(s1, m);
        s2 += __shfl_xor(s2, m);
    }
    __shared__ float red[8];
    const int wave = t >> 6;
    if ((t & 63) == 0) { red[wave * 2] = s1; red[wave * 2 + 1] = s2; }
    __syncthreads();
    s1 = red[0] + red[2] + red[4] + red[6];
    s2 = red[1] + red[3] + red[5] + red[7];
    float mean = s1 * (1.0f / H_DIM);
    float var  = s2 * (1.0f / H_DIM) - mean * mean;
    float inv  = rsqrtf(var + 1e-5f);
    f32x4 gg = *(const f32x4*)(g + t * 4);
    f32x4 bb = *(const f32x4*)(b + t * 4);
    bf16x4 o;
#pragma unroll
    for (int j = 0; j < 4; ++j) o[j] = (bf16)((v[j] - mean) * inv * gg[j] + bb[j]);
    *(bf16x4*)(out + (size_t)row * H_DIM + t * 4) = o;
}

// LN with fp8 output (for the QKV GEMM's A operand)
__global__ __launch_bounds__(256) void ln_fp8_kernel(const float* __restrict__ in, float inScale,
                                                     const float* __restrict__ g,
                                                     const float* __restrict__ b,
                                                     unsigned* __restrict__ out) {
    const int row = blockIdx.x, t = threadIdx.x;
    const float* p = in + (size_t)row * H_DIM;
    f32x4 v = *(const f32x4*)(p + t * 4);
    v *= inScale;
    float s1 = v[0] + v[1] + v[2] + v[3];
    float s2 = v[0] * v[0] + v[1] * v[1] + v[2] * v[2] + v[3] * v[3];
#pragma unroll
    for (int m = 1; m < 64; m <<= 1) {
        s1 += __shfl_xor(s1, m);
        s2 += __shfl_xor(s2, m);
    }
    __shared__ float red[8];
    const int wave = t >> 6;
    if ((t & 63) == 0) { red[wave * 2] = s1; red[wave * 2 + 1] = s2; }
    __syncthreads();
    s1 = red[0] + red[2] + red[4] + red[6];
    s2 = red[1] + red[3] + red[5] + red[7];
    float mean = s1 * (1.0f / H_DIM);
    float var  = s2 * (1.0f / H_DIM) - mean * mean;
    float inv  = rsqrtf(var + 1e-5f);
    f32x4 gg = *(const f32x4*)(g + t * 4);
    f32x4 bb = *(const f32x4*)(b + t * 4);
    float y0 = (v[0] - mean) * inv * gg[0] + bb[0];
    float y1 = (v[1] - mean) * inv * gg[1] + bb[1];
    float y2 = (v[2] - mean) * inv * gg[2] + bb[2];
    float y3 = (v[3] - mean) * inv * gg[3] + bb[3];
    out[row * 256 + t] = pack4_fp8(y0, y1, y2, y3);
}

// ---------------- fp32 -> bf16 with scale ----------------
__global__ __launch_bounds__(256) void cvt_scale_kernel(const float* __restrict__ in,
                                                        bf16* __restrict__ out,
                                                        float s, int n4) {
    int i = blockIdx.x * 256 + threadIdx.x;
    if (i < n4) {
        f32x4 v = *(const f32x4*)(in + (size_t)i * 4);
        bf16x4 o;
#pragma unroll
        for (int j = 0; j < 4; ++j) o[j] = (bf16)(v[j] * s);
        *(bf16x4*)(out + (size_t)i * 4) = o;
    }
}

// ---------------- GEMM v5 (bf16): dbuf + counted vmcnt, 32x32x16, XOR swizzle, T1 ----
// C/D: col = lane&31, row = (reg&3) + 8*(reg>>2) + 4*(lane>>5)
// MODE 0: plain epilogue -> o1; MODE 2: KV fused
template <int BM, int BN, int MODE, bool OUT_BF16, bool GELU_EPI, bool HAS_RES>
__global__ __launch_bounds__(256) void gemm_kernel(const bf16* __restrict__ A,
                                                   const bf16* __restrict__ Bt,
                                                   const float* __restrict__ bias1,
                                                   const float* __restrict__ bias2,
                                                   const float* __restrict__ bias3,
                                                   const float* __restrict__ res,
                                                   void* __restrict__ o1, void* __restrict__ o2,
                                                   void* __restrict__ o3,
                                                   int M, int N, int K,
                                                   float resScale, float outScale, int slog2) {
    constexpr int CHUNKS = (BM + BN) / 32;
    constexpr int WRR = BM / 2, WCC = BN / 2;
    constexpr int MI = WRR / 32, NJ = WCC / 32;
    __shared__ bf16 SM[2][(BM + BN) * 64];
    const int nwg = gridDim.x * gridDim.y;
    const int dlin = blockIdx.y * gridDim.x + blockIdx.x;
    const int id = (dlin & 7) * (nwg >> 3) + (dlin >> 3);
    const int bx = id % gridDim.x, by = id / gridDim.x;
    const int m0 = by * BM, n0 = bx * BN;
    const int tid = threadIdx.x;
    const int wave = tid >> 6, lane = tid & 63;
    const int l31 = lane & 31, l5 = lane >> 5;
    const int wr = wave >> 1, wc = wave & 1;
    const int sr = lane >> 3, sc8 = (lane & 7) * 8;
    const int sc8x = sc8 ^ (sr << 3);
    const int rxr = (l31 & 7) << 3;

    f32x16 acc[MI][NJ] = {};

    auto stage = [&](int buf, int k0) {
#pragma unroll
        for (int p = 0; p < CHUNKS; ++p) {
            const int rr = p * 32 + wave * 8 + sr;
            bf16* l = &SM[buf][0] + p * 2048 + wave * 512;
            const bf16* g = (p < BM / 32)
                ? (A  + (size_t)(m0 + rr) * K + k0 + sc8x)
                : (Bt + (size_t)(n0 + rr - BM) * K + k0 + sc8x);
            gload_lds16(g, l);
        }
    };

    stage(0, 0);
    int buf = 0;
    for (int k0 = 0; k0 < K; k0 += 64) {
        const bool pre = (k0 + 64 < K);
        if (pre) {
            stage(buf ^ 1, k0 + 64);
            asm volatile("s_waitcnt vmcnt(%0)" :: "i"(CHUNKS) : "memory");
        } else {
            asm volatile("s_waitcnt vmcnt(0)" ::: "memory");
        }
        __builtin_amdgcn_sched_barrier(0);
        __builtin_amdgcn_s_barrier();
#pragma unroll
        for (int kk = 0; kk < 4; ++kk) {
            const int sa = (kk * 16 + l5 * 8) ^ rxr;
            bf16x8 af[MI], bfr[NJ];
#pragma unroll
            for (int i = 0; i < MI; ++i)
                af[i] = *(const bf16x8*)&SM[buf][(wr * WRR + i * 32 + l31) * 64 + sa];
#pragma unroll
            for (int j = 0; j < NJ; ++j)
                bfr[j] = *(const bf16x8*)&SM[buf][(BM + wc * WCC + j * 32 + l31) * 64 + sa];
#pragma unroll
            for (int i = 0; i < MI; ++i)
#pragma unroll
                for (int j = 0; j < NJ; ++j)
                    acc[i][j] = __builtin_amdgcn_mfma_f32_32x32x16_bf16(af[i], bfr[j], acc[i][j], 0, 0, 0);
        }
        __builtin_amdgcn_s_barrier();
        buf ^= 1;
    }

#pragma unroll
    for (int i = 0; i < MI; ++i) {
#pragma unroll
        for (int j = 0; j < NJ; ++j) {
            const int col = n0 + wc * WCC + j * 32 + l31;
            const int rbase = m0 + wr * WRR + i * 32 + l5 * 4;
            if (MODE == 0) {
                const float bv = bias1[col];
#pragma unroll
                for (int rq = 0; rq < 4; ++rq)
#pragma unroll
                    for (int rr = 0; rr < 4; ++rr) {
                        const int row = rbase + rq * 8 + rr;
                        const size_t idx = (size_t)row * N + col;
                        float v = acc[i][j][rq * 4 + rr] + bv;
                        if (HAS_RES) v += res[idx] * resScale;
                        if (GELU_EPI) v = 0.5f * v * (1.0f + erff(v * 0.70710678118654752f));
                        v *= outScale;
                        if (OUT_BF16) ((bf16*)o1)[idx] = (bf16)v;
                        else          ((float*)o1)[idx] = v;
                    }
            } else {
                const int sec = col >> 10, cl = col & 1023;
                const bool isV = (sec == 1);
                const float bv = (sec == 0 ? bias1 : bias2)[cl];
                if (!isV) {
                    bf16* dst = (bf16*)o1;
#pragma unroll
                    for (int rq = 0; rq < 4; ++rq)
#pragma unroll
                        for (int rr = 0; rr < 4; ++rr) {
                            const int row = rbase + rq * 8 + rr;
                            dst[(size_t)row * H_DIM + cl] = (bf16)(acc[i][j][rq * 4 + rr] + bv);
                        }
                } else {
                    bf16* dst = (bf16*)o2;
                    const int S = 1 << slog2;
                    const int hI = cl >> 6, dI = cl & 63;
#pragma unroll
                    for (int rq = 0; rq < 4; ++rq) {
                        const int row0 = rbase + rq * 8;
                        const int bI = row0 >> slog2, s0 = row0 & (S - 1);
                        bf16x4 ov;
#pragma unroll
                        for (int rr = 0; rr < 4; ++rr) ov[rr] = (bf16)(acc[i][j][rq * 4 + rr] + bv);
                        *(bf16x4*)(dst + ((size_t)((bI * NHEAD + hI) * HD + dI)) * S + s0) = ov;
                    }
                }
            }
        }
    }
}

// ---------------- fp8 QKV GEMM: A8[4096][1024] x W8[3072][1024]^T, 32x32x16 fp8 MFMA ----
// dbuf + counted vmcnt + T1. 8B-granular XOR swizzle: logical 16B-unit v of row r stored
// at linear unit v ^ ((r>>1)&3) (source pre-swizzle; involution; gload_lds-compatible).
// Epilogue = QKV fused: sec0 -> Q*QSCL, sec1 -> K, sec2 -> V transposed [b][h][d][s].
__global__ __launch_bounds__(256) void gemm_qkv_fp8(const unsigned char* __restrict__ A8,
                                                    const unsigned char* __restrict__ B8,
                                                    const float* __restrict__ bias1,
                                                    const float* __restrict__ bias2,
                                                    const float* __restrict__ bias3,
                                                    bf16* __restrict__ Qo, bf16* __restrict__ Ko,
                                                    bf16* __restrict__ Vo) {
    constexpr int Kd = 1024;
    __shared__ unsigned char SM[2][256 * 64];    // 16 KB per buffer
    const int nwg = gridDim.x * gridDim.y;
    const int dlin = blockIdx.y * gridDim.x + blockIdx.x;
    const int id = (dlin & 7) * (nwg >> 3) + (dlin >> 3);
    const int bx = id % gridDim.x, by = id / gridDim.x;
    const int m0 = by * 128, n0 = bx * 128;
    const int tid = threadIdx.x;
    const int wave = tid >> 6, lane = tid & 63;
    const int l31 = lane & 31, l5 = lane >> 5;
    const int wr = wave >> 1, wc = wave & 1;
    const int srow = wave * 16 + (lane >> 2);                 // row within 64-row chunk
    const int sunit = (((lane & 3) ^ ((srow >> 1) & 3)) << 4); // pre-swizzled source byte col
    const int rxc = (l31 >> 1) & 3;                            // read-side XOR class

    f32x16 acc[2][2] = {};

    auto stage = [&](int buf, int k0) {
#pragma unroll
        for (int p = 0; p < 4; ++p) {
            const int rr = p * 64 + srow;
            unsigned char* l = &SM[buf][0] + p * 4096 + wave * 1024;
            const unsigned char* g = (p < 2)
                ? (A8 + (size_t)(m0 + rr) * Kd + k0 + sunit)
                : (B8 + (size_t)(n0 + rr - 128) * Kd + k0 + sunit);
            gload_lds16_u8(g, l);
        }
    };

    stage(0, 0);
    int buf = 0;
    for (int k0 = 0; k0 < Kd; k0 += 64) {
        const bool pre = (k0 + 64 < Kd);
        if (pre) {
            stage(buf ^ 1, k0 + 64);
            asm volatile("s_waitcnt vmcnt(4)" ::: "memory");
        } else {
            asm volatile("s_waitcnt vmcnt(0)" ::: "memory");
        }
        __builtin_amdgcn_sched_barrier(0);
        __builtin_amdgcn_s_barrier();
#pragma unroll
        for (int kk = 0; kk < 4; ++kk) {
            const int sa = (((kk ^ rxc) << 4) + l5 * 8);
            long long af[2], bfr[2];
#pragma unroll
            for (int i = 0; i < 2; ++i)
                af[i] = *(const long long*)&SM[buf][(wr * 64 + i * 32 + l31) * 64 + sa];
#pragma unroll
            for (int j = 0; j < 2; ++j)
                bfr[j] = *(const long long*)&SM[buf][(128 + wc * 64 + j * 32 + l31) * 64 + sa];
#pragma unroll
            for (int i = 0; i < 2; ++i)
#pragma unroll
                for (int j = 0; j < 2; ++j)
                    acc[i][j] = __builtin_amdgcn_mfma_f32_32x32x16_fp8_fp8(af[i], bfr[j], acc[i][j], 0, 0, 0);
        }
        __builtin_amdgcn_s_barrier();
        buf ^= 1;
    }

#pragma unroll
    for (int i = 0; i < 2; ++i) {
#pragma unroll
        for (int j = 0; j < 2; ++j) {
            const int col = n0 + wc * 64 + j * 32 + l31;
            const int rbase = m0 + wr * 64 + i * 32 + l5 * 4;
            const int sec = col >> 10, cl = col & 1023;
            const float bv = (sec == 0 ? bias1 : sec == 1 ? bias2 : bias3)[cl];
            if (sec < 2) {
                bf16* dst = (sec == 0) ? Qo : Ko;
                const float sc = (sec == 0) ? QSCL : 1.f;
#pragma unroll
                for (int rq = 0; rq < 4; ++rq)
#pragma unroll
                    for (int rr = 0; rr < 4; ++rr) {
                        const int row = rbase + rq * 8 + rr;
                        dst[(size_t)row * H_DIM + cl] = (bf16)((acc[i][j][rq * 4 + rr] + bv) * sc);
                    }
            } else {
                const int hI = cl >> 6, dI = cl & 63;
#pragma unroll
                for (int rq = 0; rq < 4; ++rq) {
                    const int row0 = rbase + rq * 8;
                    const int bI = row0 >> 11, s0 = row0 & 2047;
                    bf16x4 ov;
#pragma unroll
                    for (int rr = 0; rr < 4; ++rr) ov[rr] = (bf16)(acc[i][j][rq * 4 + rr] + bv);
                    *(bf16x4*)(Vo + ((size_t)((bI * NHEAD + hI) * HD + dI)) * 2048 + s0) = ov;
                }
            }
        }
    }
}

// ---------------- flash attention v10 (unchanged): raw v_exp_f32 + setprio ----------------
__global__ __launch_bounds__(256) void attn_kernel(const bf16* __restrict__ Qb,
                                                   const bf16* __restrict__ Kb,
                                                   const bf16* __restrict__ Vt_g,
                                                   bf16* __restrict__ Ob,
                                                   int SQ, int SK) {
    __shared__ bf16 SMEM[2][2][64 * 64];
    const int nwg = gridDim.x * gridDim.y;
    const int dlin = blockIdx.y * gridDim.x + blockIdx.x;
    const int id = (dlin & 7) * (nwg >> 3) + (dlin >> 3);
    const int NQ = gridDim.y;
    const int bh = id / NQ, qt = id - bh * NQ;
    const int b = bh >> 4, h = bh & 15;
    const int q0 = qt * 128;
    const int tid = threadIdx.x, wave = tid >> 6, lane = tid & 63;
    const int lr = lane & 15, lhi = lane >> 4;

    bf16x8 qf[2][2];
#pragma unroll
    for (int qi = 0; qi < 2; ++qi) {
        const bf16* qp = Qb + ((size_t)b * SQ + q0 + wave * 32 + qi * 16 + lr) * H_DIM + h * HD;
        qf[qi][0] = *(const bf16x8*)(qp + lhi * 8);
        qf[qi][1] = *(const bf16x8*)(qp + 32 + lhi * 8);
    }

    const int kx = (((lr & 3) | (((lr >> 2) & 1) << 2)) << 3);
    const int vx = (((lr & 3) | (((lr >> 3) & 1) << 2)) << 3);
    int krow[4];
#pragma unroll
    for (int nf = 0; nf < 4; ++nf)
        krow[nf] = (nf >> 1) * 32 + (lr >> 2) * 8 + (nf & 1) * 4 + (lr & 3);

    const int rS = tid >> 3, cS = (tid & 7) * 8;
    const int kxw = (((rS & 3) | (((rS >> 3) & 1) << 2)) << 3);
    const bf16* Kg = Kb + (size_t)b * SK * H_DIM + h * HD;
    const bf16* Vg = Vt_g + (size_t)bh * 64 * SK;

    bf16x8 onesv;
#pragma unroll
    for (int j = 0; j < 8; ++j) onesv[j] = (bf16)1.0f;

    f32x4 o[2][4] = {};
    f32x4 psum[2] = {};
    bf16x8 gK[2], gV[2];

    auto LOADG = [&](int kb) {
#pragma unroll
        for (int p = 0; p < 2; ++p) {
            gK[p] = *(const bf16x8*)(Kg + (size_t)(kb + p * 32 + rS) * H_DIM + cS);
            gV[p] = *(const bf16x8*)(Vg + (size_t)(p * 32 + rS) * SK + kb + cS);
        }
    };
    auto STORES = [&](int buf) {
#pragma unroll
        for (int p = 0; p < 2; ++p) {
            *(bf16x8*)&SMEM[buf][0][(p * 32 + rS) * 64 + (cS ^ kxw)] = gK[p];
            *(bf16x8*)&SMEM[buf][1][(p * 32 + rS) * 64 + (cS ^ kxw)] = gV[p];
        }
    };
    auto COMPUTE = [&](int buf) {
        f32x4 s[2][4] = {};
        __builtin_amdgcn_s_setprio(1);
#pragma unroll
        for (int nf = 0; nf < 4; ++nf) {
            const int base = krow[nf] * 64;
            bf16x8 kf0 = *(const bf16x8*)&SMEM[buf][0][base + ((lhi * 8) ^ kx)];
            bf16x8 kf1 = *(const bf16x8*)&SMEM[buf][0][base + ((32 + lhi * 8) ^ kx)];
#pragma unroll
            for (int qi = 0; qi < 2; ++qi) {
                s[qi][nf] = __builtin_amdgcn_mfma_f32_16x16x32_bf16(kf0, qf[qi][0], s[qi][nf], 0, 0, 0);
                s[qi][nf] = __builtin_amdgcn_mfma_f32_16x16x32_bf16(kf1, qf[qi][1], s[qi][nf], 0, 0, 0);
            }
        }
        __builtin_amdgcn_s_setprio(0);
        unsigned pw[2][8];
#pragma unroll
        for (int qi = 0; qi < 2; ++qi)
#pragma unroll
            for (int nf = 0; nf < 4; ++nf) {
                float p0 = fexp2(s[qi][nf][0]);
                float p1 = fexp2(s[qi][nf][1]);
                float p2 = fexp2(s[qi][nf][2]);
                float p3 = fexp2(s[qi][nf][3]);
                pw[qi][nf * 2]     = cvtpk_bf16(p0, p1);
                pw[qi][nf * 2 + 1] = cvtpk_bf16(p2, p3);
            }
        __builtin_amdgcn_s_setprio(1);
#pragma unroll
        for (int kk = 0; kk < 2; ++kk) {
            bf16x8 pb[2];
#pragma unroll
            for (int qi = 0; qi < 2; ++qi) {
                int4v w = { (int)pw[qi][kk * 4], (int)pw[qi][kk * 4 + 1],
                            (int)pw[qi][kk * 4 + 2], (int)pw[qi][kk * 4 + 3] };
                pb[qi] = __builtin_bit_cast(bf16x8, w);
                psum[qi] = __builtin_amdgcn_mfma_f32_16x16x32_bf16(onesv, pb[qi], psum[qi], 0, 0, 0);
            }
#pragma unroll
            for (int df = 0; df < 4; ++df) {
                bf16x8 vf = *(const bf16x8*)&SMEM[buf][1][(df * 16 + lr) * 64 + ((kk * 32 + lhi * 8) ^ vx)];
                o[0][df] = __builtin_amdgcn_mfma_f32_16x16x32_bf16(vf, pb[0], o[0][df], 0, 0, 0);
                o[1][df] = __builtin_amdgcn_mfma_f32_16x16x32_bf16(vf, pb[1], o[1][df], 0, 0, 0);
            }
        }
        __builtin_amdgcn_s_setprio(0);
    };

    const int nt = SK >> 6;
    LOADG(0);
    STORES(0);
    if (nt > 1) LOADG(64);
    __syncthreads();
    for (int t = 0; t < nt; ++t) {
        COMPUTE(t & 1);
        if (t + 1 < nt) {
            STORES((t + 1) & 1);
            if (t + 2 < nt) LOADG((t + 2) << 6);
        }
        __syncthreads();
    }

    bf16* T = &SMEM[0][0][0] + wave * (32 * 72);
#pragma unroll
    for (int qi = 0; qi < 2; ++qi) {
        const float inv = 1.0f / psum[qi][0];
#pragma unroll
        for (int df = 0; df < 4; ++df)
#pragma unroll
            for (int r = 0; r < 4; ++r)
                T[(qi * 16 + lr) * 72 + df * 16 + lhi * 4 + r] = (bf16)(o[qi][df][r] * inv);
    }
#pragma unroll
    for (int pp = 0; pp < 4; ++pp) {
        const int r32 = pp * 8 + (lane >> 3), ch = (lane & 7) * 8;
        bf16x8 v = *(const bf16x8*)&T[r32 * 72 + ch];
        *(bf16x8*)(Ob + ((size_t)b * SQ + q0 + wave * 32 + r32) * H_DIM + h * HD + ch) = v;
    }
}

extern "C" void kernel_launch(void* const* d_in, const int* in_sizes, int n_in,
                              void* d_out, int out_size, void* d_ws, size_t ws_size,
                              hipStream_t stream) {
    const float* x    = (const float*)d_in[0];
    const float* img  = (const float*)d_in[1];
    const float* W_sq = (const float*)d_in[2];   const float* b_sq = (const float*)d_in[3];
    const float* W_sk = (const float*)d_in[4];   const float* b_sk = (const float*)d_in[5];
    const float* W_sv = (const float*)d_in[6];   const float* b_sv = (const float*)d_in[7];
    const float* W_so = (const float*)d_in[8];   const float* b_so = (const float*)d_in[9];
    const float* W_cq = (const float*)d_in[10];  const float* b_cq = (const float*)d_in[11];
    const float* W_ck = (const float*)d_in[12];  const float* b_ck = (const float*)d_in[13];
    const float* W_cv = (const float*)d_in[14];  const float* b_cv = (const float*)d_in[15];
    const float* W_co = (const float*)d_in[16];  const float* b_co = (const float*)d_in[17];
    const float* W_f1 = (const float*)d_in[18];  const float* b_f1 = (const float*)d_in[19];
    const float* W_f2 = (const float*)d_in[20];  const float* b_f2 = (const float*)d_in[21];
    const float* g1 = (const float*)d_in[22];    const float* bb1 = (const float*)d_in[23];
    const float* g2 = (const float*)d_in[24];    const float* bb2 = (const float*)d_in[25];
    const float* g3 = (const float*)d_in[26];    const float* bb3 = (const float*)d_in[27];

    char* ws = (char*)d_ws;
    const size_t MB = 1ull << 20;
    bf16* WT   = (bf16*)ws;
    bf16* w_sq = WT + 0 * (1u << 20);
    bf16* w_sk = WT + 1 * (1u << 20);
    bf16* w_sv = WT + 2 * (1u << 20);
    bf16* w_so = WT + 3 * (1u << 20);
    bf16* w_cq = WT + 4 * (1u << 20);
    bf16* w_ck = WT + 5 * (1u << 20);   // ck,cv contiguous -> fused KV weight [2048][1024]
    bf16* w_cv = WT + 6 * (1u << 20);
    bf16* w_co = WT + 7 * (1u << 20);
    bf16* w_f1 = WT + 8 * (1u << 20);   // [4096][1024]
    bf16* w_f2 = WT + 12 * (1u << 20);  // [1024][4096]
    float* XR  = (float*)(ws + 32 * MB);
    bf16* NX   = (bf16*)(ws + 48 * MB);
    bf16* Qb   = (bf16*)(ws + 56 * MB);
    bf16* Kb   = (bf16*)(ws + 64 * MB);
    bf16* Vt   = (bf16*)(ws + 72 * MB);  // [b][h][d][s] (8 MB)
    bf16* FF   = (bf16*)(ws + 56 * MB);  // reused after attention (56-88 MB)
    unsigned char* W8  = (unsigned char*)(ws + 80 * MB);   // fp8 QKV weights [3072][1024] (3 MB)
    unsigned char* NX8 = (unsigned char*)(ws + 83 * MB);   // fp8 LN1 out [4096][1024] (4 MB)
    bf16* IMGB = (bf16*)(ws + 88 * MB);

    const dim3 blk(256);

    WPtrs wp;
    wp.w[0] = W_sq; wp.o[0] = w_sq;  wp.w[1] = W_sk; wp.o[1] = w_sk;
    wp.w[2] = W_sv; wp.o[2] = w_sv;  wp.w[3] = W_so; wp.o[3] = w_so;
    wp.w[4] = W_cq; wp.o[4] = w_cq;  wp.w[5] = W_ck; wp.o[5] = w_ck;
    wp.w[6] = W_cv; wp.o[6] = w_cv;  wp.w[7] = W_co; wp.o[7] = w_co;
    wconv8_kernel<<<dim3(16, 16, 8), blk, 0, stream>>>(wp);
    W3Ptrs w3; w3.w[0] = W_sq; w3.w[1] = W_sk; w3.w[2] = W_sv;
    wconv_fp8_kernel<<<dim3(16, 16, 3), blk, 0, stream>>>(w3, W8);
    wconv_kernel<<<dim3(64, 16), blk, 0, stream>>>(W_f1, w_f1, 1024, 4096);
    wconv_kernel<<<dim3(16, 64), blk, 0, stream>>>(W_f2, w_f2, 4096, 1024);

    // ---- self attention ----
    ln_fp8_kernel<<<4096, blk, 0, stream>>>(x, 0.1f, g1, bb1, (unsigned*)NX8);
    gemm_qkv_fp8<<<dim3(24, 32), blk, 0, stream>>>(NX8, W8, b_sq, b_sk, b_sv, Qb, Kb, Vt);
    attn_kernel<<<dim3(32, 16), blk, 0, stream>>>(Qb, Kb, Vt, NX, 2048, 2048);
    gemm_kernel<64, 128, 0, false, false, true><<<dim3(8, 64), blk, 0, stream>>>(
        NX, w_so, b_so, nullptr, nullptr, x, XR, nullptr, nullptr, 4096, 1024, 1024, 0.1f, 1.f, 0);

    // ---- cross attention ----
    ln_kernel<<<4096, blk, 0, stream>>>(XR, 1.f, g2, bb2, NX);
    gemm_kernel<64, 128, 0, true, false, false><<<dim3(8, 64), blk, 0, stream>>>(
        NX, w_cq, b_cq, nullptr, nullptr, nullptr, Qb, nullptr, nullptr, 4096, 1024, 1024, 0.f, QSCL, 0);
    cvt_scale_kernel<<<dim3(512), blk, 0, stream>>>(img, IMGB, 0.1f, 131072);
    gemm_kernel<64, 128, 2, true, false, false><<<dim3(16, 8), blk, 0, stream>>>(
        IMGB, w_ck, b_ck, b_cv, nullptr, nullptr, Kb, Vt, nullptr, 512, 2048, 1024, 0.f, 1.f, 8);
    attn_kernel<<<dim3(32, 16), blk, 0, stream>>>(Qb, Kb, Vt, NX, 2048, 256);
    gemm_kernel<64, 128, 0, false, false, true><<<dim3(8, 64), blk, 0, stream>>>(
        NX, w_co, b_co, nullptr, nullptr, XR, XR, nullptr, nullptr, 4096, 1024, 1024, 1.f, 1.f, 0);

    // ---- feed forward ----
    ln_kernel<<<4096, blk, 0, stream>>>(XR, 1.f, g3, bb3, NX);
    gemm_kernel<128, 128, 0, true, true, false><<<dim3(32, 32), blk, 0, stream>>>(
        NX, w_f1, b_f1, nullptr, nullptr, nullptr, FF, nullptr, nullptr, 4096, 4096, 1024, 0.f, 1.f, 0);
    gemm_kernel<64, 128, 0, false, false, true><<<dim3(8, 64), blk, 0, stream>>>(
        FF, w_f2, b_f2, nullptr, nullptr, XR, d_out, nullptr, nullptr, 4096, 1024, 4096, 1.f, 10.f, 0);
}

// Round 19
// 264.303 us; speedup vs baseline: 1.2252x; 1.0348x over previous
//
#include <hip/hip_runtime.h>
#include <hip/hip_bf16.h>

typedef __bf16 bf16;
typedef __bf16 bf16x4 __attribute__((ext_vector_type(4)));
typedef __bf16 bf16x8 __attribute__((ext_vector_type(8)));
typedef float  f32x4  __attribute__((ext_vector_type(4)));
typedef float  f32x16 __attribute__((ext_vector_type(16)));
typedef int    int4v  __attribute__((ext_vector_type(4)));

#define H_DIM 1024
#define NHEAD 16
#define HD    64
// SCALE * log2(e), folded into Q-projection epilogue; attn softmax runs in base-2
#define QSCL 0.18033688011112042f

__device__ __forceinline__ void gload_lds16(const bf16* g, bf16* l) {
    __builtin_amdgcn_global_load_lds((const __attribute__((address_space(1))) void*)g,
                                     (__attribute__((address_space(3))) void*)l, 16, 0, 0);
}
__device__ __forceinline__ void gload_lds16_u8(const unsigned char* g, unsigned char* l) {
    __builtin_amdgcn_global_load_lds((const __attribute__((address_space(1))) void*)g,
                                     (__attribute__((address_space(3))) void*)l, 16, 0, 0);
}

__device__ __forceinline__ unsigned cvtpk_bf16(float lo, float hi) {
    unsigned r;
    asm volatile("v_cvt_pk_bf16_f32 %0, %1, %2" : "=v"(r) : "v"(lo), "v"(hi));
    return r;
}
// pack 2 floats -> 2 e4m3 bytes (low 16 bits of dest)
__device__ __forceinline__ unsigned cvt2_fp8(float a, float b) {
    unsigned r;
    asm volatile("v_cvt_pk_fp8_f32 %0, %1, %2" : "=v"(r) : "v"(a), "v"(b));
    return r & 0xffffu;
}
__device__ __forceinline__ unsigned pack4_fp8(float a, float b, float c, float d) {
    return cvt2_fp8(a, b) | (cvt2_fp8(c, d) << 16);
}

// single-instruction 2^x (v_exp_f32); plain exp2f lowers to the multi-instr libm path
__device__ __forceinline__ float fexp2(float x) {
    float r;
    asm("v_exp_f32 %0, %1" : "=v"(r) : "v"(x));
    return r;
}

// ---------------- weight fp32 [K][N] -> bf16 [N][K] (transpose+convert) ----------------
__device__ __forceinline__ void wconv_body(const float* __restrict__ W,
                                           bf16* __restrict__ Wt, int K, int N,
                                           int bx, int by, int t) {
    __shared__ float tile[64][65];
    const int n0 = bx * 64, k0 = by * 64;
#pragma unroll
    for (int p = 0; p < 4; ++p) {
        int lin = p * 1024 + t * 4;
        int r = lin >> 6, c = lin & 63;
        f32x4 v = *(const f32x4*)(W + (size_t)(k0 + r) * N + n0 + c);
        tile[r][c]     = v[0];
        tile[r][c + 1] = v[1];
        tile[r][c + 2] = v[2];
        tile[r][c + 3] = v[3];
    }
    __syncthreads();
#pragma unroll
    for (int p = 0; p < 4; ++p) {
        int lin = p * 1024 + t * 4;
        int rn = lin >> 6, ck = lin & 63;
        bf16x4 o;
#pragma unroll
        for (int j = 0; j < 4; ++j) o[j] = (bf16)tile[ck + j][rn];
        *(bf16x4*)(Wt + (size_t)(n0 + rn) * K + k0 + ck) = o;
    }
}

__global__ __launch_bounds__(256) void wconv_kernel(const float* __restrict__ W,
                                                    bf16* __restrict__ Wt,
                                                    int K, int N) {
    wconv_body(W, Wt, K, N, blockIdx.x, blockIdx.y, threadIdx.x);
}

struct WPtrs { const float* w[8]; bf16* o[8]; };
__global__ __launch_bounds__(256) void wconv8_kernel(WPtrs p) {
    const int m = blockIdx.z;
    wconv_body(p.w[m], p.o[m], 1024, 1024, blockIdx.x, blockIdx.y, threadIdx.x);
}

// fp8 variant for the QKV weights: out[m] = fp8 [1024][1024] at out + m*1MB
struct W3Ptrs { const float* w[3]; };
__global__ __launch_bounds__(256) void wconv_fp8_kernel(W3Ptrs p, unsigned char* __restrict__ out) {
    __shared__ float tile[64][65];
    const int m = blockIdx.z, t = threadIdx.x;
    const float* W = p.w[m];
    unsigned char* Wt = out + (size_t)m * 1024 * 1024;
    const int n0 = blockIdx.x * 64, k0 = blockIdx.y * 64;
#pragma unroll
    for (int pp = 0; pp < 4; ++pp) {
        int lin = pp * 1024 + t * 4;
        int r = lin >> 6, c = lin & 63;
        f32x4 v = *(const f32x4*)(W + (size_t)(k0 + r) * 1024 + n0 + c);
        tile[r][c]     = v[0];
        tile[r][c + 1] = v[1];
        tile[r][c + 2] = v[2];
        tile[r][c + 3] = v[3];
    }
    __syncthreads();
#pragma unroll
    for (int pp = 0; pp < 4; ++pp) {
        int lin = pp * 1024 + t * 4;
        int rn = lin >> 6, ck = lin & 63;
        unsigned u = pack4_fp8(tile[ck][rn], tile[ck + 1][rn], tile[ck + 2][rn], tile[ck + 3][rn]);
        *(unsigned*)&Wt[(size_t)(n0 + rn) * 1024 + k0 + ck] = u;
    }
}

// ---------------- layernorm (fp32 in, bf16 out), one row per block ----------------
__global__ __launch_bounds__(256) void ln_kernel(const float* __restrict__ in, float inScale,
                                                 const float* __restrict__ g,
                                                 const float* __restrict__ b,
                                                 bf16* __restrict__ out) {
    const int row = blockIdx.x, t = threadIdx.x;
    const float* p = in + (size_t)row * H_DIM;
    f32x4 v = *(const f32x4*)(p + t * 4);
    v *= inScale;
    float s1 = v[0] + v[1] + v[2] + v[3];
    float s2 = v[0] * v[0] + v[1] * v[1] + v[2] * v[2] + v[3] * v[3];
#pragma unroll
    for (int m = 1; m < 64; m <<= 1) {
        s1 += __shfl_xor(s1, m);
        s2 += __shfl_xor(s2, m);
    }
    __shared__ float red[8];
    const int wave = t >> 6;
    if ((t & 63) == 0) { red[wave * 2] = s1; red[wave * 2 + 1] = s2; }
    __syncthreads();
    s1 = red[0] + red[2] + red[4] + red[6];
    s2 = red[1] + red[3] + red[5] + red[7];
    float mean = s1 * (1.0f / H_DIM);
    float var  = s2 * (1.0f / H_DIM) - mean * mean;
    float inv  = rsqrtf(var + 1e-5f);
    f32x4 gg = *(const f32x4*)(g + t * 4);
    f32x4 bb = *(const f32x4*)(b + t * 4);
    bf16x4 o;
#pragma unroll
    for (int j = 0; j < 4; ++j) o[j] = (bf16)((v[j] - mean) * inv * gg[j] + bb[j]);
    *(bf16x4*)(out + (size_t)row * H_DIM + t * 4) = o;
}

// LN with fp8 output (for the QKV GEMM's A operand)
__global__ __launch_bounds__(256) void ln_fp8_kernel(const float* __restrict__ in, float inScale,
                                                     const float* __restrict__ g,
                                                     const float* __restrict__ b,
                                                     unsigned* __restrict__ out) {
    const int row = blockIdx.x, t = threadIdx.x;
    const float* p = in + (size_t)row * H_DIM;
    f32x4 v = *(const f32x4*)(p + t * 4);
    v *= inScale;
    float s1 = v[0] + v[1] + v[2] + v[3];
    float s2 = v[0] * v[0] + v[1] * v[1] + v[2] * v[2] + v[3] * v[3];
#pragma unroll
    for (int m = 1; m < 64; m <<= 1) {
        s1 += __shfl_xor(s1, m);
        s2 += __shfl_xor(s2, m);
    }
    __shared__ float red[8];
    const int wave = t >> 6;
    if ((t & 63) == 0) { red[wave * 2] = s1; red[wave * 2 + 1] = s2; }
    __syncthreads();
    s1 = red[0] + red[2] + red[4] + red[6];
    s2 = red[1] + red[3] + red[5] + red[7];
    float mean = s1 * (1.0f / H_DIM);
    float var  = s2 * (1.0f / H_DIM) - mean * mean;
    float inv  = rsqrtf(var + 1e-5f);
    f32x4 gg = *(const f32x4*)(g + t * 4);
    f32x4 bb = *(const f32x4*)(b + t * 4);
    float y0 = (v[0] - mean) * inv * gg[0] + bb[0];
    float y1 = (v[1] - mean) * inv * gg[1] + bb[1];
    float y2 = (v[2] - mean) * inv * gg[2] + bb[2];
    float y3 = (v[3] - mean) * inv * gg[3] + bb[3];
    out[row * 256 + t] = pack4_fp8(y0, y1, y2, y3);
}

// ---------------- fp32 -> bf16 with scale ----------------
__global__ __launch_bounds__(256) void cvt_scale_kernel(const float* __restrict__ in,
                                                        bf16* __restrict__ out,
                                                        float s, int n4) {
    int i = blockIdx.x * 256 + threadIdx.x;
    if (i < n4) {
        f32x4 v = *(const f32x4*)(in + (size_t)i * 4);
        bf16x4 o;
#pragma unroll
        for (int j = 0; j < 4; ++j) o[j] = (bf16)(v[j] * s);
        *(bf16x4*)(out + (size_t)i * 4) = o;
    }
}

// ---------------- GEMM v6: 16x16x32 MFMA (m97 fragment economics) + XOR swizzle ----
// Per wave per kk: 8 ds_read_b128 feed 16 MFMAs (2 MFMAs/read) -- vs 1/read at 32x32.
// All fragment rows satisfy row&7 == lr&7, so the read XOR (lr&7)<<3 matches the
// source pre-swizzle involution (rule #21). dbuf + counted vmcnt + T1 retained.
// C/D (16x16x32): col = lane&15, row = (lane>>4)*4 + reg   [m89/m91-verified]
// MODE 0: plain epilogue -> o1; MODE 2: KV fused
template <int BM, int BN, int MODE, bool OUT_BF16, bool GELU_EPI, bool HAS_RES>
__global__ __launch_bounds__(256) void gemm_kernel(const bf16* __restrict__ A,
                                                   const bf16* __restrict__ Bt,
                                                   const float* __restrict__ bias1,
                                                   const float* __restrict__ bias2,
                                                   const float* __restrict__ bias3,
                                                   const float* __restrict__ res,
                                                   void* __restrict__ o1, void* __restrict__ o2,
                                                   void* __restrict__ o3,
                                                   int M, int N, int K,
                                                   float resScale, float outScale, int slog2) {
    constexpr int CHUNKS = (BM + BN) / 32;
    constexpr int WRR = BM / 2, WCC = BN / 2;
    constexpr int MI = WRR / 16, NJ = WCC / 16;
    __shared__ bf16 SM[2][(BM + BN) * 64];
    const int nwg = gridDim.x * gridDim.y;
    const int dlin = blockIdx.y * gridDim.x + blockIdx.x;
    const int id = (dlin & 7) * (nwg >> 3) + (dlin >> 3);
    const int bx = id % gridDim.x, by = id / gridDim.x;
    const int m0 = by * BM, n0 = bx * BN;
    const int tid = threadIdx.x;
    const int wave = tid >> 6, lane = tid & 63;
    const int lr = lane & 15, lhi = lane >> 4;
    const int wr = wave >> 1, wc = wave & 1;
    const int sr = lane >> 3, sc8 = (lane & 7) * 8;
    const int sc8x = sc8 ^ (sr << 3);            // pre-swizzled source col (involution)
    const int rxr = (lr & 7) << 3;               // read-side XOR (row&7 == lr&7)

    f32x4 acc[MI][NJ] = {};

    auto stage = [&](int buf, int k0) {
#pragma unroll
        for (int p = 0; p < CHUNKS; ++p) {
            const int rr = p * 32 + wave * 8 + sr;
            bf16* l = &SM[buf][0] + p * 2048 + wave * 512;
            const bf16* g = (p < BM / 32)
                ? (A  + (size_t)(m0 + rr) * K + k0 + sc8x)
                : (Bt + (size_t)(n0 + rr - BM) * K + k0 + sc8x);
            gload_lds16(g, l);
        }
    };

    stage(0, 0);
    int buf = 0;
    for (int k0 = 0; k0 < K; k0 += 64) {
        const bool pre = (k0 + 64 < K);
        if (pre) {
            stage(buf ^ 1, k0 + 64);
            asm volatile("s_waitcnt vmcnt(%0)" :: "i"(CHUNKS) : "memory");
        } else {
            asm volatile("s_waitcnt vmcnt(0)" ::: "memory");
        }
        __builtin_amdgcn_sched_barrier(0);
        __builtin_amdgcn_s_barrier();
#pragma unroll
        for (int kk = 0; kk < 2; ++kk) {
            const int sa = (kk * 32 + lhi * 8) ^ rxr;
            bf16x8 af[MI], bfr[NJ];
#pragma unroll
            for (int i = 0; i < MI; ++i)
                af[i] = *(const bf16x8*)&SM[buf][(wr * WRR + i * 16 + lr) * 64 + sa];
#pragma unroll
            for (int j = 0; j < NJ; ++j)
                bfr[j] = *(const bf16x8*)&SM[buf][(BM + wc * WCC + j * 16 + lr) * 64 + sa];
#pragma unroll
            for (int i = 0; i < MI; ++i)
#pragma unroll
                for (int j = 0; j < NJ; ++j)
                    acc[i][j] = __builtin_amdgcn_mfma_f32_16x16x32_bf16(af[i], bfr[j], acc[i][j], 0, 0, 0);
        }
        __builtin_amdgcn_s_barrier();
        buf ^= 1;
    }

#pragma unroll
    for (int i = 0; i < MI; ++i) {
#pragma unroll
        for (int j = 0; j < NJ; ++j) {
            const int col = n0 + wc * WCC + j * 16 + lr;
            const int row0 = m0 + wr * WRR + i * 16 + lhi * 4;
            if (MODE == 0) {
                const float bv = bias1[col];
#pragma unroll
                for (int r = 0; r < 4; ++r) {
                    const int row = row0 + r;
                    const size_t idx = (size_t)row * N + col;
                    float v = acc[i][j][r] + bv;
                    if (HAS_RES) v += res[idx] * resScale;
                    if (GELU_EPI) v = 0.5f * v * (1.0f + erff(v * 0.70710678118654752f));
                    v *= outScale;
                    if (OUT_BF16) ((bf16*)o1)[idx] = (bf16)v;
                    else          ((float*)o1)[idx] = v;
                }
            } else {
                const int sec = col >> 10, cl = col & 1023;
                const bool isV = (sec == 1);
                const float bv = (sec == 0 ? bias1 : bias2)[cl];
                if (!isV) {
                    bf16* dst = (bf16*)o1;
#pragma unroll
                    for (int r = 0; r < 4; ++r)
                        dst[(size_t)(row0 + r) * H_DIM + cl] = (bf16)(acc[i][j][r] + bv);
                } else {
                    bf16* dst = (bf16*)o2;
                    const int S = 1 << slog2;
                    const int hI = cl >> 6, dI = cl & 63;
                    const int bI = row0 >> slog2, s0 = row0 & (S - 1);
                    bf16x4 ov;
#pragma unroll
                    for (int r = 0; r < 4; ++r) ov[r] = (bf16)(acc[i][j][r] + bv);
                    *(bf16x4*)(dst + ((size_t)((bI * NHEAD + hI) * HD + dI)) * S + s0) = ov;
                }
            }
        }
    }
}

// ---------------- fp8 QKV GEMM (unchanged): 32x32x16 fp8 MFMA, dbuf + counted vmcnt ----
__global__ __launch_bounds__(256) void gemm_qkv_fp8(const unsigned char* __restrict__ A8,
                                                    const unsigned char* __restrict__ B8,
                                                    const float* __restrict__ bias1,
                                                    const float* __restrict__ bias2,
                                                    const float* __restrict__ bias3,
                                                    bf16* __restrict__ Qo, bf16* __restrict__ Ko,
                                                    bf16* __restrict__ Vo) {
    constexpr int Kd = 1024;
    __shared__ unsigned char SM[2][256 * 64];
    const int nwg = gridDim.x * gridDim.y;
    const int dlin = blockIdx.y * gridDim.x + blockIdx.x;
    const int id = (dlin & 7) * (nwg >> 3) + (dlin >> 3);
    const int bx = id % gridDim.x, by = id / gridDim.x;
    const int m0 = by * 128, n0 = bx * 128;
    const int tid = threadIdx.x;
    const int wave = tid >> 6, lane = tid & 63;
    const int l31 = lane & 31, l5 = lane >> 5;
    const int wr = wave >> 1, wc = wave & 1;
    const int srow = wave * 16 + (lane >> 2);
    const int sunit = (((lane & 3) ^ ((srow >> 1) & 3)) << 4);
    const int rxc = (l31 >> 1) & 3;

    f32x16 acc[2][2] = {};

    auto stage = [&](int buf, int k0) {
#pragma unroll
        for (int p = 0; p < 4; ++p) {
            const int rr = p * 64 + srow;
            unsigned char* l = &SM[buf][0] + p * 4096 + wave * 1024;
            const unsigned char* g = (p < 2)
                ? (A8 + (size_t)(m0 + rr) * Kd + k0 + sunit)
                : (B8 + (size_t)(n0 + rr - 128) * Kd + k0 + sunit);
            gload_lds16_u8(g, l);
        }
    };

    stage(0, 0);
    int buf = 0;
    for (int k0 = 0; k0 < Kd; k0 += 64) {
        const bool pre = (k0 + 64 < Kd);
        if (pre) {
            stage(buf ^ 1, k0 + 64);
            asm volatile("s_waitcnt vmcnt(4)" ::: "memory");
        } else {
            asm volatile("s_waitcnt vmcnt(0)" ::: "memory");
        }
        __builtin_amdgcn_sched_barrier(0);
        __builtin_amdgcn_s_barrier();
#pragma unroll
        for (int kk = 0; kk < 4; ++kk) {
            const int sa = (((kk ^ rxc) << 4) + l5 * 8);
            long long af[2], bfr[2];
#pragma unroll
            for (int i = 0; i < 2; ++i)
                af[i] = *(const long long*)&SM[buf][(wr * 64 + i * 32 + l31) * 64 + sa];
#pragma unroll
            for (int j = 0; j < 2; ++j)
                bfr[j] = *(const long long*)&SM[buf][(128 + wc * 64 + j * 32 + l31) * 64 + sa];
#pragma unroll
            for (int i = 0; i < 2; ++i)
#pragma unroll
                for (int j = 0; j < 2; ++j)
                    acc[i][j] = __builtin_amdgcn_mfma_f32_32x32x16_fp8_fp8(af[i], bfr[j], acc[i][j], 0, 0, 0);
        }
        __builtin_amdgcn_s_barrier();
        buf ^= 1;
    }

#pragma unroll
    for (int i = 0; i < 2; ++i) {
#pragma unroll
        for (int j = 0; j < 2; ++j) {
            const int col = n0 + wc * 64 + j * 32 + l31;
            const int rbase = m0 + wr * 64 + i * 32 + l5 * 4;
            const int sec = col >> 10, cl = col & 1023;
            const float bv = (sec == 0 ? bias1 : sec == 1 ? bias2 : bias3)[cl];
            if (sec < 2) {
                bf16* dst = (sec == 0) ? Qo : Ko;
                const float sc = (sec == 0) ? QSCL : 1.f;
#pragma unroll
                for (int rq = 0; rq < 4; ++rq)
#pragma unroll
                    for (int rr = 0; rr < 4; ++rr) {
                        const int row = rbase + rq * 8 + rr;
                        dst[(size_t)row * H_DIM + cl] = (bf16)((acc[i][j][rq * 4 + rr] + bv) * sc);
                    }
            } else {
                const int hI = cl >> 6, dI = cl & 63;
#pragma unroll
                for (int rq = 0; rq < 4; ++rq) {
                    const int row0 = rbase + rq * 8;
                    const int bI = row0 >> 11, s0 = row0 & 2047;
                    bf16x4 ov;
#pragma unroll
                    for (int rr = 0; rr < 4; ++rr) ov[rr] = (bf16)(acc[i][j][rq * 4 + rr] + bv);
                    *(bf16x4*)(Vo + ((size_t)((bI * NHEAD + hI) * HD + dI)) * 2048 + s0) = ov;
                }
            }
        }
    }
}

// ---------------- flash attention v10 (unchanged): raw v_exp_f32 + setprio ----------------
__global__ __launch_bounds__(256) void attn_kernel(const bf16* __restrict__ Qb,
                                                   const bf16* __restrict__ Kb,
                                                   const bf16* __restrict__ Vt_g,
                                                   bf16* __restrict__ Ob,
                                                   int SQ, int SK) {
    __shared__ bf16 SMEM[2][2][64 * 64];
    const int nwg = gridDim.x * gridDim.y;
    const int dlin = blockIdx.y * gridDim.x + blockIdx.x;
    const int id = (dlin & 7) * (nwg >> 3) + (dlin >> 3);
    const int NQ = gridDim.y;
    const int bh = id / NQ, qt = id - bh * NQ;
    const int b = bh >> 4, h = bh & 15;
    const int q0 = qt * 128;
    const int tid = threadIdx.x, wave = tid >> 6, lane = tid & 63;
    const int lr = lane & 15, lhi = lane >> 4;

    bf16x8 qf[2][2];
#pragma unroll
    for (int qi = 0; qi < 2; ++qi) {
        const bf16* qp = Qb + ((size_t)b * SQ + q0 + wave * 32 + qi * 16 + lr) * H_DIM + h * HD;
        qf[qi][0] = *(const bf16x8*)(qp + lhi * 8);
        qf[qi][1] = *(const bf16x8*)(qp + 32 + lhi * 8);
    }

    const int kx = (((lr & 3) | (((lr >> 2) & 1) << 2)) << 3);
    const int vx = (((lr & 3) | (((lr >> 3) & 1) << 2)) << 3);
    int krow[4];
#pragma unroll
    for (int nf = 0; nf < 4; ++nf)
        krow[nf] = (nf >> 1) * 32 + (lr >> 2) * 8 + (nf & 1) * 4 + (lr & 3);

    const int rS = tid >> 3, cS = (tid & 7) * 8;
    const int kxw = (((rS & 3) | (((rS >> 3) & 1) << 2)) << 3);
    const bf16* Kg = Kb + (size_t)b * SK * H_DIM + h * HD;
    const bf16* Vg = Vt_g + (size_t)bh * 64 * SK;

    bf16x8 onesv;
#pragma unroll
    for (int j = 0; j < 8; ++j) onesv[j] = (bf16)1.0f;

    f32x4 o[2][4] = {};
    f32x4 psum[2] = {};
    bf16x8 gK[2], gV[2];

    auto LOADG = [&](int kb) {
#pragma unroll
        for (int p = 0; p < 2; ++p) {
            gK[p] = *(const bf16x8*)(Kg + (size_t)(kb + p * 32 + rS) * H_DIM + cS);
            gV[p] = *(const bf16x8*)(Vg + (size_t)(p * 32 + rS) * SK + kb + cS);
        }
    };
    auto STORES = [&](int buf) {
#pragma unroll
        for (int p = 0; p < 2; ++p) {
            *(bf16x8*)&SMEM[buf][0][(p * 32 + rS) * 64 + (cS ^ kxw)] = gK[p];
            *(bf16x8*)&SMEM[buf][1][(p * 32 + rS) * 64 + (cS ^ kxw)] = gV[p];
        }
    };
    auto COMPUTE = [&](int buf) {
        f32x4 s[2][4] = {};
        __builtin_amdgcn_s_setprio(1);
#pragma unroll
        for (int nf = 0; nf < 4; ++nf) {
            const int base = krow[nf] * 64;
            bf16x8 kf0 = *(const bf16x8*)&SMEM[buf][0][base + ((lhi * 8) ^ kx)];
            bf16x8 kf1 = *(const bf16x8*)&SMEM[buf][0][base + ((32 + lhi * 8) ^ kx)];
#pragma unroll
            for (int qi = 0; qi < 2; ++qi) {
                s[qi][nf] = __builtin_amdgcn_mfma_f32_16x16x32_bf16(kf0, qf[qi][0], s[qi][nf], 0, 0, 0);
                s[qi][nf] = __builtin_amdgcn_mfma_f32_16x16x32_bf16(kf1, qf[qi][1], s[qi][nf], 0, 0, 0);
            }
        }
        __builtin_amdgcn_s_setprio(0);
        unsigned pw[2][8];
#pragma unroll
        for (int qi = 0; qi < 2; ++qi)
#pragma unroll
            for (int nf = 0; nf < 4; ++nf) {
                float p0 = fexp2(s[qi][nf][0]);
                float p1 = fexp2(s[qi][nf][1]);
                float p2 = fexp2(s[qi][nf][2]);
                float p3 = fexp2(s[qi][nf][3]);
                pw[qi][nf * 2]     = cvtpk_bf16(p0, p1);
                pw[qi][nf * 2 + 1] = cvtpk_bf16(p2, p3);
            }
        __builtin_amdgcn_s_setprio(1);
#pragma unroll
        for (int kk = 0; kk < 2; ++kk) {
            bf16x8 pb[2];
#pragma unroll
            for (int qi = 0; qi < 2; ++qi) {
                int4v w = { (int)pw[qi][kk * 4], (int)pw[qi][kk * 4 + 1],
                            (int)pw[qi][kk * 4 + 2], (int)pw[qi][kk * 4 + 3] };
                pb[qi] = __builtin_bit_cast(bf16x8, w);
                psum[qi] = __builtin_amdgcn_mfma_f32_16x16x32_bf16(onesv, pb[qi], psum[qi], 0, 0, 0);
            }
#pragma unroll
            for (int df = 0; df < 4; ++df) {
                bf16x8 vf = *(const bf16x8*)&SMEM[buf][1][(df * 16 + lr) * 64 + ((kk * 32 + lhi * 8) ^ vx)];
                o[0][df] = __builtin_amdgcn_mfma_f32_16x16x32_bf16(vf, pb[0], o[0][df], 0, 0, 0);
                o[1][df] = __builtin_amdgcn_mfma_f32_16x16x32_bf16(vf, pb[1], o[1][df], 0, 0, 0);
            }
        }
        __builtin_amdgcn_s_setprio(0);
    };

    const int nt = SK >> 6;
    LOADG(0);
    STORES(0);
    if (nt > 1) LOADG(64);
    __syncthreads();
    for (int t = 0; t < nt; ++t) {
        COMPUTE(t & 1);
        if (t + 1 < nt) {
            STORES((t + 1) & 1);
            if (t + 2 < nt) LOADG((t + 2) << 6);
        }
        __syncthreads();
    }

    bf16* T = &SMEM[0][0][0] + wave * (32 * 72);
#pragma unroll
    for (int qi = 0; qi < 2; ++qi) {
        const float inv = 1.0f / psum[qi][0];
#pragma unroll
        for (int df = 0; df < 4; ++df)
#pragma unroll
            for (int r = 0; r < 4; ++r)
                T[(qi * 16 + lr) * 72 + df * 16 + lhi * 4 + r] = (bf16)(o[qi][df][r] * inv);
    }
#pragma unroll
    for (int pp = 0; pp < 4; ++pp) {
        const int r32 = pp * 8 + (lane >> 3), ch = (lane & 7) * 8;
        bf16x8 v = *(const bf16x8*)&T[r32 * 72 + ch];
        *(bf16x8*)(Ob + ((size_t)b * SQ + q0 + wave * 32 + r32) * H_DIM + h * HD + ch) = v;
    }
}

extern "C" void kernel_launch(void* const* d_in, const int* in_sizes, int n_in,
                              void* d_out, int out_size, void* d_ws, size_t ws_size,
                              hipStream_t stream) {
    const float* x    = (const float*)d_in[0];
    const float* img  = (const float*)d_in[1];
    const float* W_sq = (const float*)d_in[2];   const float* b_sq = (const float*)d_in[3];
    const float* W_sk = (const float*)d_in[4];   const float* b_sk = (const float*)d_in[5];
    const float* W_sv = (const float*)d_in[6];   const float* b_sv = (const float*)d_in[7];
    const float* W_so = (const float*)d_in[8];   const float* b_so = (const float*)d_in[9];
    const float* W_cq = (const float*)d_in[10];  const float* b_cq = (const float*)d_in[11];
    const float* W_ck = (const float*)d_in[12];  const float* b_ck = (const float*)d_in[13];
    const float* W_cv = (const float*)d_in[14];  const float* b_cv = (const float*)d_in[15];
    const float* W_co = (const float*)d_in[16];  const float* b_co = (const float*)d_in[17];
    const float* W_f1 = (const float*)d_in[18];  const float* b_f1 = (const float*)d_in[19];
    const float* W_f2 = (const float*)d_in[20];  const float* b_f2 = (const float*)d_in[21];
    const float* g1 = (const float*)d_in[22];    const float* bb1 = (const float*)d_in[23];
    const float* g2 = (const float*)d_in[24];    const float* bb2 = (const float*)d_in[25];
    const float* g3 = (const float*)d_in[26];    const float* bb3 = (const float*)d_in[27];

    char* ws = (char*)d_ws;
    const size_t MB = 1ull << 20;
    bf16* WT   = (bf16*)ws;
    bf16* w_sq = WT + 0 * (1u << 20);
    bf16* w_sk = WT + 1 * (1u << 20);
    bf16* w_sv = WT + 2 * (1u << 20);
    bf16* w_so = WT + 3 * (1u << 20);
    bf16* w_cq = WT + 4 * (1u << 20);
    bf16* w_ck = WT + 5 * (1u << 20);   // ck,cv contiguous -> fused KV weight [2048][1024]
    bf16* w_cv = WT + 6 * (1u << 20);
    bf16* w_co = WT + 7 * (1u << 20);
    bf16* w_f1 = WT + 8 * (1u << 20);   // [4096][1024]
    bf16* w_f2 = WT + 12 * (1u << 20);  // [1024][4096]
    float* XR  = (float*)(ws + 32 * MB);
    bf16* NX   = (bf16*)(ws + 48 * MB);
    bf16* Qb   = (bf16*)(ws + 56 * MB);
    bf16* Kb   = (bf16*)(ws + 64 * MB);
    bf16* Vt   = (bf16*)(ws + 72 * MB);  // [b][h][d][s] (8 MB)
    bf16* FF   = (bf16*)(ws + 56 * MB);  // reused after attention (56-88 MB)
    unsigned char* W8  = (unsigned char*)(ws + 80 * MB);   // fp8 QKV weights [3072][1024] (3 MB)
    unsigned char* NX8 = (unsigned char*)(ws + 83 * MB);   // fp8 LN1 out [4096][1024] (4 MB)
    bf16* IMGB = (bf16*)(ws + 88 * MB);

    const dim3 blk(256);

    WPtrs wp;
    wp.w[0] = W_sq; wp.o[0] = w_sq;  wp.w[1] = W_sk; wp.o[1] = w_sk;
    wp.w[2] = W_sv; wp.o[2] = w_sv;  wp.w[3] = W_so; wp.o[3] = w_so;
    wp.w[4] = W_cq; wp.o[4] = w_cq;  wp.w[5] = W_ck; wp.o[5] = w_ck;
    wp.w[6] = W_cv; wp.o[6] = w_cv;  wp.w[7] = W_co; wp.o[7] = w_co;
    wconv8_kernel<<<dim3(16, 16, 8), blk, 0, stream>>>(wp);
    W3Ptrs w3; w3.w[0] = W_sq; w3.w[1] = W_sk; w3.w[2] = W_sv;
    wconv_fp8_kernel<<<dim3(16, 16, 3), blk, 0, stream>>>(w3, W8);
    wconv_kernel<<<dim3(64, 16), blk, 0, stream>>>(W_f1, w_f1, 1024, 4096);
    wconv_kernel<<<dim3(16, 64), blk, 0, stream>>>(W_f2, w_f2, 4096, 1024);

    // ---- self attention ----
    ln_fp8_kernel<<<4096, blk, 0, stream>>>(x, 0.1f, g1, bb1, (unsigned*)NX8);
    gemm_qkv_fp8<<<dim3(24, 32), blk, 0, stream>>>(NX8, W8, b_sq, b_sk, b_sv, Qb, Kb, Vt);
    attn_kernel<<<dim3(32, 16), blk, 0, stream>>>(Qb, Kb, Vt, NX, 2048, 2048);
    gemm_kernel<64, 128, 0, false, false, true><<<dim3(8, 64), blk, 0, stream>>>(
        NX, w_so, b_so, nullptr, nullptr, x, XR, nullptr, nullptr, 4096, 1024, 1024, 0.1f, 1.f, 0);

    // ---- cross attention ----
    ln_kernel<<<4096, blk, 0, stream>>>(XR, 1.f, g2, bb2, NX);
    gemm_kernel<64, 128, 0, true, false, false><<<dim3(8, 64), blk, 0, stream>>>(
        NX, w_cq, b_cq, nullptr, nullptr, nullptr, Qb, nullptr, nullptr, 4096, 1024, 1024, 0.f, QSCL, 0);
    cvt_scale_kernel<<<dim3(512), blk, 0, stream>>>(img, IMGB, 0.1f, 131072);
    gemm_kernel<64, 128, 2, true, false, false><<<dim3(16, 8), blk, 0, stream>>>(
        IMGB, w_ck, b_ck, b_cv, nullptr, nullptr, Kb, Vt, nullptr, 512, 2048, 1024, 0.f, 1.f, 8);
    attn_kernel<<<dim3(32, 16), blk, 0, stream>>>(Qb, Kb, Vt, NX, 2048, 256);
    gemm_kernel<64, 128, 0, false, false, true><<<dim3(8, 64), blk, 0, stream>>>(
        NX, w_co, b_co, nullptr, nullptr, XR, XR, nullptr, nullptr, 4096, 1024, 1024, 1.f, 1.f, 0);

    // ---- feed forward ----
    ln_kernel<<<4096, blk, 0, stream>>>(XR, 1.f, g3, bb3, NX);
    gemm_kernel<128, 128, 0, true, true, false><<<dim3(32, 32), blk, 0, stream>>>(
        NX, w_f1, b_f1, nullptr, nullptr, nullptr, FF, nullptr, nullptr, 4096, 4096, 1024, 0.f, 1.f, 0);
    gemm_kernel<64, 128, 0, false, false, true><<<dim3(8, 64), blk, 0, stream>>>(
        FF, w_f2, b_f2, nullptr, nullptr, XR, d_out, nullptr, nullptr, 4096, 1024, 4096, 1.f, 10.f, 0);
}

// Round 21
// 262.825 us; speedup vs baseline: 1.2321x; 1.0056x over previous
//
#include <hip/hip_runtime.h>
#include <hip/hip_bf16.h>

typedef __bf16 bf16;
typedef __bf16 bf16x4 __attribute__((ext_vector_type(4)));
typedef __bf16 bf16x8 __attribute__((ext_vector_type(8)));
typedef float  f32x4  __attribute__((ext_vector_type(4)));
typedef float  f32x16 __attribute__((ext_vector_type(16)));
typedef int    int4v  __attribute__((ext_vector_type(4)));

#define H_DIM 1024
#define NHEAD 16
#define HD    64
// SCALE * log2(e), folded into Q-projection epilogue; attn softmax runs in base-2
#define QSCL 0.18033688011112042f

__device__ __forceinline__ void gload_lds16(const bf16* g, bf16* l) {
    __builtin_amdgcn_global_load_lds((const __attribute__((address_space(1))) void*)g,
                                     (__attribute__((address_space(3))) void*)l, 16, 0, 0);
}
__device__ __forceinline__ void gload_lds16_u8(const unsigned char* g, unsigned char* l) {
    __builtin_amdgcn_global_load_lds((const __attribute__((address_space(1))) void*)g,
                                     (__attribute__((address_space(3))) void*)l, 16, 0, 0);
}

__device__ __forceinline__ unsigned cvtpk_bf16(float lo, float hi) {
    unsigned r;
    asm volatile("v_cvt_pk_bf16_f32 %0, %1, %2" : "=v"(r) : "v"(lo), "v"(hi));
    return r;
}
// pack 2 floats -> 2 e4m3 bytes (low 16 bits of dest)
__device__ __forceinline__ unsigned cvt2_fp8(float a, float b) {
    unsigned r;
    asm volatile("v_cvt_pk_fp8_f32 %0, %1, %2" : "=v"(r) : "v"(a), "v"(b));
    return r & 0xffffu;
}
__device__ __forceinline__ unsigned pack4_fp8(float a, float b, float c, float d) {
    return cvt2_fp8(a, b) | (cvt2_fp8(c, d) << 16);
}

// single-instruction 2^x (v_exp_f32); plain exp2f lowers to the multi-instr libm path
__device__ __forceinline__ float fexp2(float x) {
    float r;
    asm("v_exp_f32 %0, %1" : "=v"(r) : "v"(x));
    return r;
}

// ---------------- weight fp32 [K][N] -> bf16 [N][K] (transpose+convert) ----------------
__device__ __forceinline__ void wconv_body(const float* __restrict__ W,
                                           bf16* __restrict__ Wt, int K, int N,
                                           int bx, int by, int t) {
    __shared__ float tile[64][65];
    const int n0 = bx * 64, k0 = by * 64;
#pragma unroll
    for (int p = 0; p < 4; ++p) {
        int lin = p * 1024 + t * 4;
        int r = lin >> 6, c = lin & 63;
        f32x4 v = *(const f32x4*)(W + (size_t)(k0 + r) * N + n0 + c);
        tile[r][c]     = v[0];
        tile[r][c + 1] = v[1];
        tile[r][c + 2] = v[2];
        tile[r][c + 3] = v[3];
    }
    __syncthreads();
#pragma unroll
    for (int p = 0; p < 4; ++p) {
        int lin = p * 1024 + t * 4;
        int rn = lin >> 6, ck = lin & 63;
        bf16x4 o;
#pragma unroll
        for (int j = 0; j < 4; ++j) o[j] = (bf16)tile[ck + j][rn];
        *(bf16x4*)(Wt + (size_t)(n0 + rn) * K + k0 + ck) = o;
    }
}

__global__ __launch_bounds__(256) void wconv_kernel(const float* __restrict__ W,
                                                    bf16* __restrict__ Wt,
                                                    int K, int N) {
    wconv_body(W, Wt, K, N, blockIdx.x, blockIdx.y, threadIdx.x);
}

struct WPtrs { const float* w[4]; bf16* o[4]; };
__global__ __launch_bounds__(256) void wconv4_kernel(WPtrs p) {
    const int m = blockIdx.z;
    wconv_body(p.w[m], p.o[m], 1024, 1024, blockIdx.x, blockIdx.y, threadIdx.x);
}

// fp8 variants: out is [N][1024] fp8 (K fixed at 1024)
struct W3Ptrs { const float* w[3]; };
__global__ __launch_bounds__(256) void wconv_fp8_kernel(W3Ptrs p, unsigned char* __restrict__ out) {
    __shared__ float tile[64][65];
    const int m = blockIdx.z, t = threadIdx.x;
    const float* W = p.w[m];
    unsigned char* Wt = out + (size_t)m * 1024 * 1024;
    const int n0 = blockIdx.x * 64, k0 = blockIdx.y * 64;
#pragma unroll
    for (int pp = 0; pp < 4; ++pp) {
        int lin = pp * 1024 + t * 4;
        int r = lin >> 6, c = lin & 63;
        f32x4 v = *(const f32x4*)(W + (size_t)(k0 + r) * 1024 + n0 + c);
        tile[r][c]     = v[0];
        tile[r][c + 1] = v[1];
        tile[r][c + 2] = v[2];
        tile[r][c + 3] = v[3];
    }
    __syncthreads();
#pragma unroll
    for (int pp = 0; pp < 4; ++pp) {
        int lin = pp * 1024 + t * 4;
        int rn = lin >> 6, ck = lin & 63;
        unsigned u = pack4_fp8(tile[ck][rn], tile[ck + 1][rn], tile[ck + 2][rn], tile[ck + 3][rn]);
        *(unsigned*)&Wt[(size_t)(n0 + rn) * 1024 + k0 + ck] = u;
    }
}

// general-N fp8 weight convert: W fp32 [1024][N] -> Wt fp8 [N][1024]
__global__ __launch_bounds__(256) void wconv_fp8g(const float* __restrict__ W,
                                                  unsigned char* __restrict__ Wt, int N) {
    __shared__ float tile[64][65];
    const int t = threadIdx.x;
    const int n0 = blockIdx.x * 64, k0 = blockIdx.y * 64;
#pragma unroll
    for (int pp = 0; pp < 4; ++pp) {
        int lin = pp * 1024 + t * 4;
        int r = lin >> 6, c = lin & 63;
        f32x4 v = *(const f32x4*)(W + (size_t)(k0 + r) * N + n0 + c);
        tile[r][c]     = v[0];
        tile[r][c + 1] = v[1];
        tile[r][c + 2] = v[2];
        tile[r][c + 3] = v[3];
    }
    __syncthreads();
#pragma unroll
    for (int pp = 0; pp < 4; ++pp) {
        int lin = pp * 1024 + t * 4;
        int rn = lin >> 6, ck = lin & 63;
        unsigned u = pack4_fp8(tile[ck][rn], tile[ck + 1][rn], tile[ck + 2][rn], tile[ck + 3][rn]);
        *(unsigned*)&Wt[(size_t)(n0 + rn) * 1024 + k0 + ck] = u;
    }
}

// ---------------- layernorm (fp32 in, bf16 out), one row per block ----------------
__global__ __launch_bounds__(256) void ln_kernel(const float* __restrict__ in, float inScale,
                                                 const float* __restrict__ g,
                                                 const float* __restrict__ b,
                                                 bf16* __restrict__ out) {
    const int row = blockIdx.x, t = threadIdx.x;
    const float* p = in + (size_t)row * H_DIM;
    f32x4 v = *(const f32x4*)(p + t * 4);
    v *= inScale;
    float s1 = v[0] + v[1] + v[2] + v[3];
    float s2 = v[0] * v[0] + v[1] * v[1] + v[2] * v[2] + v[3] * v[3];
#pragma unroll
    for (int m = 1; m < 64; m <<= 1) {
        s1 += __shfl_xor(s1, m);
        s2 += __shfl_xor(s2, m);
    }
    __shared__ float red[8];
    const int wave = t >> 6;
    if ((t & 63) == 0) { red[wave * 2] = s1; red[wave * 2 + 1] = s2; }
    __syncthreads();
    s1 = red[0] + red[2] + red[4] + red[6];
    s2 = red[1] + red[3] + red[5] + red[7];
    float mean = s1 * (1.0f / H_DIM);
    float var  = s2 * (1.0f / H_DIM) - mean * mean;
    float inv  = rsqrtf(var + 1e-5f);
    f32x4 gg = *(const f32x4*)(g + t * 4);
    f32x4 bb = *(const f32x4*)(b + t * 4);
    bf16x4 o;
#pragma unroll
    for (int j = 0; j < 4; ++j) o[j] = (bf16)((v[j] - mean) * inv * gg[j] + bb[j]);
    *(bf16x4*)(out + (size_t)row * H_DIM + t * 4) = o;
}

// LN with fp8 output
__global__ __launch_bounds__(256) void ln_fp8_kernel(const float* __restrict__ in, float inScale,
                                                     const float* __restrict__ g,
                                                     const float* __restrict__ b,
                                                     unsigned* __restrict__ out) {
    const int row = blockIdx.x, t = threadIdx.x;
    const float* p = in + (size_t)row * H_DIM;
    f32x4 v = *(const f32x4*)(p + t * 4);
    v *= inScale;
    float s1 = v[0] + v[1] + v[2] + v[3];
    float s2 = v[0] * v[0] + v[1] * v[1] + v[2] * v[2] + v[3] * v[3];
#pragma unroll
    for (int m = 1; m < 64; m <<= 1) {
        s1 += __shfl_xor(s1, m);
        s2 += __shfl_xor(s2, m);
    }
    __shared__ float red[8];
    const int wave = t >> 6;
    if ((t & 63) == 0) { red[wave * 2] = s1; red[wave * 2 + 1] = s2; }
    __syncthreads();
    s1 = red[0] + red[2] + red[4] + red[6];
    s2 = red[1] + red[3] + red[5] + red[7];
    float mean = s1 * (1.0f / H_DIM);
    float var  = s2 * (1.0f / H_DIM) - mean * mean;
    float inv  = rsqrtf(var + 1e-5f);
    f32x4 gg = *(const f32x4*)(g + t * 4);
    f32x4 bb = *(const f32x4*)(b + t * 4);
    float y0 = (v[0] - mean) * inv * gg[0] + bb[0];
    float y1 = (v[1] - mean) * inv * gg[1] + bb[1];
    float y2 = (v[2] - mean) * inv * gg[2] + bb[2];
    float y3 = (v[3] - mean) * inv * gg[3] + bb[3];
    out[row * 256 + t] = pack4_fp8(y0, y1, y2, y3);
}

// ---------------- fp32 -> bf16 with scale ----------------
__global__ __launch_bounds__(256) void cvt_scale_kernel(const float* __restrict__ in,
                                                        bf16* __restrict__ out,
                                                        float s, int n4) {
    int i = blockIdx.x * 256 + threadIdx.x;
    if (i < n4) {
        f32x4 v = *(const f32x4*)(in + (size_t)i * 4);
        bf16x4 o;
#pragma unroll
        for (int j = 0; j < 4; ++j) o[j] = (bf16)(v[j] * s);
        *(bf16x4*)(out + (size_t)i * 4) = o;
    }
}

// ---------------- GEMM v6 (bf16): 16x16x32 MFMA + XOR swizzle, dbuf + counted vmcnt ----
// C/D (16x16x32): col = lane&15, row = (lane>>4)*4 + reg   [m89/m91-verified]
// MODE 0: plain epilogue -> o1; MODE 2: KV fused
template <int BM, int BN, int MODE, bool OUT_BF16, bool GELU_EPI, bool HAS_RES>
__global__ __launch_bounds__(256) void gemm_kernel(const bf16* __restrict__ A,
                                                   const bf16* __restrict__ Bt,
                                                   const float* __restrict__ bias1,
                                                   const float* __restrict__ bias2,
                                                   const float* __restrict__ bias3,
                                                   const float* __restrict__ res,
                                                   void* __restrict__ o1, void* __restrict__ o2,
                                                   void* __restrict__ o3,
                                                   int M, int N, int K,
                                                   float resScale, float outScale, int slog2) {
    constexpr int CHUNKS = (BM + BN) / 32;
    constexpr int WRR = BM / 2, WCC = BN / 2;
    constexpr int MI = WRR / 16, NJ = WCC / 16;
    __shared__ bf16 SM[2][(BM + BN) * 64];
    const int nwg = gridDim.x * gridDim.y;
    const int dlin = blockIdx.y * gridDim.x + blockIdx.x;
    const int id = (dlin & 7) * (nwg >> 3) + (dlin >> 3);
    const int bx = id % gridDim.x, by = id / gridDim.x;
    const int m0 = by * BM, n0 = bx * BN;
    const int tid = threadIdx.x;
    const int wave = tid >> 6, lane = tid & 63;
    const int lr = lane & 15, lhi = lane >> 4;
    const int wr = wave >> 1, wc = wave & 1;
    const int sr = lane >> 3, sc8 = (lane & 7) * 8;
    const int sc8x = sc8 ^ (sr << 3);
    const int rxr = (lr & 7) << 3;

    f32x4 acc[MI][NJ] = {};

    auto stage = [&](int buf, int k0) {
#pragma unroll
        for (int p = 0; p < CHUNKS; ++p) {
            const int rr = p * 32 + wave * 8 + sr;
            bf16* l = &SM[buf][0] + p * 2048 + wave * 512;
            const bf16* g = (p < BM / 32)
                ? (A  + (size_t)(m0 + rr) * K + k0 + sc8x)
                : (Bt + (size_t)(n0 + rr - BM) * K + k0 + sc8x);
            gload_lds16(g, l);
        }
    };

    stage(0, 0);
    int buf = 0;
    for (int k0 = 0; k0 < K; k0 += 64) {
        const bool pre = (k0 + 64 < K);
        if (pre) {
            stage(buf ^ 1, k0 + 64);
            asm volatile("s_waitcnt vmcnt(%0)" :: "i"(CHUNKS) : "memory");
        } else {
            asm volatile("s_waitcnt vmcnt(0)" ::: "memory");
        }
        __builtin_amdgcn_sched_barrier(0);
        __builtin_amdgcn_s_barrier();
#pragma unroll
        for (int kk = 0; kk < 2; ++kk) {
            const int sa = (kk * 32 + lhi * 8) ^ rxr;
            bf16x8 af[MI], bfr[NJ];
#pragma unroll
            for (int i = 0; i < MI; ++i)
                af[i] = *(const bf16x8*)&SM[buf][(wr * WRR + i * 16 + lr) * 64 + sa];
#pragma unroll
            for (int j = 0; j < NJ; ++j)
                bfr[j] = *(const bf16x8*)&SM[buf][(BM + wc * WCC + j * 16 + lr) * 64 + sa];
#pragma unroll
            for (int i = 0; i < MI; ++i)
#pragma unroll
                for (int j = 0; j < NJ; ++j)
                    acc[i][j] = __builtin_amdgcn_mfma_f32_16x16x32_bf16(af[i], bfr[j], acc[i][j], 0, 0, 0);
        }
        __builtin_amdgcn_s_barrier();
        buf ^= 1;
    }

#pragma unroll
    for (int i = 0; i < MI; ++i) {
#pragma unroll
        for (int j = 0; j < NJ; ++j) {
            const int col = n0 + wc * WCC + j * 16 + lr;
            const int row0 = m0 + wr * WRR + i * 16 + lhi * 4;
            if (MODE == 0) {
                const float bv = bias1[col];
#pragma unroll
                for (int r = 0; r < 4; ++r) {
                    const int row = row0 + r;
                    const size_t idx = (size_t)row * N + col;
                    float v = acc[i][j][r] + bv;
                    if (HAS_RES) v += res[idx] * resScale;
                    if (GELU_EPI) v = 0.5f * v * (1.0f + erff(v * 0.70710678118654752f));
                    v *= outScale;
                    if (OUT_BF16) ((bf16*)o1)[idx] = (bf16)v;
                    else          ((float*)o1)[idx] = v;
                }
            } else {
                const int sec = col >> 10, cl = col & 1023;
                const bool isV = (sec == 1);
                const float bv = (sec == 0 ? bias1 : bias2)[cl];
                if (!isV) {
                    bf16* dst = (bf16*)o1;
#pragma unroll
                    for (int r = 0; r < 4; ++r)
                        dst[(size_t)(row0 + r) * H_DIM + cl] = (bf16)(acc[i][j][r] + bv);
                } else {
                    bf16* dst = (bf16*)o2;
                    const int S = 1 << slog2;
                    const int hI = cl >> 6, dI = cl & 63;
                    const int bI = row0 >> slog2, s0 = row0 & (S - 1);
                    bf16x4 ov;
#pragma unroll
                    for (int r = 0; r < 4; ++r) ov[r] = (bf16)(acc[i][j][r] + bv);
                    *(bf16x4*)(dst + ((size_t)((bI * NHEAD + hI) * HD + dI)) * S + s0) = ov;
                }
            }
        }
    }
}

// ---------------- fp8 QKV GEMM: 32x32x16 fp8 MFMA, dbuf + counted vmcnt ----------------
__global__ __launch_bounds__(256) void gemm_qkv_fp8(const unsigned char* __restrict__ A8,
                                                    const unsigned char* __restrict__ B8,
                                                    const float* __restrict__ bias1,
                                                    const float* __restrict__ bias2,
                                                    const float* __restrict__ bias3,
                                                    bf16* __restrict__ Qo, bf16* __restrict__ Ko,
                                                    bf16* __restrict__ Vo) {
    constexpr int Kd = 1024;
    __shared__ unsigned char SM[2][256 * 64];
    const int nwg = gridDim.x * gridDim.y;
    const int dlin = blockIdx.y * gridDim.x + blockIdx.x;
    const int id = (dlin & 7) * (nwg >> 3) + (dlin >> 3);
    const int bx = id % gridDim.x, by = id / gridDim.x;
    const int m0 = by * 128, n0 = bx * 128;
    const int tid = threadIdx.x;
    const int wave = tid >> 6, lane = tid & 63;
    const int l31 = lane & 31, l5 = lane >> 5;
    const int wr = wave >> 1, wc = wave & 1;
    const int srow = wave * 16 + (lane >> 2);
    const int sunit = (((lane & 3) ^ ((srow >> 1) & 3)) << 4);
    const int rxc = (l31 >> 1) & 3;

    f32x16 acc[2][2] = {};

    auto stage = [&](int buf, int k0) {
#pragma unroll
        for (int p = 0; p < 4; ++p) {
            const int rr = p * 64 + srow;
            unsigned char* l = &SM[buf][0] + p * 4096 + wave * 1024;
            const unsigned char* g = (p < 2)
                ? (A8 + (size_t)(m0 + rr) * Kd + k0 + sunit)
                : (B8 + (size_t)(n0 + rr - 128) * Kd + k0 + sunit);
            gload_lds16_u8(g, l);
        }
    };

    stage(0, 0);
    int buf = 0;
    for (int k0 = 0; k0 < Kd; k0 += 64) {
        const bool pre = (k0 + 64 < Kd);
        if (pre) {
            stage(buf ^ 1, k0 + 64);
            asm volatile("s_waitcnt vmcnt(4)" ::: "memory");
        } else {
            asm volatile("s_waitcnt vmcnt(0)" ::: "memory");
        }
        __builtin_amdgcn_sched_barrier(0);
        __builtin_amdgcn_s_barrier();
#pragma unroll
        for (int kk = 0; kk < 4; ++kk) {
            const int sa = (((kk ^ rxc) << 4) + l5 * 8);
            long long af[2], bfr[2];
#pragma unroll
            for (int i = 0; i < 2; ++i)
                af[i] = *(const long long*)&SM[buf][(wr * 64 + i * 32 + l31) * 64 + sa];
#pragma unroll
            for (int j = 0; j < 2; ++j)
                bfr[j] = *(const long long*)&SM[buf][(128 + wc * 64 + j * 32 + l31) * 64 + sa];
#pragma unroll
            for (int i = 0; i < 2; ++i)
#pragma unroll
                for (int j = 0; j < 2; ++j)
                    acc[i][j] = __builtin_amdgcn_mfma_f32_32x32x16_fp8_fp8(af[i], bfr[j], acc[i][j], 0, 0, 0);
        }
        __builtin_amdgcn_s_barrier();
        buf ^= 1;
    }

#pragma unroll
    for (int i = 0; i < 2; ++i) {
#pragma unroll
        for (int j = 0; j < 2; ++j) {
            const int col = n0 + wc * 64 + j * 32 + l31;
            const int rbase = m0 + wr * 64 + i * 32 + l5 * 4;
            const int sec = col >> 10, cl = col & 1023;
            const float bv = (sec == 0 ? bias1 : sec == 1 ? bias2 : bias3)[cl];
            if (sec < 2) {
                bf16* dst = (sec == 0) ? Qo : Ko;
                const float sc = (sec == 0) ? QSCL : 1.f;
#pragma unroll
                for (int rq = 0; rq < 4; ++rq)
#pragma unroll
                    for (int rr = 0; rr < 4; ++rr) {
                        const int row = rbase + rq * 8 + rr;
                        dst[(size_t)row * H_DIM + cl] = (bf16)((acc[i][j][rq * 4 + rr] + bv) * sc);
                    }
            } else {
                const int hI = cl >> 6, dI = cl & 63;
#pragma unroll
                for (int rq = 0; rq < 4; ++rq) {
                    const int row0 = rbase + rq * 8;
                    const int bI = row0 >> 11, s0 = row0 & 2047;
                    bf16x4 ov;
#pragma unroll
                    for (int rr = 0; rr < 4; ++rr) ov[rr] = (bf16)(acc[i][j][rq * 4 + rr] + bv);
                    *(bf16x4*)(Vo + ((size_t)((bI * NHEAD + hI) * HD + dI)) * 2048 + s0) = ov;
                }
            }
        }
    }
}

// ---------------- fp8 plain GEMM (score-path only): A8 x B8^T -> bf16*QSCL ----------------
__global__ __launch_bounds__(256) void gemm_f8q(const unsigned char* __restrict__ A8,
                                                const unsigned char* __restrict__ B8,
                                                const float* __restrict__ bias,
                                                bf16* __restrict__ o1, int M, int NOUT) {
    constexpr int Kd = 1024;
    __shared__ unsigned char SM[2][256 * 64];
    const int nwg = gridDim.x * gridDim.y;
    const int dlin = blockIdx.y * gridDim.x + blockIdx.x;
    const int id = (dlin & 7) * (nwg >> 3) + (dlin >> 3);
    const int bx = id % gridDim.x, by = id / gridDim.x;
    const int m0 = by * 128, n0 = bx * 128;
    const int tid = threadIdx.x;
    const int wave = tid >> 6, lane = tid & 63;
    const int l31 = lane & 31, l5 = lane >> 5;
    const int wr = wave >> 1, wc = wave & 1;
    const int srow = wave * 16 + (lane >> 2);
    const int sunit = (((lane & 3) ^ ((srow >> 1) & 3)) << 4);
    const int rxc = (l31 >> 1) & 3;

    f32x16 acc[2][2] = {};

    auto stage = [&](int buf, int k0) {
#pragma unroll
        for (int p = 0; p < 4; ++p) {
            const int rr = p * 64 + srow;
            unsigned char* l = &SM[buf][0] + p * 4096 + wave * 1024;
            const unsigned char* g = (p < 2)
                ? (A8 + (size_t)(m0 + rr) * Kd + k0 + sunit)
                : (B8 + (size_t)(n0 + rr - 128) * Kd + k0 + sunit);
            gload_lds16_u8(g, l);
        }
    };

    stage(0, 0);
    int buf = 0;
    for (int k0 = 0; k0 < Kd; k0 += 64) {
        const bool pre = (k0 + 64 < Kd);
        if (pre) {
            stage(buf ^ 1, k0 + 64);
            asm volatile("s_waitcnt vmcnt(4)" ::: "memory");
        } else {
            asm volatile("s_waitcnt vmcnt(0)" ::: "memory");
        }
        __builtin_amdgcn_sched_barrier(0);
        __builtin_amdgcn_s_barrier();
#pragma unroll
        for (int kk = 0; kk < 4; ++kk) {
            const int sa = (((kk ^ rxc) << 4) + l5 * 8);
            long long af[2], bfr[2];
#pragma unroll
            for (int i = 0; i < 2; ++i)
                af[i] = *(const long long*)&SM[buf][(wr * 64 + i * 32 + l31) * 64 + sa];
#pragma unroll
            for (int j = 0; j < 2; ++j)
                bfr[j] = *(const long long*)&SM[buf][(128 + wc * 64 + j * 32 + l31) * 64 + sa];
#pragma unroll
            for (int i = 0; i < 2; ++i)
#pragma unroll
                for (int j = 0; j < 2; ++j)
                    acc[i][j] = __builtin_amdgcn_mfma_f32_32x32x16_fp8_fp8(af[i], bfr[j], acc[i][j], 0, 0, 0);
        }
        __builtin_amdgcn_s_barrier();
        buf ^= 1;
    }

#pragma unroll
    for (int i = 0; i < 2; ++i) {
#pragma unroll
        for (int j = 0; j < 2; ++j) {
            const int col = n0 + wc * 64 + j * 32 + l31;
            const int rbase = m0 + wr * 64 + i * 32 + l5 * 4;
            const float bv = bias[col];
#pragma unroll
            for (int rq = 0; rq < 4; ++rq)
#pragma unroll
                for (int rr = 0; rr < 4; ++rr) {
                    const int row = rbase + rq * 8 + rr;
                    o1[(size_t)row * NOUT + col] = (bf16)((acc[i][j][rq * 4 + rr] + bv) * QSCL);
                }
        }
    }
}

// ---------------- flash attention v10 (unchanged): raw v_exp_f32 + setprio ----------------
__global__ __launch_bounds__(256) void attn_kernel(const bf16* __restrict__ Qb,
                                                   const bf16* __restrict__ Kb,
                                                   const bf16* __restrict__ Vt_g,
                                                   bf16* __restrict__ Ob,
                                                   int SQ, int SK) {
    __shared__ bf16 SMEM[2][2][64 * 64];
    const int nwg = gridDim.x * gridDim.y;
    const int dlin = blockIdx.y * gridDim.x + blockIdx.x;
    const int id = (dlin & 7) * (nwg >> 3) + (dlin >> 3);
    const int NQ = gridDim.y;
    const int bh = id / NQ, qt = id - bh * NQ;
    const int b = bh >> 4, h = bh & 15;
    const int q0 = qt * 128;
    const int tid = threadIdx.x, wave = tid >> 6, lane = tid & 63;
    const int lr = lane & 15, lhi = lane >> 4;

    bf16x8 qf[2][2];
#pragma unroll
    for (int qi = 0; qi < 2; ++qi) {
        const bf16* qp = Qb + ((size_t)b * SQ + q0 + wave * 32 + qi * 16 + lr) * H_DIM + h * HD;
        qf[qi][0] = *(const bf16x8*)(qp + lhi * 8);
        qf[qi][1] = *(const bf16x8*)(qp + 32 + lhi * 8);
    }

    const int kx = (((lr & 3) | (((lr >> 2) & 1) << 2)) << 3);
    const int vx = (((lr & 3) | (((lr >> 3) & 1) << 2)) << 3);
    int krow[4];
#pragma unroll
    for (int nf = 0; nf < 4; ++nf)
        krow[nf] = (nf >> 1) * 32 + (lr >> 2) * 8 + (nf & 1) * 4 + (lr & 3);

    const int rS = tid >> 3, cS = (tid & 7) * 8;
    const int kxw = (((rS & 3) | (((rS >> 3) & 1) << 2)) << 3);
    const bf16* Kg = Kb + (size_t)b * SK * H_DIM + h * HD;
    const bf16* Vg = Vt_g + (size_t)bh * 64 * SK;

    bf16x8 onesv;
#pragma unroll
    for (int j = 0; j < 8; ++j) onesv[j] = (bf16)1.0f;

    f32x4 o[2][4] = {};
    f32x4 psum[2] = {};
    bf16x8 gK[2], gV[2];

    auto LOADG = [&](int kb) {
#pragma unroll
        for (int p = 0; p < 2; ++p) {
            gK[p] = *(const bf16x8*)(Kg + (size_t)(kb + p * 32 + rS) * H_DIM + cS);
            gV[p] = *(const bf16x8*)(Vg + (size_t)(p * 32 + rS) * SK + kb + cS);
        }
    };
    auto STORES = [&](int buf) {
#pragma unroll
        for (int p = 0; p < 2; ++p) {
            *(bf16x8*)&SMEM[buf][0][(p * 32 + rS) * 64 + (cS ^ kxw)] = gK[p];
            *(bf16x8*)&SMEM[buf][1][(p * 32 + rS) * 64 + (cS ^ kxw)] = gV[p];
        }
    };
    auto COMPUTE = [&](int buf) {
        f32x4 s[2][4] = {};
        __builtin_amdgcn_s_setprio(1);
#pragma unroll
        for (int nf = 0; nf < 4; ++nf) {
            const int base = krow[nf] * 64;
            bf16x8 kf0 = *(const bf16x8*)&SMEM[buf][0][base + ((lhi * 8) ^ kx)];
            bf16x8 kf1 = *(const bf16x8*)&SMEM[buf][0][base + ((32 + lhi * 8) ^ kx)];
#pragma unroll
            for (int qi = 0; qi < 2; ++qi) {
                s[qi][nf] = __builtin_amdgcn_mfma_f32_16x16x32_bf16(kf0, qf[qi][0], s[qi][nf], 0, 0, 0);
                s[qi][nf] = __builtin_amdgcn_mfma_f32_16x16x32_bf16(kf1, qf[qi][1], s[qi][nf], 0, 0, 0);
            }
        }
        __builtin_amdgcn_s_setprio(0);
        unsigned pw[2][8];
#pragma unroll
        for (int qi = 0; qi < 2; ++qi)
#pragma unroll
            for (int nf = 0; nf < 4; ++nf) {
                float p0 = fexp2(s[qi][nf][0]);
                float p1 = fexp2(s[qi][nf][1]);
                float p2 = fexp2(s[qi][nf][2]);
                float p3 = fexp2(s[qi][nf][3]);
                pw[qi][nf * 2]     = cvtpk_bf16(p0, p1);
                pw[qi][nf * 2 + 1] = cvtpk_bf16(p2, p3);
            }
        __builtin_amdgcn_s_setprio(1);
#pragma unroll
        for (int kk = 0; kk < 2; ++kk) {
            bf16x8 pb[2];
#pragma unroll
            for (int qi = 0; qi < 2; ++qi) {
                int4v w = { (int)pw[qi][kk * 4], (int)pw[qi][kk * 4 + 1],
                            (int)pw[qi][kk * 4 + 2], (int)pw[qi][kk * 4 + 3] };
                pb[qi] = __builtin_bit_cast(bf16x8, w);
                psum[qi] = __builtin_amdgcn_mfma_f32_16x16x32_bf16(onesv, pb[qi], psum[qi], 0, 0, 0);
            }
#pragma unroll
            for (int df = 0; df < 4; ++df) {
                bf16x8 vf = *(const bf16x8*)&SMEM[buf][1][(df * 16 + lr) * 64 + ((kk * 32 + lhi * 8) ^ vx)];
                o[0][df] = __builtin_amdgcn_mfma_f32_16x16x32_bf16(vf, pb[0], o[0][df], 0, 0, 0);
                o[1][df] = __builtin_amdgcn_mfma_f32_16x16x32_bf16(vf, pb[1], o[1][df], 0, 0, 0);
            }
        }
        __builtin_amdgcn_s_setprio(0);
    };

    const int nt = SK >> 6;
    LOADG(0);
    STORES(0);
    if (nt > 1) LOADG(64);
    __syncthreads();
    for (int t = 0; t < nt; ++t) {
        COMPUTE(t & 1);
        if (t + 1 < nt) {
            STORES((t + 1) & 1);
            if (t + 2 < nt) LOADG((t + 2) << 6);
        }
        __syncthreads();
    }

    bf16* T = &SMEM[0][0][0] + wave * (32 * 72);
#pragma unroll
    for (int qi = 0; qi < 2; ++qi) {
        const float inv = 1.0f / psum[qi][0];
#pragma unroll
        for (int df = 0; df < 4; ++df)
#pragma unroll
            for (int r = 0; r < 4; ++r)
                T[(qi * 16 + lr) * 72 + df * 16 + lhi * 4 + r] = (bf16)(o[qi][df][r] * inv);
    }
#pragma unroll
    for (int pp = 0; pp < 4; ++pp) {
        const int r32 = pp * 8 + (lane >> 3), ch = (lane & 7) * 8;
        bf16x8 v = *(const bf16x8*)&T[r32 * 72 + ch];
        *(bf16x8*)(Ob + ((size_t)b * SQ + q0 + wave * 32 + r32) * H_DIM + h * HD + ch) = v;
    }
}

extern "C" void kernel_launch(void* const* d_in, const int* in_sizes, int n_in,
                              void* d_out, int out_size, void* d_ws, size_t ws_size,
                              hipStream_t stream) {
    const float* x    = (const float*)d_in[0];
    const float* img  = (const float*)d_in[1];
    const float* W_sq = (const float*)d_in[2];   const float* b_sq = (const float*)d_in[3];
    const float* W_sk = (const float*)d_in[4];   const float* b_sk = (const float*)d_in[5];
    const float* W_sv = (const float*)d_in[6];   const float* b_sv = (const float*)d_in[7];
    const float* W_so = (const float*)d_in[8];   const float* b_so = (const float*)d_in[9];
    const float* W_cq = (const float*)d_in[10];  const float* b_cq = (const float*)d_in[11];
    const float* W_ck = (const float*)d_in[12];  const float* b_ck = (const float*)d_in[13];
    const float* W_cv = (const float*)d_in[14];  const float* b_cv = (const float*)d_in[15];
    const float* W_co = (const float*)d_in[16];  const float* b_co = (const float*)d_in[17];
    const float* W_f1 = (const float*)d_in[18];  const float* b_f1 = (const float*)d_in[19];
    const float* W_f2 = (const float*)d_in[20];  const float* b_f2 = (const float*)d_in[21];
    const float* g1 = (const float*)d_in[22];    const float* bb1 = (const float*)d_in[23];
    const float* g2 = (const float*)d_in[24];    const float* bb2 = (const float*)d_in[25];
    const float* g3 = (const float*)d_in[26];    const float* bb3 = (const float*)d_in[27];

    char* ws = (char*)d_ws;
    const size_t MB = 1ull << 20;
    // scratch map (bytes):
    //  0-4    LN2 fp8 out [4096][1024]
    //  4-5    w_cq fp8 [1024][1024]
    //  6-8    w_so bf16 | 10-12 w_ck | 12-14 w_cv | 14-16 w_co
    //  16-24  w_f1 bf16 [4096][1024]
    //  24-32  w_f2 bf16 [1024][4096]
    //  32-48  XR fp32 | 48-56 NX bf16
    //  56-64 Qb | 64-72 Kb | 72-80 Vt | 80-83 W8 qkv fp8 | 83-87 NX8 ln1 fp8
    //  56-88  FF bf16 (after attention; overlaps dead Qb/Kb/Vt/W8/NX8)
    //  88+    IMGB
    unsigned char* LN2_8 = (unsigned char*)(ws + 0 * MB);
    unsigned char* wcq8  = (unsigned char*)(ws + 4 * MB);
    bf16* WT   = (bf16*)ws;
    bf16* w_so = WT + 3 * (1u << 20);
    bf16* w_ck = WT + 5 * (1u << 20);
    bf16* w_cv = WT + 6 * (1u << 20);
    bf16* w_co = WT + 7 * (1u << 20);
    bf16* w_f1 = WT + 8 * (1u << 20);
    bf16* w_f2 = WT + 12 * (1u << 20);
    float* XR  = (float*)(ws + 32 * MB);
    bf16* NX   = (bf16*)(ws + 48 * MB);
    bf16* Qb   = (bf16*)(ws + 56 * MB);
    bf16* Kb   = (bf16*)(ws + 64 * MB);
    bf16* Vt   = (bf16*)(ws + 72 * MB);
    bf16* FF   = (bf16*)(ws + 56 * MB);
    unsigned char* W8  = (unsigned char*)(ws + 80 * MB);
    unsigned char* NX8 = (unsigned char*)(ws + 83 * MB);
    bf16* IMGB = (bf16*)(ws + 88 * MB);

    const dim3 blk(256);

    WPtrs wp;
    wp.w[0] = W_so; wp.o[0] = w_so;  wp.w[1] = W_ck; wp.o[1] = w_ck;
    wp.w[2] = W_cv; wp.o[2] = w_cv;  wp.w[3] = W_co; wp.o[3] = w_co;
    wconv4_kernel<<<dim3(16, 16, 4), blk, 0, stream>>>(wp);
    W3Ptrs w3; w3.w[0] = W_sq; w3.w[1] = W_sk; w3.w[2] = W_sv;
    wconv_fp8_kernel<<<dim3(16, 16, 3), blk, 0, stream>>>(w3, W8);
    wconv_fp8g<<<dim3(16, 16), blk, 0, stream>>>(W_cq, wcq8, 1024);
    wconv_kernel<<<dim3(64, 16), blk, 0, stream>>>(W_f1, w_f1, 1024, 4096);
    wconv_kernel<<<dim3(16, 64), blk, 0, stream>>>(W_f2, w_f2, 4096, 1024);

    // ---- self attention ----
    ln_fp8_kernel<<<4096, blk, 0, stream>>>(x, 0.1f, g1, bb1, (unsigned*)NX8);
    gemm_qkv_fp8<<<dim3(24, 32), blk, 0, stream>>>(NX8, W8, b_sq, b_sk, b_sv, Qb, Kb, Vt);
    attn_kernel<<<dim3(32, 16), blk, 0, stream>>>(Qb, Kb, Vt, NX, 2048, 2048);
    gemm_kernel<64, 128, 0, false, false, true><<<dim3(8, 64), blk, 0, stream>>>(
        NX, w_so, b_so, nullptr, nullptr, x, XR, nullptr, nullptr, 4096, 1024, 1024, 0.1f, 1.f, 0);

    // ---- cross attention ----
    ln_fp8_kernel<<<4096, blk, 0, stream>>>(XR, 1.f, g2, bb2, (unsigned*)LN2_8);
    gemm_f8q<<<dim3(8, 32), blk, 0, stream>>>(LN2_8, wcq8, b_cq, Qb, 4096, 1024);
    cvt_scale_kernel<<<dim3(512), blk, 0, stream>>>(img, IMGB, 0.1f, 131072);
    gemm_kernel<64, 128, 2, true, false, false><<<dim3(16, 8), blk, 0, stream>>>(
        IMGB, w_ck, b_ck, b_cv, nullptr, nullptr, Kb, Vt, nullptr, 512, 2048, 1024, 0.f, 1.f, 8);
    attn_kernel<<<dim3(32, 16), blk, 0, stream>>>(Qb, Kb, Vt, NX, 2048, 256);
    gemm_kernel<64, 128, 0, false, false, true><<<dim3(8, 64), blk, 0, stream>>>(
        NX, w_co, b_co, nullptr, nullptr, XR, XR, nullptr, nullptr, 4096, 1024, 1024, 1.f, 1.f, 0);

    // ---- feed forward ----
    ln_kernel<<<4096, blk, 0, stream>>>(XR, 1.f, g3, bb3, NX);
    gemm_kernel<128, 128, 0, true, true, false><<<dim3(32, 32), blk, 0, stream>>>(
        NX, w_f1, b_f1, nullptr, nullptr, nullptr, FF, nullptr, nullptr, 4096, 4096, 1024, 0.f, 1.f, 0);
    gemm_kernel<64, 128, 0, false, false, true><<<dim3(8, 64), blk, 0, stream>>>(
        FF, w_f2, b_f2, nullptr, nullptr, XR, d_out, nullptr, nullptr, 4096, 1024, 4096, 1.f, 10.f, 0);
}

// Round 22
// 261.757 us; speedup vs baseline: 1.2371x; 1.0041x over previous
//
#include <hip/hip_runtime.h>
#include <hip/hip_bf16.h>

typedef __bf16 bf16;
typedef __bf16 bf16x4 __attribute__((ext_vector_type(4)));
typedef __bf16 bf16x8 __attribute__((ext_vector_type(8)));
typedef float  f32x4  __attribute__((ext_vector_type(4)));
typedef float  f32x16 __attribute__((ext_vector_type(16)));
typedef int    int4v  __attribute__((ext_vector_type(4)));

#define H_DIM 1024
#define NHEAD 16
#define HD    64
#define QSCL 0.18033688011112042f

__device__ __forceinline__ void gload_lds16(const bf16* g, bf16* l) {
    __builtin_amdgcn_global_load_lds((const __attribute__((address_space(1))) void*)g,
                                     (__attribute__((address_space(3))) void*)l, 16, 0, 0);
}
__device__ __forceinline__ void gload_lds16_u8(const unsigned char* g, unsigned char* l) {
    __builtin_amdgcn_global_load_lds((const __attribute__((address_space(1))) void*)g,
                                     (__attribute__((address_space(3))) void*)l, 16, 0, 0);
}

__device__ __forceinline__ unsigned cvtpk_bf16(float lo, float hi) {
    unsigned r;
    asm volatile("v_cvt_pk_bf16_f32 %0, %1, %2" : "=v"(r) : "v"(lo), "v"(hi));
    return r;
}
__device__ __forceinline__ unsigned cvt2_fp8(float a, float b) {
    unsigned r;
    asm volatile("v_cvt_pk_fp8_f32 %0, %1, %2" : "=v"(r) : "v"(a), "v"(b));
    return r & 0xffffu;
}
__device__ __forceinline__ unsigned pack4_fp8(float a, float b, float c, float d) {
    return cvt2_fp8(a, b) | (cvt2_fp8(c, d) << 16);
}
__device__ __forceinline__ float fexp2(float x) {
    float r;
    asm("v_exp_f32 %0, %1" : "=v"(r) : "v"(x));
    return r;
}

// ---------------- weight fp32 [K][N] -> bf16 [N][K] (transpose+convert) ----------------
__device__ __forceinline__ void wconv_body(const float* __restrict__ W,
                                           bf16* __restrict__ Wt, int K, int N,
                                           int bx, int by, int t) {
    __shared__ float tile[64][65];
    const int n0 = bx * 64, k0 = by * 64;
#pragma unroll
    for (int p = 0; p < 4; ++p) {
        int lin = p * 1024 + t * 4;
        int r = lin >> 6, c = lin & 63;
        f32x4 v = *(const f32x4*)(W + (size_t)(k0 + r) * N + n0 + c);
        tile[r][c]     = v[0];
        tile[r][c + 1] = v[1];
        tile[r][c + 2] = v[2];
        tile[r][c + 3] = v[3];
    }
    __syncthreads();
#pragma unroll
    for (int p = 0; p < 4; ++p) {
        int lin = p * 1024 + t * 4;
        int rn = lin >> 6, ck = lin & 63;
        bf16x4 o;
#pragma unroll
        for (int j = 0; j < 4; ++j) o[j] = (bf16)tile[ck + j][rn];
        *(bf16x4*)(Wt + (size_t)(n0 + rn) * K + k0 + ck) = o;
    }
}

__global__ __launch_bounds__(256) void wconv_kernel(const float* __restrict__ W,
                                                    bf16* __restrict__ Wt,
                                                    int K, int N) {
    wconv_body(W, Wt, K, N, blockIdx.x, blockIdx.y, threadIdx.x);
}

struct WPtrs { const float* w[4]; bf16* o[4]; };
__global__ __launch_bounds__(256) void wconv4_kernel(WPtrs p) {
    const int m = blockIdx.z;
    wconv_body(p.w[m], p.o[m], 1024, 1024, blockIdx.x, blockIdx.y, threadIdx.x);
}

struct W3Ptrs { const float* w[3]; };
__global__ __launch_bounds__(256) void wconv_fp8_kernel(W3Ptrs p, unsigned char* __restrict__ out) {
    __shared__ float tile[64][65];
    const int m = blockIdx.z, t = threadIdx.x;
    const float* W = p.w[m];
    unsigned char* Wt = out + (size_t)m * 1024 * 1024;
    const int n0 = blockIdx.x * 64, k0 = blockIdx.y * 64;
#pragma unroll
    for (int pp = 0; pp < 4; ++pp) {
        int lin = pp * 1024 + t * 4;
        int r = lin >> 6, c = lin & 63;
        f32x4 v = *(const f32x4*)(W + (size_t)(k0 + r) * 1024 + n0 + c);
        tile[r][c]     = v[0];
        tile[r][c + 1] = v[1];
        tile[r][c + 2] = v[2];
        tile[r][c + 3] = v[3];
    }
    __syncthreads();
#pragma unroll
    for (int pp = 0; pp < 4; ++pp) {
        int lin = pp * 1024 + t * 4;
        int rn = lin >> 6, ck = lin & 63;
        unsigned u = pack4_fp8(tile[ck][rn], tile[ck + 1][rn], tile[ck + 2][rn], tile[ck + 3][rn]);
        *(unsigned*)&Wt[(size_t)(n0 + rn) * 1024 + k0 + ck] = u;
    }
}

__global__ __launch_bounds__(256) void wconv_fp8g(const float* __restrict__ W,
                                                  unsigned char* __restrict__ Wt, int N) {
    __shared__ float tile[64][65];
    const int t = threadIdx.x;
    const int n0 = blockIdx.x * 64, k0 = blockIdx.y * 64;
#pragma unroll
    for (int pp = 0; pp < 4; ++pp) {
        int lin = pp * 1024 + t * 4;
        int r = lin >> 6, c = lin & 63;
        f32x4 v = *(const f32x4*)(W + (size_t)(k0 + r) * N + n0 + c);
        tile[r][c]     = v[0];
        tile[r][c + 1] = v[1];
        tile[r][c + 2] = v[2];
        tile[r][c + 3] = v[3];
    }
    __syncthreads();
#pragma unroll
    for (int pp = 0; pp < 4; ++pp) {
        int lin = pp * 1024 + t * 4;
        int rn = lin >> 6, ck = lin & 63;
        unsigned u = pack4_fp8(tile[ck][rn], tile[ck + 1][rn], tile[ck + 2][rn], tile[ck + 3][rn]);
        *(unsigned*)&Wt[(size_t)(n0 + rn) * 1024 + k0 + ck] = u;
    }
}

// ---------------- layernorm (fp32 in, bf16 out) ----------------
__global__ __launch_bounds__(256) void ln_kernel(const float* __restrict__ in, float inScale,
                                                 const float* __restrict__ g,
                                                 const float* __restrict__ b,
                                                 bf16* __restrict__ out) {
    const int row = blockIdx.x, t = threadIdx.x;
    const float* p = in + (size_t)row * H_DIM;
    f32x4 v = *(const f32x4*)(p + t * 4);
    v *= inScale;
    float s1 = v[0] + v[1] + v[2] + v[3];
    float s2 = v[0] * v[0] + v[1] * v[1] + v[2] * v[2] + v[3] * v[3];
#pragma unroll
    for (int m = 1; m < 64; m <<= 1) {
        s1 += __shfl_xor(s1, m);
        s2 += __shfl_xor(s2, m);
    }
    __shared__ float red[8];
    const int wave = t >> 6;
    if ((t & 63) == 0) { red[wave * 2] = s1; red[wave * 2 + 1] = s2; }
    __syncthreads();
    s1 = red[0] + red[2] + red[4] + red[6];
    s2 = red[1] + red[3] + red[5] + red[7];
    float mean = s1 * (1.0f / H_DIM);
    float var  = s2 * (1.0f / H_DIM) - mean * mean;
    float inv  = rsqrtf(var + 1e-5f);
    f32x4 gg = *(const f32x4*)(g + t * 4);
    f32x4 bb = *(const f32x4*)(b + t * 4);
    bf16x4 o;
#pragma unroll
    for (int j = 0; j < 4; ++j) o[j] = (bf16)((v[j] - mean) * inv * gg[j] + bb[j]);
    *(bf16x4*)(out + (size_t)row * H_DIM + t * 4) = o;
}

__global__ __launch_bounds__(256) void ln_fp8_kernel(const float* __restrict__ in, float inScale,
                                                     const float* __restrict__ g,
                                                     const float* __restrict__ b,
                                                     unsigned* __restrict__ out) {
    const int row = blockIdx.x, t = threadIdx.x;
    const float* p = in + (size_t)row * H_DIM;
    f32x4 v = *(const f32x4*)(p + t * 4);
    v *= inScale;
    float s1 = v[0] + v[1] + v[2] + v[3];
    float s2 = v[0] * v[0] + v[1] * v[1] + v[2] * v[2] + v[3] * v[3];
#pragma unroll
    for (int m = 1; m < 64; m <<= 1) {
        s1 += __shfl_xor(s1, m);
        s2 += __shfl_xor(s2, m);
    }
    __shared__ float red[8];
    const int wave = t >> 6;
    if ((t & 63) == 0) { red[wave * 2] = s1; red[wave * 2 + 1] = s2; }
    __syncthreads();
    s1 = red[0] + red[2] + red[4] + red[6];
    s2 = red[1] + red[3] + red[5] + red[7];
    float mean = s1 * (1.0f / H_DIM);
    float var  = s2 * (1.0f / H_DIM) - mean * mean;
    float inv  = rsqrtf(var + 1e-5f);
    f32x4 gg = *(const f32x4*)(g + t * 4);
    f32x4 bb = *(const f32x4*)(b + t * 4);
    float y0 = (v[0] - mean) * inv * gg[0] + bb[0];
    float y1 = (v[1] - mean) * inv * gg[1] + bb[1];
    float y2 = (v[2] - mean) * inv * gg[2] + bb[2];
    float y3 = (v[3] - mean) * inv * gg[3] + bb[3];
    out[row * 256 + t] = pack4_fp8(y0, y1, y2, y3);
}

__global__ __launch_bounds__(256) void cvt_scale_kernel(const float* __restrict__ in,
                                                        bf16* __restrict__ out,
                                                        float s, int n4) {
    int i = blockIdx.x * 256 + threadIdx.x;
    if (i < n4) {
        f32x4 v = *(const f32x4*)(in + (size_t)i * 4);
        bf16x4 o;
#pragma unroll
        for (int j = 0; j < 4; ++j) o[j] = (bf16)(v[j] * s);
        *(bf16x4*)(out + (size_t)i * 4) = o;
    }
}

// ---------------- GEMM v6 (bf16): 16x16x32 MFMA + XOR swizzle, dbuf + counted vmcnt ----
template <int BM, int BN, int MODE, bool OUT_BF16, bool GELU_EPI, bool HAS_RES>
__global__ __launch_bounds__(256) void gemm_kernel(const bf16* __restrict__ A,
                                                   const bf16* __restrict__ Bt,
                                                   const float* __restrict__ bias1,
                                                   const float* __restrict__ bias2,
                                                   const float* __restrict__ bias3,
                                                   const float* __restrict__ res,
                                                   void* __restrict__ o1, void* __restrict__ o2,
                                                   void* __restrict__ o3,
                                                   int M, int N, int K,
                                                   float resScale, float outScale, int slog2) {
    constexpr int CHUNKS = (BM + BN) / 32;
    constexpr int WRR = BM / 2, WCC = BN / 2;
    constexpr int MI = WRR / 16, NJ = WCC / 16;
    __shared__ bf16 SM[2][(BM + BN) * 64];
    const int nwg = gridDim.x * gridDim.y;
    const int dlin = blockIdx.y * gridDim.x + blockIdx.x;
    const int id = (dlin & 7) * (nwg >> 3) + (dlin >> 3);
    const int bx = id % gridDim.x, by = id / gridDim.x;
    const int m0 = by * BM, n0 = bx * BN;
    const int tid = threadIdx.x;
    const int wave = tid >> 6, lane = tid & 63;
    const int lr = lane & 15, lhi = lane >> 4;
    const int wr = wave >> 1, wc = wave & 1;
    const int sr = lane >> 3, sc8 = (lane & 7) * 8;
    const int sc8x = sc8 ^ (sr << 3);
    const int rxr = (lr & 7) << 3;

    f32x4 acc[MI][NJ] = {};

    auto stage = [&](int buf, int k0) {
#pragma unroll
        for (int p = 0; p < CHUNKS; ++p) {
            const int rr = p * 32 + wave * 8 + sr;
            bf16* l = &SM[buf][0] + p * 2048 + wave * 512;
            const bf16* g = (p < BM / 32)
                ? (A  + (size_t)(m0 + rr) * K + k0 + sc8x)
                : (Bt + (size_t)(n0 + rr - BM) * K + k0 + sc8x);
            gload_lds16(g, l);
        }
    };

    stage(0, 0);
    int buf = 0;
    for (int k0 = 0; k0 < K; k0 += 64) {
        const bool pre = (k0 + 64 < K);
        if (pre) {
            stage(buf ^ 1, k0 + 64);
            asm volatile("s_waitcnt vmcnt(%0)" :: "i"(CHUNKS) : "memory");
        } else {
            asm volatile("s_waitcnt vmcnt(0)" ::: "memory");
        }
        __builtin_amdgcn_sched_barrier(0);
        __builtin_amdgcn_s_barrier();
#pragma unroll
        for (int kk = 0; kk < 2; ++kk) {
            const int sa = (kk * 32 + lhi * 8) ^ rxr;
            bf16x8 af[MI], bfr[NJ];
#pragma unroll
            for (int i = 0; i < MI; ++i)
                af[i] = *(const bf16x8*)&SM[buf][(wr * WRR + i * 16 + lr) * 64 + sa];
#pragma unroll
            for (int j = 0; j < NJ; ++j)
                bfr[j] = *(const bf16x8*)&SM[buf][(BM + wc * WCC + j * 16 + lr) * 64 + sa];
#pragma unroll
            for (int i = 0; i < MI; ++i)
#pragma unroll
                for (int j = 0; j < NJ; ++j)
                    acc[i][j] = __builtin_amdgcn_mfma_f32_16x16x32_bf16(af[i], bfr[j], acc[i][j], 0, 0, 0);
        }
        __builtin_amdgcn_s_barrier();
        buf ^= 1;
    }

#pragma unroll
    for (int i = 0; i < MI; ++i) {
#pragma unroll
        for (int j = 0; j < NJ; ++j) {
            const int col = n0 + wc * WCC + j * 16 + lr;
            const int row0 = m0 + wr * WRR + i * 16 + lhi * 4;
            if (MODE == 0) {
                const float bv = bias1[col];
#pragma unroll
                for (int r = 0; r < 4; ++r) {
                    const int row = row0 + r;
                    const size_t idx = (size_t)row * N + col;
                    float v = acc[i][j][r] + bv;
                    if (HAS_RES) v += res[idx] * resScale;
                    if (GELU_EPI) v = 0.5f * v * (1.0f + erff(v * 0.70710678118654752f));
                    v *= outScale;
                    if (OUT_BF16) ((bf16*)o1)[idx] = (bf16)v;
                    else          ((float*)o1)[idx] = v;
                }
            } else {
                const int sec = col >> 10, cl = col & 1023;
                const bool isV = (sec == 1);
                const float bv = (sec == 0 ? bias1 : bias2)[cl];
                if (!isV) {
                    bf16* dst = (bf16*)o1;
#pragma unroll
                    for (int r = 0; r < 4; ++r)
                        dst[(size_t)(row0 + r) * H_DIM + cl] = (bf16)(acc[i][j][r] + bv);
                } else {
                    bf16* dst = (bf16*)o2;
                    const int S = 1 << slog2;
                    const int hI = cl >> 6, dI = cl & 63;
                    const int bI = row0 >> slog2, s0 = row0 & (S - 1);
                    bf16x4 ov;
#pragma unroll
                    for (int r = 0; r < 4; ++r) ov[r] = (bf16)(acc[i][j][r] + bv);
                    *(bf16x4*)(dst + ((size_t)((bI * NHEAD + hI) * HD + dI)) * S + s0) = ov;
                }
            }
        }
    }
}

// ---------------- FF1 8-phase 256x256 (T3+T4+T5): 512 thr, 128KB dyn LDS ----------------
// Per tile t (BK=64): 4 phases = quadrants (mh,nh) in order (0,0),(0,1),(1,0),(1,1);
// phase p stages half-tile stage_order[p]={A0,B0,B1,A1} of tile t+1 (2 gload_lds/wave).
// vmcnt(4) each phase (residency case-checked); tail drains 2,0,0,0. XOR swizzle as v6.
__global__ __launch_bounds__(512) void gemm_ff1_8ph(const bf16* __restrict__ A,
                                                    const bf16* __restrict__ Bt,
                                                    const float* __restrict__ bias,
                                                    bf16* __restrict__ out) {
    extern __shared__ bf16 SM[];                 // 2 bufs x 32768 elems (128 KB)
    constexpr int Kd = 1024, KT = 16;
    const int nwg = gridDim.x * gridDim.y;       // 256
    const int dlin = blockIdx.y * gridDim.x + blockIdx.x;
    const int id = (dlin & 7) * (nwg >> 3) + (dlin >> 3);
    const int bx = id % gridDim.x, by = id / gridDim.x;
    const int m0 = by * 256, n0 = bx * 256;
    const int tid = threadIdx.x;
    const int wave = tid >> 6, lane = tid & 63;
    const int lr = lane & 15, lhi = lane >> 4;
    const int wm = wave >> 2, wn = wave & 3;     // 2M x 4N waves
    const int rxr = (lr & 7) << 3;
    const int strow = tid >> 3;                  // 0..63 (chunk s adds 64)
    const int scol = (((tid & 7) << 3)) ^ (((tid >> 3) & 7) << 3);  // pre-swizzled src col

    f32x4 acc[8][4] = {};

    auto stageH = [&](int buf, const bf16* gp, int grow0, int kcol0, int region) {
#pragma unroll
        for (int s = 0; s < 2; ++s) {
            bf16* l = &SM[buf * 32768 + region + s * 4096 + wave * 512];
            gload_lds16(gp + (size_t)(grow0 + s * 64 + strow) * Kd + kcol0 + scol, l);
        }
    };
    // regions (elems): A0=0, A1=8192, B0=16384, B1=24576

    // prologue: tile 0 fully staged, full drain once
    stageH(0, A, m0, 0, 0);
    stageH(0, A, m0 + 128, 0, 8192);
    stageH(0, Bt, n0, 0, 16384);
    stageH(0, Bt, n0 + 128, 0, 24576);
    asm volatile("s_waitcnt vmcnt(0)" ::: "memory");
    __builtin_amdgcn_s_barrier();

    for (int t = 0; t < KT; ++t) {
        const int buf = t & 1;
        const int kn = (t + 1) * 64;
        const bool pre = (t + 1 < KT);
#pragma unroll
        for (int p = 0; p < 4; ++p) {
            const int mh = p >> 1, nh = p & 1;
            // 1. ds_read fragments for quadrant (mh,nh)
            bf16x8 af[4][2], bfr[2][2];
#pragma unroll
            for (int kk = 0; kk < 2; ++kk) {
                const int sa = (kk * 32 + lhi * 8) ^ rxr;
#pragma unroll
                for (int i = 0; i < 4; ++i)
                    af[i][kk] = *(const bf16x8*)&SM[buf * 32768 +
                        (wm * 128 + mh * 64 + i * 16 + lr) * 64 + sa];
#pragma unroll
                for (int j = 0; j < 2; ++j)
                    bfr[j][kk] = *(const bf16x8*)&SM[buf * 32768 + 16384 +
                        (wn * 64 + nh * 32 + j * 16 + lr) * 64 + sa];
            }
            // 2. stage one half-tile of t+1 (order A0, B0, B1, A1)
            if (pre) {
                if (p == 0)      stageH(buf ^ 1, A, m0, kn, 0);
                else if (p == 1) stageH(buf ^ 1, Bt, n0, kn, 16384);
                else if (p == 2) stageH(buf ^ 1, Bt, n0 + 128, kn, 24576);
                else             stageH(buf ^ 1, A, m0 + 128, kn, 8192);
            }
            // 3. counted vmcnt (never 0 in steady state)
            if (pre) {
                asm volatile("s_waitcnt vmcnt(4)" ::: "memory");
            } else {
                if (p == 0)      asm volatile("s_waitcnt vmcnt(2)" ::: "memory");
                else             asm volatile("s_waitcnt vmcnt(0)" ::: "memory");
            }
            // 4. barrier: all waves' needed half-tiles resident
            __builtin_amdgcn_s_barrier();
            // 5. drain ds_reads, pin MFMA after (rule #18)
            asm volatile("s_waitcnt lgkmcnt(0)" ::: "memory");
            __builtin_amdgcn_sched_barrier(0);
            // 6. MFMA cluster (T5)
            __builtin_amdgcn_s_setprio(1);
#pragma unroll
            for (int i = 0; i < 4; ++i)
#pragma unroll
                for (int j = 0; j < 2; ++j) {
                    acc[mh * 4 + i][nh * 2 + j] = __builtin_amdgcn_mfma_f32_16x16x32_bf16(
                        af[i][0], bfr[j][0], acc[mh * 4 + i][nh * 2 + j], 0, 0, 0);
                    acc[mh * 4 + i][nh * 2 + j] = __builtin_amdgcn_mfma_f32_16x16x32_bf16(
                        af[i][1], bfr[j][1], acc[mh * 4 + i][nh * 2 + j], 0, 0, 0);
                }
            __builtin_amdgcn_s_setprio(0);
            // 7. barrier: protect buf reuse across tile boundary
            __builtin_amdgcn_s_barrier();
        }
    }

    // epilogue: bias + GELU -> out[4096][4096]
#pragma unroll
    for (int i = 0; i < 8; ++i) {
#pragma unroll
        for (int j = 0; j < 4; ++j) {
            const int col = n0 + wn * 64 + j * 16 + lr;
            const int row0 = m0 + wm * 128 + i * 16 + lhi * 4;
            const float bv = bias[col];
#pragma unroll
            for (int r = 0; r < 4; ++r) {
                float v = acc[i][j][r] + bv;
                v = 0.5f * v * (1.0f + erff(v * 0.70710678118654752f));
                out[(size_t)(row0 + r) * 4096 + col] = (bf16)v;
            }
        }
    }
}

// ---------------- fp8 QKV GEMM ----------------
__global__ __launch_bounds__(256) void gemm_qkv_fp8(const unsigned char* __restrict__ A8,
                                                    const unsigned char* __restrict__ B8,
                                                    const float* __restrict__ bias1,
                                                    const float* __restrict__ bias2,
                                                    const float* __restrict__ bias3,
                                                    bf16* __restrict__ Qo, bf16* __restrict__ Ko,
                                                    bf16* __restrict__ Vo) {
    constexpr int Kd = 1024;
    __shared__ unsigned char SM[2][256 * 64];
    const int nwg = gridDim.x * gridDim.y;
    const int dlin = blockIdx.y * gridDim.x + blockIdx.x;
    const int id = (dlin & 7) * (nwg >> 3) + (dlin >> 3);
    const int bx = id % gridDim.x, by = id / gridDim.x;
    const int m0 = by * 128, n0 = bx * 128;
    const int tid = threadIdx.x;
    const int wave = tid >> 6, lane = tid & 63;
    const int l31 = lane & 31, l5 = lane >> 5;
    const int wr = wave >> 1, wc = wave & 1;
    const int srow = wave * 16 + (lane >> 2);
    const int sunit = (((lane & 3) ^ ((srow >> 1) & 3)) << 4);
    const int rxc = (l31 >> 1) & 3;

    f32x16 acc[2][2] = {};

    auto stage = [&](int buf, int k0) {
#pragma unroll
        for (int p = 0; p < 4; ++p) {
            const int rr = p * 64 + srow;
            unsigned char* l = &SM[buf][0] + p * 4096 + wave * 1024;
            const unsigned char* g = (p < 2)
                ? (A8 + (size_t)(m0 + rr) * Kd + k0 + sunit)
                : (B8 + (size_t)(n0 + rr - 128) * Kd + k0 + sunit);
            gload_lds16_u8(g, l);
        }
    };

    stage(0, 0);
    int buf = 0;
    for (int k0 = 0; k0 < Kd; k0 += 64) {
        const bool pre = (k0 + 64 < Kd);
        if (pre) {
            stage(buf ^ 1, k0 + 64);
            asm volatile("s_waitcnt vmcnt(4)" ::: "memory");
        } else {
            asm volatile("s_waitcnt vmcnt(0)" ::: "memory");
        }
        __builtin_amdgcn_sched_barrier(0);
        __builtin_amdgcn_s_barrier();
#pragma unroll
        for (int kk = 0; kk < 4; ++kk) {
            const int sa = (((kk ^ rxc) << 4) + l5 * 8);
            long long af[2], bfr[2];
#pragma unroll
            for (int i = 0; i < 2; ++i)
                af[i] = *(const long long*)&SM[buf][(wr * 64 + i * 32 + l31) * 64 + sa];
#pragma unroll
            for (int j = 0; j < 2; ++j)
                bfr[j] = *(const long long*)&SM[buf][(128 + wc * 64 + j * 32 + l31) * 64 + sa];
#pragma unroll
            for (int i = 0; i < 2; ++i)
#pragma unroll
                for (int j = 0; j < 2; ++j)
                    acc[i][j] = __builtin_amdgcn_mfma_f32_32x32x16_fp8_fp8(af[i], bfr[j], acc[i][j], 0, 0, 0);
        }
        __builtin_amdgcn_s_barrier();
        buf ^= 1;
    }

#pragma unroll
    for (int i = 0; i < 2; ++i) {
#pragma unroll
        for (int j = 0; j < 2; ++j) {
            const int col = n0 + wc * 64 + j * 32 + l31;
            const int rbase = m0 + wr * 64 + i * 32 + l5 * 4;
            const int sec = col >> 10, cl = col & 1023;
            const float bv = (sec == 0 ? bias1 : sec == 1 ? bias2 : bias3)[cl];
            if (sec < 2) {
                bf16* dst = (sec == 0) ? Qo : Ko;
                const float sc = (sec == 0) ? QSCL : 1.f;
#pragma unroll
                for (int rq = 0; rq < 4; ++rq)
#pragma unroll
                    for (int rr = 0; rr < 4; ++rr) {
                        const int row = rbase + rq * 8 + rr;
                        dst[(size_t)row * H_DIM + cl] = (bf16)((acc[i][j][rq * 4 + rr] + bv) * sc);
                    }
            } else {
                const int hI = cl >> 6, dI = cl & 63;
#pragma unroll
                for (int rq = 0; rq < 4; ++rq) {
                    const int row0 = rbase + rq * 8;
                    const int bI = row0 >> 11, s0 = row0 & 2047;
                    bf16x4 ov;
#pragma unroll
                    for (int rr = 0; rr < 4; ++rr) ov[rr] = (bf16)(acc[i][j][rq * 4 + rr] + bv);
                    *(bf16x4*)(Vo + ((size_t)((bI * NHEAD + hI) * HD + dI)) * 2048 + s0) = ov;
                }
            }
        }
    }
}

// ---------------- fp8 plain GEMM (score-path only): -> bf16*QSCL ----------------
__global__ __launch_bounds__(256) void gemm_f8q(const unsigned char* __restrict__ A8,
                                                const unsigned char* __restrict__ B8,
                                                const float* __restrict__ bias,
                                                bf16* __restrict__ o1, int M, int NOUT) {
    constexpr int Kd = 1024;
    __shared__ unsigned char SM[2][256 * 64];
    const int nwg = gridDim.x * gridDim.y;
    const int dlin = blockIdx.y * gridDim.x + blockIdx.x;
    const int id = (dlin & 7) * (nwg >> 3) + (dlin >> 3);
    const int bx = id % gridDim.x, by = id / gridDim.x;
    const int m0 = by * 128, n0 = bx * 128;
    const int tid = threadIdx.x;
    const int wave = tid >> 6, lane = tid & 63;
    const int l31 = lane & 31, l5 = lane >> 5;
    const int wr = wave >> 1, wc = wave & 1;
    const int srow = wave * 16 + (lane >> 2);
    const int sunit = (((lane & 3) ^ ((srow >> 1) & 3)) << 4);
    const int rxc = (l31 >> 1) & 3;

    f32x16 acc[2][2] = {};

    auto stage = [&](int buf, int k0) {
#pragma unroll
        for (int p = 0; p < 4; ++p) {
            const int rr = p * 64 + srow;
            unsigned char* l = &SM[buf][0] + p * 4096 + wave * 1024;
            const unsigned char* g = (p < 2)
                ? (A8 + (size_t)(m0 + rr) * Kd + k0 + sunit)
                : (B8 + (size_t)(n0 + rr - 128) * Kd + k0 + sunit);
            gload_lds16_u8(g, l);
        }
    };

    stage(0, 0);
    int buf = 0;
    for (int k0 = 0; k0 < Kd; k0 += 64) {
        const bool pre = (k0 + 64 < Kd);
        if (pre) {
            stage(buf ^ 1, k0 + 64);
            asm volatile("s_waitcnt vmcnt(4)" ::: "memory");
        } else {
            asm volatile("s_waitcnt vmcnt(0)" ::: "memory");
        }
        __builtin_amdgcn_sched_barrier(0);
        __builtin_amdgcn_s_barrier();
#pragma unroll
        for (int kk = 0; kk < 4; ++kk) {
            const int sa = (((kk ^ rxc) << 4) + l5 * 8);
            long long af[2], bfr[2];
#pragma unroll
            for (int i = 0; i < 2; ++i)
                af[i] = *(const long long*)&SM[buf][(wr * 64 + i * 32 + l31) * 64 + sa];
#pragma unroll
            for (int j = 0; j < 2; ++j)
                bfr[j] = *(const long long*)&SM[buf][(128 + wc * 64 + j * 32 + l31) * 64 + sa];
#pragma unroll
            for (int i = 0; i < 2; ++i)
#pragma unroll
                for (int j = 0; j < 2; ++j)
                    acc[i][j] = __builtin_amdgcn_mfma_f32_32x32x16_fp8_fp8(af[i], bfr[j], acc[i][j], 0, 0, 0);
        }
        __builtin_amdgcn_s_barrier();
        buf ^= 1;
    }

#pragma unroll
    for (int i = 0; i < 2; ++i) {
#pragma unroll
        for (int j = 0; j < 2; ++j) {
            const int col = n0 + wc * 64 + j * 32 + l31;
            const int rbase = m0 + wr * 64 + i * 32 + l5 * 4;
            const float bv = bias[col];
#pragma unroll
            for (int rq = 0; rq < 4; ++rq)
#pragma unroll
                for (int rr = 0; rr < 4; ++rr) {
                    const int row = rbase + rq * 8 + rr;
                    o1[(size_t)row * NOUT + col] = (bf16)((acc[i][j][rq * 4 + rr] + bv) * QSCL);
                }
        }
    }
}

// ---------------- flash attention v10: raw v_exp_f32 + setprio ----------------
__global__ __launch_bounds__(256) void attn_kernel(const bf16* __restrict__ Qb,
                                                   const bf16* __restrict__ Kb,
                                                   const bf16* __restrict__ Vt_g,
                                                   bf16* __restrict__ Ob,
                                                   int SQ, int SK) {
    __shared__ bf16 SMEM[2][2][64 * 64];
    const int nwg = gridDim.x * gridDim.y;
    const int dlin = blockIdx.y * gridDim.x + blockIdx.x;
    const int id = (dlin & 7) * (nwg >> 3) + (dlin >> 3);
    const int NQ = gridDim.y;
    const int bh = id / NQ, qt = id - bh * NQ;
    const int b = bh >> 4, h = bh & 15;
    const int q0 = qt * 128;
    const int tid = threadIdx.x, wave = tid >> 6, lane = tid & 63;
    const int lr = lane & 15, lhi = lane >> 4;

    bf16x8 qf[2][2];
#pragma unroll
    for (int qi = 0; qi < 2; ++qi) {
        const bf16* qp = Qb + ((size_t)b * SQ + q0 + wave * 32 + qi * 16 + lr) * H_DIM + h * HD;
        qf[qi][0] = *(const bf16x8*)(qp + lhi * 8);
        qf[qi][1] = *(const bf16x8*)(qp + 32 + lhi * 8);
    }

    const int kx = (((lr & 3) | (((lr >> 2) & 1) << 2)) << 3);
    const int vx = (((lr & 3) | (((lr >> 3) & 1) << 2)) << 3);
    int krow[4];
#pragma unroll
    for (int nf = 0; nf < 4; ++nf)
        krow[nf] = (nf >> 1) * 32 + (lr >> 2) * 8 + (nf & 1) * 4 + (lr & 3);

    const int rS = tid >> 3, cS = (tid & 7) * 8;
    const int kxw = (((rS & 3) | (((rS >> 3) & 1) << 2)) << 3);
    const bf16* Kg = Kb + (size_t)b * SK * H_DIM + h * HD;
    const bf16* Vg = Vt_g + (size_t)bh * 64 * SK;

    bf16x8 onesv;
#pragma unroll
    for (int j = 0; j < 8; ++j) onesv[j] = (bf16)1.0f;

    f32x4 o[2][4] = {};
    f32x4 psum[2] = {};
    bf16x8 gK[2], gV[2];

    auto LOADG = [&](int kb) {
#pragma unroll
        for (int p = 0; p < 2; ++p) {
            gK[p] = *(const bf16x8*)(Kg + (size_t)(kb + p * 32 + rS) * H_DIM + cS);
            gV[p] = *(const bf16x8*)(Vg + (size_t)(p * 32 + rS) * SK + kb + cS);
        }
    };
    auto STORES = [&](int buf) {
#pragma unroll
        for (int p = 0; p < 2; ++p) {
            *(bf16x8*)&SMEM[buf][0][(p * 32 + rS) * 64 + (cS ^ kxw)] = gK[p];
            *(bf16x8*)&SMEM[buf][1][(p * 32 + rS) * 64 + (cS ^ kxw)] = gV[p];
        }
    };
    auto COMPUTE = [&](int buf) {
        f32x4 s[2][4] = {};
        __builtin_amdgcn_s_setprio(1);
#pragma unroll
        for (int nf = 0; nf < 4; ++nf) {
            const int base = krow[nf] * 64;
            bf16x8 kf0 = *(const bf16x8*)&SMEM[buf][0][base + ((lhi * 8) ^ kx)];
            bf16x8 kf1 = *(const bf16x8*)&SMEM[buf][0][base + ((32 + lhi * 8) ^ kx)];
#pragma unroll
            for (int qi = 0; qi < 2; ++qi) {
                s[qi][nf] = __builtin_amdgcn_mfma_f32_16x16x32_bf16(kf0, qf[qi][0], s[qi][nf], 0, 0, 0);
                s[qi][nf] = __builtin_amdgcn_mfma_f32_16x16x32_bf16(kf1, qf[qi][1], s[qi][nf], 0, 0, 0);
            }
        }
        __builtin_amdgcn_s_setprio(0);
        unsigned pw[2][8];
#pragma unroll
        for (int qi = 0; qi < 2; ++qi)
#pragma unroll
            for (int nf = 0; nf < 4; ++nf) {
                float p0 = fexp2(s[qi][nf][0]);
                float p1 = fexp2(s[qi][nf][1]);
                float p2 = fexp2(s[qi][nf][2]);
                float p3 = fexp2(s[qi][nf][3]);
                pw[qi][nf * 2]     = cvtpk_bf16(p0, p1);
                pw[qi][nf * 2 + 1] = cvtpk_bf16(p2, p3);
            }
        __builtin_amdgcn_s_setprio(1);
#pragma unroll
        for (int kk = 0; kk < 2; ++kk) {
            bf16x8 pb[2];
#pragma unroll
            for (int qi = 0; qi < 2; ++qi) {
                int4v w = { (int)pw[qi][kk * 4], (int)pw[qi][kk * 4 + 1],
                            (int)pw[qi][kk * 4 + 2], (int)pw[qi][kk * 4 + 3] };
                pb[qi] = __builtin_bit_cast(bf16x8, w);
                psum[qi] = __builtin_amdgcn_mfma_f32_16x16x32_bf16(onesv, pb[qi], psum[qi], 0, 0, 0);
            }
#pragma unroll
            for (int df = 0; df < 4; ++df) {
                bf16x8 vf = *(const bf16x8*)&SMEM[buf][1][(df * 16 + lr) * 64 + ((kk * 32 + lhi * 8) ^ vx)];
                o[0][df] = __builtin_amdgcn_mfma_f32_16x16x32_bf16(vf, pb[0], o[0][df], 0, 0, 0);
                o[1][df] = __builtin_amdgcn_mfma_f32_16x16x32_bf16(vf, pb[1], o[1][df], 0, 0, 0);
            }
        }
        __builtin_amdgcn_s_setprio(0);
    };

    const int nt = SK >> 6;
    LOADG(0);
    STORES(0);
    if (nt > 1) LOADG(64);
    __syncthreads();
    for (int t = 0; t < nt; ++t) {
        COMPUTE(t & 1);
        if (t + 1 < nt) {
            STORES((t + 1) & 1);
            if (t + 2 < nt) LOADG((t + 2) << 6);
        }
        __syncthreads();
    }

    bf16* T = &SMEM[0][0][0] + wave * (32 * 72);
#pragma unroll
    for (int qi = 0; qi < 2; ++qi) {
        const float inv = 1.0f / psum[qi][0];
#pragma unroll
        for (int df = 0; df < 4; ++df)
#pragma unroll
            for (int r = 0; r < 4; ++r)
                T[(qi * 16 + lr) * 72 + df * 16 + lhi * 4 + r] = (bf16)(o[qi][df][r] * inv);
    }
#pragma unroll
    for (int pp = 0; pp < 4; ++pp) {
        const int r32 = pp * 8 + (lane >> 3), ch = (lane & 7) * 8;
        bf16x8 v = *(const bf16x8*)&T[r32 * 72 + ch];
        *(bf16x8*)(Ob + ((size_t)b * SQ + q0 + wave * 32 + r32) * H_DIM + h * HD + ch) = v;
    }
}

extern "C" void kernel_launch(void* const* d_in, const int* in_sizes, int n_in,
                              void* d_out, int out_size, void* d_ws, size_t ws_size,
                              hipStream_t stream) {
    const float* x    = (const float*)d_in[0];
    const float* img  = (const float*)d_in[1];
    const float* W_sq = (const float*)d_in[2];   const float* b_sq = (const float*)d_in[3];
    const float* W_sk = (const float*)d_in[4];   const float* b_sk = (const float*)d_in[5];
    const float* W_sv = (const float*)d_in[6];   const float* b_sv = (const float*)d_in[7];
    const float* W_so = (const float*)d_in[8];   const float* b_so = (const float*)d_in[9];
    const float* W_cq = (const float*)d_in[10];  const float* b_cq = (const float*)d_in[11];
    const float* W_ck = (const float*)d_in[12];  const float* b_ck = (const float*)d_in[13];
    const float* W_cv = (const float*)d_in[14];  const float* b_cv = (const float*)d_in[15];
    const float* W_co = (const float*)d_in[16];  const float* b_co = (const float*)d_in[17];
    const float* W_f1 = (const float*)d_in[18];  const float* b_f1 = (const float*)d_in[19];
    const float* W_f2 = (const float*)d_in[20];  const float* b_f2 = (const float*)d_in[21];
    const float* g1 = (const float*)d_in[22];    const float* bb1 = (const float*)d_in[23];
    const float* g2 = (const float*)d_in[24];    const float* bb2 = (const float*)d_in[25];
    const float* g3 = (const float*)d_in[26];    const float* bb3 = (const float*)d_in[27];

    char* ws = (char*)d_ws;
    const size_t MB = 1ull << 20;
    unsigned char* LN2_8 = (unsigned char*)(ws + 0 * MB);
    unsigned char* wcq8  = (unsigned char*)(ws + 4 * MB);
    bf16* WT   = (bf16*)ws;
    bf16* w_so = WT + 3 * (1u << 20);
    bf16* w_ck = WT + 5 * (1u << 20);
    bf16* w_cv = WT + 6 * (1u << 20);
    bf16* w_co = WT + 7 * (1u << 20);
    bf16* w_f1 = WT + 8 * (1u << 20);
    bf16* w_f2 = WT + 12 * (1u << 20);
    float* XR  = (float*)(ws + 32 * MB);
    bf16* NX   = (bf16*)(ws + 48 * MB);
    bf16* Qb   = (bf16*)(ws + 56 * MB);
    bf16* Kb   = (bf16*)(ws + 64 * MB);
    bf16* Vt   = (bf16*)(ws + 72 * MB);
    bf16* FF   = (bf16*)(ws + 56 * MB);
    unsigned char* W8  = (unsigned char*)(ws + 80 * MB);
    unsigned char* NX8 = (unsigned char*)(ws + 83 * MB);
    bf16* IMGB = (bf16*)(ws + 88 * MB);

    const dim3 blk(256);

    hipFuncSetAttribute((const void*)gemm_ff1_8ph,
                        hipFuncAttributeMaxDynamicSharedMemorySize, 131072);

    WPtrs wp;
    wp.w[0] = W_so; wp.o[0] = w_so;  wp.w[1] = W_ck; wp.o[1] = w_ck;
    wp.w[2] = W_cv; wp.o[2] = w_cv;  wp.w[3] = W_co; wp.o[3] = w_co;
    wconv4_kernel<<<dim3(16, 16, 4), blk, 0, stream>>>(wp);
    W3Ptrs w3; w3.w[0] = W_sq; w3.w[1] = W_sk; w3.w[2] = W_sv;
    wconv_fp8_kernel<<<dim3(16, 16, 3), blk, 0, stream>>>(w3, W8);
    wconv_fp8g<<<dim3(16, 16), blk, 0, stream>>>(W_cq, wcq8, 1024);
    wconv_kernel<<<dim3(64, 16), blk, 0, stream>>>(W_f1, w_f1, 1024, 4096);
    wconv_kernel<<<dim3(16, 64), blk, 0, stream>>>(W_f2, w_f2, 4096, 1024);

    // ---- self attention ----
    ln_fp8_kernel<<<4096, blk, 0, stream>>>(x, 0.1f, g1, bb1, (unsigned*)NX8);
    gemm_qkv_fp8<<<dim3(24, 32), blk, 0, stream>>>(NX8, W8, b_sq, b_sk, b_sv, Qb, Kb, Vt);
    attn_kernel<<<dim3(32, 16), blk, 0, stream>>>(Qb, Kb, Vt, NX, 2048, 2048);
    gemm_kernel<64, 128, 0, false, false, true><<<dim3(8, 64), blk, 0, stream>>>(
        NX, w_so, b_so, nullptr, nullptr, x, XR, nullptr, nullptr, 4096, 1024, 1024, 0.1f, 1.f, 0);

    // ---- cross attention ----
    ln_fp8_kernel<<<4096, blk, 0, stream>>>(XR, 1.f, g2, bb2, (unsigned*)LN2_8);
    gemm_f8q<<<dim3(8, 32), blk, 0, stream>>>(LN2_8, wcq8, b_cq, Qb, 4096, 1024);
    cvt_scale_kernel<<<dim3(512), blk, 0, stream>>>(img, IMGB, 0.1f, 131072);
    gemm_kernel<64, 128, 2, true, false, false><<<dim3(16, 8), blk, 0, stream>>>(
        IMGB, w_ck, b_ck, b_cv, nullptr, nullptr, Kb, Vt, nullptr, 512, 2048, 1024, 0.f, 1.f, 8);
    attn_kernel<<<dim3(32, 16), blk, 0, stream>>>(Qb, Kb, Vt, NX, 2048, 256);
    gemm_kernel<64, 128, 0, false, false, true><<<dim3(8, 64), blk, 0, stream>>>(
        NX, w_co, b_co, nullptr, nullptr, XR, XR, nullptr, nullptr, 4096, 1024, 1024, 1.f, 1.f, 0);

    // ---- feed forward ----
    ln_kernel<<<4096, blk, 0, stream>>>(XR, 1.f, g3, bb3, NX);
    gemm_ff1_8ph<<<dim3(16, 16), dim3(512), 131072, stream>>>(NX, w_f1, b_f1, FF);
    gemm_kernel<64, 128, 0, false, false, true><<<dim3(8, 64), blk, 0, stream>>>(
        FF, w_f2, b_f2, nullptr, nullptr, XR, d_out, nullptr, nullptr, 4096, 1024, 4096, 1.f, 10.f, 0);
}